// Round 1
// baseline (2908.960 us; speedup 1.0000x reference)
//
#include <hip/hip_runtime.h>

#define TB 35
#define BB 128
#define VV 10000
#define FF 1408
#define EE 512
#define HH 512
#define G4 2048   // 4*H

__device__ __forceinline__ float sigf(float x) { return 1.f / (1.f + expf(-x)); }

// ---------- mean over R=81 regions: mf[b][f] ----------
__global__ __launch_bounds__(256)
void mean_k(const float* __restrict__ img, float* __restrict__ mf) {
    int idx = blockIdx.x * 256 + threadIdx.x;      // exactly B*F = 180224
    int b = idx / FF, f = idx - b * FF;
    const float* p = img + (long)b * (81 * FF) + f;
    float s = 0.f;
    for (int r = 0; r < 81; ++r) s += p[r * FF];
    mf[idx] = s * (1.f / 81.f);
}

// ---------- init partial GEMM: mf(128x1408) x {W_init_h | W_init_c | W_ih[:,E:]}^T ----------
// 64x64 tiles, split-K by 4 (chunks of 352). part layout [4][128][3072].
__global__ __launch_bounds__(256)
void init_partial_k(const float* __restrict__ mf,
                    const float* __restrict__ Wh, const float* __restrict__ Wc,
                    const float* __restrict__ Wih,
                    float* __restrict__ part)
{
    __shared__ float As[16][68];
    __shared__ float Ws[16][68];
    const int t  = threadIdx.x;
    const int bx = blockIdx.x;              // 0..47
    const int bm = blockIdx.y * 64;         // 0 or 64
    const int kz = blockIdx.z;              // 0..3
    const float* W; int ldw; long wr0;
    if (bx < 8)       { W = Wh;       ldw = FF;   wr0 = (long)bx * 64; }
    else if (bx < 16) { W = Wc;       ldw = FF;   wr0 = (long)(bx - 8) * 64; }
    else              { W = Wih + EE; ldw = 1920; wr0 = (long)(bx - 16) * 64; }
    const int lrow = t >> 2, lc4 = (t & 3) << 2;
    const int ty = t >> 4, tx = t & 15;
    const float* arow = mf + (long)(bm + lrow) * FF;
    const float* wrow = W + (wr0 + lrow) * (long)ldw;
    float acc[4][4] = {};
    const int kbeg = kz * 352, kend2 = kbeg + 352;
    for (int k0 = kbeg; k0 < kend2; k0 += 16) {
        float4 av = *(const float4*)(arow + k0 + lc4);
        float4 wv = *(const float4*)(wrow + k0 + lc4);
        As[lc4+0][lrow]=av.x; As[lc4+1][lrow]=av.y; As[lc4+2][lrow]=av.z; As[lc4+3][lrow]=av.w;
        Ws[lc4+0][lrow]=wv.x; Ws[lc4+1][lrow]=wv.y; Ws[lc4+2][lrow]=wv.z; Ws[lc4+3][lrow]=wv.w;
        __syncthreads();
        #pragma unroll
        for (int kk = 0; kk < 16; ++kk) {
            float4 a = *(const float4*)&As[kk][ty*4];
            float4 w = *(const float4*)&Ws[kk][tx*4];
            acc[0][0]+=a.x*w.x; acc[0][1]+=a.x*w.y; acc[0][2]+=a.x*w.z; acc[0][3]+=a.x*w.w;
            acc[1][0]+=a.y*w.x; acc[1][1]+=a.y*w.y; acc[1][2]+=a.y*w.z; acc[1][3]+=a.y*w.w;
            acc[2][0]+=a.z*w.x; acc[2][1]+=a.z*w.y; acc[2][2]+=a.z*w.z; acc[2][3]+=a.z*w.w;
            acc[3][0]+=a.w*w.x; acc[3][1]+=a.w*w.y; acc[3][2]+=a.w*w.z; acc[3][3]+=a.w*w.w;
        }
        __syncthreads();
    }
    const int ncol = bx * 64;
    #pragma unroll
    for (int i = 0; i < 4; ++i) {
        long base = (long)kz * (BB*3072) + (long)(bm + ty*4 + i) * 3072 + ncol + tx*4;
        *(float4*)(part + base) = make_float4(acc[i][0], acc[i][1], acc[i][2], acc[i][3]);
    }
}

// ---------- combine init partials -> h0 (tanh), c0 (tanh), gxb (+b_ih+b_hh) ----------
__global__ __launch_bounds__(256)
void init_combine_k(const float* __restrict__ part,
                    const float* __restrict__ b_ih, const float* __restrict__ b_hh,
                    const float* __restrict__ b_init_h, const float* __restrict__ b_init_c,
                    float* __restrict__ h0, float* __restrict__ c_cur, float* __restrict__ gxb)
{
    int idx = blockIdx.x * 256 + threadIdx.x;   // 128*3072
    int b = idx / 3072, n = idx - b * 3072;
    float s = part[idx] + part[393216 + idx] + part[2*393216 + idx] + part[3*393216 + idx];
    if (n < 512)       h0[b*512 + n]          = tanhf(s + b_init_h[n]);
    else if (n < 1024) c_cur[b*512 + (n-512)] = tanhf(s + b_init_c[n-512]);
    else               gxb[b*2048 + (n-1024)] = s + b_ih[n-1024] + b_hh[n-1024];
}

// ---------- big GEMM: C = A(gathered rows) x W^T (+bias)(+radd)(act) ----------
// 128x128 tile, 256 thr, 8x8 micro. A staged in LDS; W rows streamed into registers
// (8 FMA per LDS float -> VALU-bound, not LDS-port-bound). M must be mult of 128.
template<int ACT>   // 0 none, 1 tanh, 2 relu
__global__ __launch_bounds__(256)
void gemm_big(const float* __restrict__ A, int lda, const int* __restrict__ rowidx,
              const float* __restrict__ W, int ldw,
              const float* __restrict__ bias,
              const float* __restrict__ radd, int radd_div, int radd_ld,
              float* __restrict__ C, int cdiv, long csq, long csr,
              int N, int K)
{
    __shared__ float As[8][132];
    const int t  = threadIdx.x;
    const int bm = blockIdx.y * 128;
    const int bn = blockIdx.x * 128;
    const int tx = t & 15;
    const int ty = t >> 4;                 // 0..15
    const int lrow = t >> 1, lc4 = (t & 1) << 2;
    const int am = bm + lrow;
    const float* arow = A + (long)(rowidx ? rowidx[am] : am) * lda;

    const float* wp[8];
    #pragma unroll
    for (int nn = 0; nn < 8; ++nn) {
        int row = bn + ((nn < 4) ? (tx*4 + nn) : (64 + tx*4 + nn - 4));
        if (row > N - 1) row = N - 1;       // clamp; epilogue guards the store
        wp[nn] = W + (long)row * ldw;
    }

    float acc[8][8] = {};
    for (int k0 = 0; k0 < K; k0 += 8) {
        float4 av = *(const float4*)(arow + k0 + lc4);
        As[lc4+0][lrow]=av.x; As[lc4+1][lrow]=av.y; As[lc4+2][lrow]=av.z; As[lc4+3][lrow]=av.w;
        float wreg[8][8];
        #pragma unroll
        for (int nn = 0; nn < 8; ++nn) {
            float4 w0 = *(const float4*)(wp[nn] + k0);
            float4 w1 = *(const float4*)(wp[nn] + k0 + 4);
            wreg[nn][0]=w0.x; wreg[nn][1]=w0.y; wreg[nn][2]=w0.z; wreg[nn][3]=w0.w;
            wreg[nn][4]=w1.x; wreg[nn][5]=w1.y; wreg[nn][6]=w1.z; wreg[nn][7]=w1.w;
        }
        __syncthreads();
        #pragma unroll
        for (int kk = 0; kk < 8; ++kk) {
            float4 q0 = *(const float4*)&As[kk][ty*4];
            float4 q1 = *(const float4*)&As[kk][64 + ty*4];
            float am8[8] = {q0.x,q0.y,q0.z,q0.w,q1.x,q1.y,q1.z,q1.w};
            #pragma unroll
            for (int mm = 0; mm < 8; ++mm)
                #pragma unroll
                for (int nn = 0; nn < 8; ++nn)
                    acc[mm][nn] += am8[mm] * wreg[nn][kk];
        }
        __syncthreads();
    }
    #pragma unroll
    for (int mm = 0; mm < 8; ++mm) {
        int m = bm + ((mm < 4) ? (ty*4 + mm) : (64 + ty*4 + mm - 4));
        long cb = (long)(m / cdiv) * csq + (long)(m % cdiv) * csr;
        const float* rr = radd ? (radd + (long)(m / radd_div) * radd_ld) : nullptr;
        #pragma unroll
        for (int nn = 0; nn < 8; ++nn) {
            int n = bn + ((nn < 4) ? (tx*4 + nn) : (64 + tx*4 + nn - 4));
            if (n < N) {
                float v = acc[mm][nn];
                if (bias) v += bias[n];
                if (rr)   v += rr[n];
                if (ACT == 1) v = tanhf(v);
                if (ACT == 2) v = fmaxf(v, 0.f);
                C[cb + n] = v;
            }
        }
    }
}

// ---------- LSTM step GEMM: part[z][128][2048] = h_prev x Whh^T (K chunk z of 64) ----------
// 128 thr/block, 8x8 micro, W in registers. grid (32 n-tiles, 8 k-chunks) = 256 blocks.
__global__ __launch_bounds__(128)
void step_gemm_k(const float* __restrict__ h_prev, const float* __restrict__ Whh,
                 float* __restrict__ part)
{
    __shared__ float As[8][132];
    const int t   = threadIdx.x;           // 0..127
    const int bn  = blockIdx.x * 64;
    const int k00 = blockIdx.y * 64;
    const int my  = t >> 3;                // 0..15 -> rows my*8..+7
    const int nx  = t & 7;                 // 0..7  -> cols nx*8..+7
    const float* wb[8];
    #pragma unroll
    for (int j = 0; j < 8; ++j) wb[j] = Whh + (long)(bn + nx*8 + j) * 512 + k00;
    float acc[8][8] = {};
    for (int ph = 0; ph < 8; ++ph) {
        const float* hp = h_prev + (long)t * 512 + k00 + ph*8;
        float4 a0 = *(const float4*)hp;
        float4 a1 = *(const float4*)(hp + 4);
        As[0][t]=a0.x; As[1][t]=a0.y; As[2][t]=a0.z; As[3][t]=a0.w;
        As[4][t]=a1.x; As[5][t]=a1.y; As[6][t]=a1.z; As[7][t]=a1.w;
        float wreg[8][8];
        #pragma unroll
        for (int j = 0; j < 8; ++j) {
            float4 w0 = *(const float4*)(wb[j] + ph*8);
            float4 w1 = *(const float4*)(wb[j] + ph*8 + 4);
            wreg[j][0]=w0.x; wreg[j][1]=w0.y; wreg[j][2]=w0.z; wreg[j][3]=w0.w;
            wreg[j][4]=w1.x; wreg[j][5]=w1.y; wreg[j][6]=w1.z; wreg[j][7]=w1.w;
        }
        __syncthreads();
        #pragma unroll
        for (int kk = 0; kk < 8; ++kk) {
            float4 q0 = *(const float4*)&As[kk][my*8];
            float4 q1 = *(const float4*)&As[kk][my*8+4];
            float am8[8] = {q0.x,q0.y,q0.z,q0.w,q1.x,q1.y,q1.z,q1.w};
            #pragma unroll
            for (int mm = 0; mm < 8; ++mm)
                #pragma unroll
                for (int j = 0; j < 8; ++j)
                    acc[mm][j] += am8[mm] * wreg[j][kk];
        }
        __syncthreads();
    }
    const long pb = (long)blockIdx.y * (BB * G4);
    #pragma unroll
    for (int mm = 0; mm < 8; ++mm) {
        long base = pb + (long)(my*8 + mm) * G4 + bn + nx*8;
        *(float4*)(part + base)     = make_float4(acc[mm][0],acc[mm][1],acc[mm][2],acc[mm][3]);
        *(float4*)(part + base + 4) = make_float4(acc[mm][4],acc[mm][5],acc[mm][6],acc[mm][7]);
    }
}

// ---------- LSTM elementwise: sum partials + gx_t -> gates -> update c, write h ----------
__global__ __launch_bounds__(256)
void lstm_elem_k(const float* __restrict__ part, const float* __restrict__ gx_t,
                 float* __restrict__ c_cur, float* __restrict__ h_next)
{
    int idx = blockIdx.x * 256 + threadIdx.x;   // 128*512
    int b = idx >> 9, j = idx & 511;
    float g4[4];
    #pragma unroll
    for (int g = 0; g < 4; ++g) {
        long col = (long)b * G4 + g*512 + j;
        float s = gx_t[(long)b * (TB*G4) + g*512 + j];
        #pragma unroll
        for (int z = 0; z < 8; ++z) s += part[(long)z * (BB*G4) + col];
        g4[g] = s;
    }
    float ig = sigf(g4[0]), fg = sigf(g4[1]);
    float gg = tanhf(g4[2]), og = sigf(g4[3]);
    float c = fg * c_cur[idx] + ig * gg;
    c_cur[idx] = c;
    h_next[idx] = og * tanhf(c);
}

extern "C" void kernel_launch(void* const* d_in, const int* in_sizes, int n_in,
                              void* d_out, int out_size, void* d_ws, size_t ws_size,
                              hipStream_t stream)
{
    const float* img    = (const float*)d_in[0];
    const int*   seqs   = (const int*)d_in[1];
    // d_in[2] = lengths: unused by the reference
    const float* emb    = (const float*)d_in[3];
    const float* W_ih   = (const float*)d_in[4];
    const float* b_ih   = (const float*)d_in[5];
    const float* W_hh   = (const float*)d_in[6];
    const float* b_hh   = (const float*)d_in[7];
    const float* W_inh  = (const float*)d_in[8];
    const float* b_inh  = (const float*)d_in[9];
    const float* W_inc  = (const float*)d_in[10];
    const float* b_inc  = (const float*)d_in[11];
    const float* W_fc1  = (const float*)d_in[12];
    const float* b_fc1  = (const float*)d_in[13];
    const float* W_fc2  = (const float*)d_in[14];
    const float* b_fc2  = (const float*)d_in[15];
    float* out = (float*)d_out;

    float* ws    = (float*)d_ws;
    float* mf    = ws;                      // 180224
    float* h0    = mf    + 180224;          // 65536
    float* c_cur = h0    + 65536;           // 65536
    float* gxb   = c_cur + 65536;           // 262144
    float* ipart = gxb   + 262144;          // 4*393216
    float* spart = ipart + 1572864;         // 8*262144
    float* gx    = spart + 2097152;         // 128*35*2048
    float* h_all = gx    + 9175040;         // 35*128*512
    float* o_all = h_all + 2293760;         // 35*128*512

    mean_k<<<704, 256, 0, stream>>>(img, mf);
    init_partial_k<<<dim3(48, 2, 4), 256, 0, stream>>>(mf, W_inh, W_inc, W_ih, ipart);
    init_combine_k<<<1536, 256, 0, stream>>>(ipart, b_ih, b_hh, b_inh, b_inc, h0, c_cur, gxb);

    // gx[b*T+t][n] = emb[seq[b][t]] . W_ih[n][:E] + gxb[b][n]   (biases already in gxb)
    gemm_big<0><<<dim3(16, 35), 256, 0, stream>>>(emb, EE, seqs, W_ih, 1920, nullptr,
                                                  gxb, TB, G4, gx, 1 << 30, 0, G4, G4, EE);

    for (int t = 0; t < TB; ++t) {
        const float* hp = t ? (h_all + (long)(t - 1) * (BB * HH)) : h0;
        step_gemm_k<<<dim3(32, 8), 128, 0, stream>>>(hp, W_hh, spart);
        lstm_elem_k<<<256, 256, 0, stream>>>(spart, gx + (long)t * G4, c_cur,
                                             h_all + (long)t * (BB * HH));
    }

    // out_all = relu(h_all @ W_fc1^T + b_fc1)   rows are (t,b)
    gemm_big<2><<<dim3(4, 35), 256, 0, stream>>>(h_all, HH, nullptr, W_fc1, HH, b_fc1,
                                                 nullptr, 1, 0, o_all, 1 << 30, 0, HH, HH, HH);
    // logits: row m=(t*128+b) -> out[b][t][:]  via cdiv=128, csq=V, csr=T*V
    gemm_big<0><<<dim3(79, 35), 256, 0, stream>>>(o_all, HH, nullptr, W_fc2, HH, b_fc2,
                                                  nullptr, 1, 0, out, BB, VV, (long)TB * VV,
                                                  VV, HH);
}

// Round 2
// 1097.557 us; speedup vs baseline: 2.6504x; 2.6504x over previous
//
#include <hip/hip_runtime.h>

#define TB 35
#define BB 128
#define VV 10000
#define FF 1408
#define EE 512
#define HH 512
#define G4 2048   // 4*H

typedef unsigned short u16;
typedef __attribute__((ext_vector_type(8))) short bfrag;   // 8 bf16 = 4 VGPR
typedef __attribute__((ext_vector_type(4))) float facc;    // 4 f32 accum

__device__ __forceinline__ float sigf(float x) { return 1.f / (1.f + expf(-x)); }

__device__ __forceinline__ u16 f2bf(float f) {             // RNE f32->bf16
    unsigned u = __float_as_uint(f);
    return (u16)((u + 0x7FFFu + ((u >> 16) & 1u)) >> 16);
}

__device__ __forceinline__ void gload16(const void* g, void* l) {
    __builtin_amdgcn_global_load_lds(
        (const __attribute__((address_space(1))) void*)g,
        (__attribute__((address_space(3))) void*)l, 16, 0, 0);
}

// ---------- mean over R=81 regions ----------
__global__ __launch_bounds__(256)
void mean_k(const float* __restrict__ img, float* __restrict__ mf) {
    int idx = blockIdx.x * 256 + threadIdx.x;      // B*F = 180224
    int b = idx / FF, f = idx - b * FF;
    const float* p = img + (long)b * (81 * FF) + f;
    float s = 0.f;
    for (int r = 0; r < 81; ++r) s += p[r * FF];
    mf[idx] = s * (1.f / 81.f);
}

// ---------- fp32 -> bf16 cast (cols==512, vector-4) ----------
__global__ __launch_bounds__(256)
void cast512_k(const float* __restrict__ src, int lds, u16* __restrict__ dst, int n4) {
    int i = blockIdx.x * 256 + threadIdx.x;
    if (i >= n4) return;
    long e = (long)i * 4;
    long row = e >> 9; int col = (int)(e & 511);
    float4 v = *(const float4*)(src + row * lds + col);
    uint2 o;
    o.x = (unsigned)f2bf(v.x) | ((unsigned)f2bf(v.y) << 16);
    o.y = (unsigned)f2bf(v.z) | ((unsigned)f2bf(v.w) << 16);
    *(uint2*)(dst + e) = o;
}

// ---------- init partial GEMM (fp32): mf(128x1408) x {W_init_h|W_init_c|W_ih[:,E:]}^T ----------
__global__ __launch_bounds__(256)
void init_partial_k(const float* __restrict__ mf,
                    const float* __restrict__ Wh, const float* __restrict__ Wc,
                    const float* __restrict__ Wih,
                    float* __restrict__ part)
{
    __shared__ float As[16][68];
    __shared__ float Ws[16][68];
    const int t  = threadIdx.x;
    const int bx = blockIdx.x;              // 0..47
    const int bm = blockIdx.y * 64;
    const int kz = blockIdx.z;              // 0..3
    const float* W; int ldw; long wr0;
    if (bx < 8)       { W = Wh;       ldw = FF;   wr0 = (long)bx * 64; }
    else if (bx < 16) { W = Wc;       ldw = FF;   wr0 = (long)(bx - 8) * 64; }
    else              { W = Wih + EE; ldw = 1920; wr0 = (long)(bx - 16) * 64; }
    const int lrow = t >> 2, lc4 = (t & 3) << 2;
    const int ty = t >> 4, tx = t & 15;
    const float* arow = mf + (long)(bm + lrow) * FF;
    const float* wrow = W + (wr0 + lrow) * (long)ldw;
    float acc[4][4] = {};
    const int kbeg = kz * 352, kend2 = kbeg + 352;
    for (int k0 = kbeg; k0 < kend2; k0 += 16) {
        float4 av = *(const float4*)(arow + k0 + lc4);
        float4 wv = *(const float4*)(wrow + k0 + lc4);
        As[lc4+0][lrow]=av.x; As[lc4+1][lrow]=av.y; As[lc4+2][lrow]=av.z; As[lc4+3][lrow]=av.w;
        Ws[lc4+0][lrow]=wv.x; Ws[lc4+1][lrow]=wv.y; Ws[lc4+2][lrow]=wv.z; Ws[lc4+3][lrow]=wv.w;
        __syncthreads();
        #pragma unroll
        for (int kk = 0; kk < 16; ++kk) {
            float4 a = *(const float4*)&As[kk][ty*4];
            float4 w = *(const float4*)&Ws[kk][tx*4];
            acc[0][0]+=a.x*w.x; acc[0][1]+=a.x*w.y; acc[0][2]+=a.x*w.z; acc[0][3]+=a.x*w.w;
            acc[1][0]+=a.y*w.x; acc[1][1]+=a.y*w.y; acc[1][2]+=a.y*w.z; acc[1][3]+=a.y*w.w;
            acc[2][0]+=a.z*w.x; acc[2][1]+=a.z*w.y; acc[2][2]+=a.z*w.z; acc[2][3]+=a.z*w.w;
            acc[3][0]+=a.w*w.x; acc[3][1]+=a.w*w.y; acc[3][2]+=a.w*w.z; acc[3][3]+=a.w*w.w;
        }
        __syncthreads();
    }
    const int ncol = bx * 64;
    #pragma unroll
    for (int i = 0; i < 4; ++i) {
        long base = (long)kz * (BB*3072) + (long)(bm + ty*4 + i) * 3072 + ncol + tx*4;
        *(float4*)(part + base) = make_float4(acc[i][0], acc[i][1], acc[i][2], acc[i][3]);
    }
}

// ---------- combine init partials -> h0, c0, gxb ----------
__global__ __launch_bounds__(256)
void init_combine_k(const float* __restrict__ part,
                    const float* __restrict__ b_ih, const float* __restrict__ b_hh,
                    const float* __restrict__ b_init_h, const float* __restrict__ b_init_c,
                    float* __restrict__ h0, float* __restrict__ c_cur, float* __restrict__ gxb)
{
    int idx = blockIdx.x * 256 + threadIdx.x;   // 128*3072
    int b = idx / 3072, n = idx - b * 3072;
    float s = part[idx] + part[393216 + idx] + part[2*393216 + idx] + part[3*393216 + idx];
    if (n < 512)       h0[b*512 + n]          = tanhf(s + b_init_h[n]);
    else if (n < 1024) c_cur[b*512 + (n-512)] = tanhf(s + b_init_c[n-512]);
    else               gxb[b*2048 + (n-1024)] = s + b_ih[n-1024] + b_hh[n-1024];
}

// ---------- bf16 MFMA GEMM: C = A(bf16, gathered rows) x W(bf16)^T, fp32 epilogue ----------
// 128x128 tile, 4 waves (2x2), each wave 64x64 = 4x4 frags of 16x16x32.
// LDS linear for global_load_lds; chunk-XOR swizzle (chunk^=(row>>1)&3) applied on BOTH
// the pre-swizzled global source and the ds_read addr -> 2-way (free) bank access.
template<int ACT, int OBF>   // ACT: 0 none, 2 relu; OBF: 1 = bf16 output
__global__ __launch_bounds__(256)
void gemm_mfma(const u16* __restrict__ A, int lda, const int* __restrict__ rowidx,
               const u16* __restrict__ W, const float* __restrict__ bias,
               const float* __restrict__ radd, int radd_div, int radd_ld,
               void* __restrict__ C, int cdiv, long csq, long csr,
               int N, int K)
{
    __shared__ u16 lA[4096];   // [128][32]
    __shared__ u16 lB[4096];
    const int t    = threadIdx.x;
    const int bm   = blockIdx.y * 128;
    const int bn   = blockIdx.x * 128;
    const int lane = t & 63;
    const int wv   = t >> 6;
    const int wm   = (wv >> 1) * 64;
    const int wn   = (wv & 1) * 64;
    const int fr   = lane & 15;
    const int cc   = lane >> 4;

    // staging: thread handles tile chunks q and q+256 (16B each) of both A and B
    const int q0 = t, q1 = t + 256;
    const int ra0 = q0 >> 2, ca0 = (q0 & 3) ^ ((ra0 >> 1) & 3);
    const int ra1 = q1 >> 2, ca1 = (q1 & 3) ^ ((ra1 >> 1) & 3);
    long arow0 = rowidx ? (long)rowidx[bm + ra0] : (long)(bm + ra0);
    long arow1 = rowidx ? (long)rowidx[bm + ra1] : (long)(bm + ra1);
    const u16* asrc0 = A + arow0 * lda + ca0 * 8;
    const u16* asrc1 = A + arow1 * lda + ca1 * 8;
    int brow0 = bn + ra0; if (brow0 > N - 1) brow0 = N - 1;
    int brow1 = bn + ra1; if (brow1 > N - 1) brow1 = N - 1;
    const u16* bsrc0 = W + (long)brow0 * K + ca0 * 8;
    const u16* bsrc1 = W + (long)brow1 * K + ca1 * 8;
    u16* adst0 = lA + q0 * 8;  u16* adst1 = lA + q1 * 8;
    u16* bdst0 = lB + q0 * 8;  u16* bdst1 = lB + q1 * 8;

    // fragment ds_read byte offsets (swizzled)
    int aoff[4], boff[4];
    #pragma unroll
    for (int i = 0; i < 4; ++i) {
        int rA = wm + i * 16 + fr;
        aoff[i] = rA * 64 + ((cc ^ ((rA >> 1) & 3)) << 4);
        int rB = wn + i * 16 + fr;
        boff[i] = rB * 64 + ((cc ^ ((rB >> 1) & 3)) << 4);
    }
    const char* lac = (const char*)lA;
    const char* lbc = (const char*)lB;

    facc acc[4][4] = {};
    for (int k0 = 0; k0 < K; k0 += 32) {
        gload16(asrc0 + k0, adst0);
        gload16(asrc1 + k0, adst1);
        gload16(bsrc0 + k0, bdst0);
        gload16(bsrc1 + k0, bdst1);
        __syncthreads();               // compiler drains vmcnt before s_barrier
        bfrag av[4], bv[4];
        #pragma unroll
        for (int i = 0; i < 4; ++i) av[i] = *(const bfrag*)(lac + aoff[i]);
        #pragma unroll
        for (int i = 0; i < 4; ++i) bv[i] = *(const bfrag*)(lbc + boff[i]);
        #pragma unroll
        for (int mi = 0; mi < 4; ++mi)
            #pragma unroll
            for (int ni = 0; ni < 4; ++ni)
                acc[mi][ni] = __builtin_amdgcn_mfma_f32_16x16x32_bf16(
                    av[mi], bv[ni], acc[mi][ni], 0, 0, 0);
        __syncthreads();
    }

    // epilogue: D[row=(lane>>4)*4+r][col=lane&15] per frag
    #pragma unroll
    for (int mi = 0; mi < 4; ++mi) {
        #pragma unroll
        for (int r = 0; r < 4; ++r) {
            int m = bm + wm + mi * 16 + (lane >> 4) * 4 + r;
            long cb = (long)(m / cdiv) * csq + (long)(m % cdiv) * csr;
            const float* rr = radd ? (radd + (long)(m / radd_div) * radd_ld) : nullptr;
            #pragma unroll
            for (int ni = 0; ni < 4; ++ni) {
                int n = bn + wn + ni * 16 + fr;
                if (n < N) {
                    float v = acc[mi][ni][r];
                    if (bias) v += bias[n];
                    if (rr)   v += rr[n];
                    if (ACT == 2) v = fmaxf(v, 0.f);
                    if (OBF) ((u16*)C)[cb + n] = f2bf(v);
                    else     ((float*)C)[cb + n] = v;
                }
            }
        }
    }
}

// ---------- LSTM step GEMM (fp32): part[z][128][2048] = h_prev x Whh^T (K chunk z) ----------
__global__ __launch_bounds__(128)
void step_gemm_k(const float* __restrict__ h_prev, const float* __restrict__ Whh,
                 float* __restrict__ part)
{
    __shared__ float As[8][132];
    const int t   = threadIdx.x;
    const int bn  = blockIdx.x * 64;
    const int k00 = blockIdx.y * 64;
    const int my  = t >> 3;
    const int nx  = t & 7;
    const float* wb[8];
    #pragma unroll
    for (int j = 0; j < 8; ++j) wb[j] = Whh + (long)(bn + nx*8 + j) * 512 + k00;
    float acc[8][8] = {};
    for (int ph = 0; ph < 8; ++ph) {
        const float* hp = h_prev + (long)t * 512 + k00 + ph*8;
        float4 a0 = *(const float4*)hp;
        float4 a1 = *(const float4*)(hp + 4);
        As[0][t]=a0.x; As[1][t]=a0.y; As[2][t]=a0.z; As[3][t]=a0.w;
        As[4][t]=a1.x; As[5][t]=a1.y; As[6][t]=a1.z; As[7][t]=a1.w;
        float wreg[8][8];
        #pragma unroll
        for (int j = 0; j < 8; ++j) {
            float4 w0 = *(const float4*)(wb[j] + ph*8);
            float4 w1 = *(const float4*)(wb[j] + ph*8 + 4);
            wreg[j][0]=w0.x; wreg[j][1]=w0.y; wreg[j][2]=w0.z; wreg[j][3]=w0.w;
            wreg[j][4]=w1.x; wreg[j][5]=w1.y; wreg[j][6]=w1.z; wreg[j][7]=w1.w;
        }
        __syncthreads();
        #pragma unroll
        for (int kk = 0; kk < 8; ++kk) {
            float4 q0 = *(const float4*)&As[kk][my*8];
            float4 q1 = *(const float4*)&As[kk][my*8+4];
            float am8[8] = {q0.x,q0.y,q0.z,q0.w,q1.x,q1.y,q1.z,q1.w};
            #pragma unroll
            for (int mm = 0; mm < 8; ++mm)
                #pragma unroll
                for (int j = 0; j < 8; ++j)
                    acc[mm][j] += am8[mm] * wreg[j][kk];
        }
        __syncthreads();
    }
    const long pb = (long)blockIdx.y * (BB * G4);
    #pragma unroll
    for (int mm = 0; mm < 8; ++mm) {
        long base = pb + (long)(my*8 + mm) * G4 + bn + nx*8;
        *(float4*)(part + base)     = make_float4(acc[mm][0],acc[mm][1],acc[mm][2],acc[mm][3]);
        *(float4*)(part + base + 4) = make_float4(acc[mm][4],acc[mm][5],acc[mm][6],acc[mm][7]);
    }
}

// ---------- LSTM elementwise (also writes bf16 copy of h for fc1) ----------
__global__ __launch_bounds__(256)
void lstm_elem_k(const float* __restrict__ part, const float* __restrict__ gx_t,
                 float* __restrict__ c_cur, float* __restrict__ h_next,
                 u16* __restrict__ h_b16)
{
    int idx = blockIdx.x * 256 + threadIdx.x;   // 128*512
    int b = idx >> 9, j = idx & 511;
    float g4[4];
    #pragma unroll
    for (int g = 0; g < 4; ++g) {
        long col = (long)b * G4 + g*512 + j;
        float s = gx_t[(long)b * (TB*G4) + g*512 + j];
        #pragma unroll
        for (int z = 0; z < 8; ++z) s += part[(long)z * (BB*G4) + col];
        g4[g] = s;
    }
    float ig = sigf(g4[0]), fg = sigf(g4[1]);
    float gg = tanhf(g4[2]), og = sigf(g4[3]);
    float c = fg * c_cur[idx] + ig * gg;
    c_cur[idx] = c;
    float h = og * tanhf(c);
    h_next[idx] = h;
    h_b16[idx]  = f2bf(h);
}

extern "C" void kernel_launch(void* const* d_in, const int* in_sizes, int n_in,
                              void* d_out, int out_size, void* d_ws, size_t ws_size,
                              hipStream_t stream)
{
    const float* img    = (const float*)d_in[0];
    const int*   seqs   = (const int*)d_in[1];
    const float* emb    = (const float*)d_in[3];
    const float* W_ih   = (const float*)d_in[4];
    const float* b_ih   = (const float*)d_in[5];
    const float* W_hh   = (const float*)d_in[6];
    const float* b_hh   = (const float*)d_in[7];
    const float* W_inh  = (const float*)d_in[8];
    const float* b_inh  = (const float*)d_in[9];
    const float* W_inc  = (const float*)d_in[10];
    const float* b_inc  = (const float*)d_in[11];
    const float* W_fc1  = (const float*)d_in[12];
    const float* b_fc1  = (const float*)d_in[13];
    const float* W_fc2  = (const float*)d_in[14];
    const float* b_fc2  = (const float*)d_in[15];
    float* out = (float*)d_out;

    float* ws    = (float*)d_ws;
    float* mf    = ws;                      // 180224
    float* h0    = mf    + 180224;          // 65536
    float* c_cur = h0    + 65536;           // 65536
    float* gxb   = c_cur + 65536;           // 262144
    float* spart = gxb   + 262144;          // 2097152 (8*262144)
    float* gx    = spart + 2097152;         // 9175040 (128*35*2048)
    float* h_all = gx    + 9175040;         // 2293760
    float* ipart = gx;                      // alias: 1572864 <= 9175040, dead before gx
    u16*   o_b   = (u16*)spart;             // alias: 2293760 u16 <= spart bytes, used post-recurrence
    u16*   emb_b  = (u16*)(h_all + 2293760);   // 5120000
    u16*   wih_b  = emb_b  + 5120000;          // 1048576
    u16*   wfc1_b = wih_b  + 1048576;          // 262144
    u16*   wfc2_b = wfc1_b + 262144;           // 5120000
    u16*   h_b    = wfc2_b + 5120000;          // 2293760

    // weight / embedding casts to bf16
    cast512_k<<<5000, 256, 0, stream>>>(emb,   512,  emb_b,  1280000);
    cast512_k<<<1024, 256, 0, stream>>>(W_ih,  1920, wih_b,   262144);
    cast512_k<<< 256, 256, 0, stream>>>(W_fc1, 512,  wfc1_b,   65536);
    cast512_k<<<5000, 256, 0, stream>>>(W_fc2, 512,  wfc2_b, 1280000);

    mean_k<<<704, 256, 0, stream>>>(img, mf);
    init_partial_k<<<dim3(48, 2, 4), 256, 0, stream>>>(mf, W_inh, W_inc, W_ih, ipart);
    init_combine_k<<<1536, 256, 0, stream>>>(ipart, b_ih, b_hh, b_inh, b_inc, h0, c_cur, gxb);

    // gx[b*T+t][n] = emb_b[seq[b][t]] . wih_b[n] + gxb[b][n]
    gemm_mfma<0,0><<<dim3(16, 35), 256, 0, stream>>>(emb_b, EE, seqs, wih_b, nullptr,
                                                     gxb, TB, G4, gx, 1 << 30, 0, G4,
                                                     G4, EE);

    for (int t = 0; t < TB; ++t) {
        const float* hp = t ? (h_all + (long)(t - 1) * (BB * HH)) : h0;
        step_gemm_k<<<dim3(32, 8), 128, 0, stream>>>(hp, W_hh, spart);
        lstm_elem_k<<<256, 256, 0, stream>>>(spart, gx + (long)t * G4, c_cur,
                                             h_all + (long)t * (BB * HH),
                                             h_b + (long)t * (BB * HH));
    }

    // o_b = relu(h_all @ W_fc1^T + b_fc1), bf16, rows m=(t*128+b)
    gemm_mfma<2,1><<<dim3(4, 35), 256, 0, stream>>>(h_b, HH, nullptr, wfc1_b, b_fc1,
                                                    nullptr, 1, 0, o_b, 1 << 30, 0, HH,
                                                    HH, HH);
    // logits: row m=(t*128+b) -> out[b][t][:]
    gemm_mfma<0,0><<<dim3(79, 35), 256, 0, stream>>>(o_b, HH, nullptr, wfc2_b, b_fc2,
                                                     nullptr, 1, 0, out, BB, VV,
                                                     (long)TB * VV, VV, HH);
}

// Round 3
// 841.025 us; speedup vs baseline: 3.4588x; 1.3050x over previous
//
#include <hip/hip_runtime.h>
#include <hip/hip_cooperative_groups.h>

namespace cg = cooperative_groups;

#define TB 35
#define BB 128
#define VV 10000
#define FF 1408
#define EE 512
#define HH 512
#define G4 2048   // 4*H

typedef unsigned short u16;
typedef __attribute__((ext_vector_type(8))) short bfrag;   // 8 bf16 = 4 VGPR
typedef __attribute__((ext_vector_type(4))) float f32x4;

__device__ __forceinline__ u16 f2bf(float f) {             // RNE f32->bf16
    unsigned u = __float_as_uint(f);
    return (u16)((u + 0x7FFFu + ((u >> 16) & 1u)) >> 16);
}
__device__ __forceinline__ float fast_sig(float x) {
    return __builtin_amdgcn_rcpf(1.f + __expf(-x));
}
__device__ __forceinline__ float fast_tanh(float x) {
    return 1.f - 2.f * __builtin_amdgcn_rcpf(1.f + __expf(2.f * x));
}

__device__ __forceinline__ void gload16(const void* g, void* l) {
    __builtin_amdgcn_global_load_lds(
        (const __attribute__((address_space(1))) void*)g,
        (__attribute__((address_space(3))) void*)l, 16, 0, 0);
}

// ---------- mean over R=81 regions ----------
__global__ __launch_bounds__(256)
void mean_k(const float* __restrict__ img, float* __restrict__ mf) {
    int idx = blockIdx.x * 256 + threadIdx.x;      // B*F = 180224
    int b = idx / FF, f = idx - b * FF;
    const float* p = img + (long)b * (81 * FF) + f;
    float s = 0.f;
    for (int r = 0; r < 81; ++r) s += p[r * FF];
    mf[idx] = s * (1.f / 81.f);
}

// ---------- fp32 -> bf16 cast (row length 512, vector-4) ----------
__global__ __launch_bounds__(256)
void cast512_k(const float* __restrict__ src, int lds, u16* __restrict__ dst, int n4) {
    int i = blockIdx.x * 256 + threadIdx.x;
    if (i >= n4) return;
    long e = (long)i * 4;
    long row = e >> 9; int col = (int)(e & 511);
    float4 v = *(const float4*)(src + row * lds + col);
    uint2 o;
    o.x = (unsigned)f2bf(v.x) | ((unsigned)f2bf(v.y) << 16);
    o.y = (unsigned)f2bf(v.z) | ((unsigned)f2bf(v.w) << 16);
    *(uint2*)(dst + e) = o;
}

// ---------- init partial GEMM (fp32): mf(128x1408) x {W_init_h|W_init_c|W_ih[:,E:]}^T ----------
__global__ __launch_bounds__(256)
void init_partial_k(const float* __restrict__ mf,
                    const float* __restrict__ Wh, const float* __restrict__ Wc,
                    const float* __restrict__ Wih,
                    float* __restrict__ part)
{
    __shared__ float As[16][68];
    __shared__ float Ws[16][68];
    const int t  = threadIdx.x;
    const int bx = blockIdx.x;              // 0..47
    const int bm = blockIdx.y * 64;
    const int kz = blockIdx.z;              // 0..3
    const float* W; int ldw; long wr0;
    if (bx < 8)       { W = Wh;       ldw = FF;   wr0 = (long)bx * 64; }
    else if (bx < 16) { W = Wc;       ldw = FF;   wr0 = (long)(bx - 8) * 64; }
    else              { W = Wih + EE; ldw = 1920; wr0 = (long)(bx - 16) * 64; }
    const int lrow = t >> 2, lc4 = (t & 3) << 2;
    const int ty = t >> 4, tx = t & 15;
    const float* arow = mf + (long)(bm + lrow) * FF;
    const float* wrow = W + (wr0 + lrow) * (long)ldw;
    float acc[4][4] = {};
    const int kbeg = kz * 352, kend2 = kbeg + 352;
    for (int k0 = kbeg; k0 < kend2; k0 += 16) {
        float4 av = *(const float4*)(arow + k0 + lc4);
        float4 wv = *(const float4*)(wrow + k0 + lc4);
        As[lc4+0][lrow]=av.x; As[lc4+1][lrow]=av.y; As[lc4+2][lrow]=av.z; As[lc4+3][lrow]=av.w;
        Ws[lc4+0][lrow]=wv.x; Ws[lc4+1][lrow]=wv.y; Ws[lc4+2][lrow]=wv.z; Ws[lc4+3][lrow]=wv.w;
        __syncthreads();
        #pragma unroll
        for (int kk = 0; kk < 16; ++kk) {
            float4 a = *(const float4*)&As[kk][ty*4];
            float4 w = *(const float4*)&Ws[kk][tx*4];
            acc[0][0]+=a.x*w.x; acc[0][1]+=a.x*w.y; acc[0][2]+=a.x*w.z; acc[0][3]+=a.x*w.w;
            acc[1][0]+=a.y*w.x; acc[1][1]+=a.y*w.y; acc[1][2]+=a.y*w.z; acc[1][3]+=a.y*w.w;
            acc[2][0]+=a.z*w.x; acc[2][1]+=a.z*w.y; acc[2][2]+=a.z*w.z; acc[2][3]+=a.z*w.w;
            acc[3][0]+=a.w*w.x; acc[3][1]+=a.w*w.y; acc[3][2]+=a.w*w.z; acc[3][3]+=a.w*w.w;
        }
        __syncthreads();
    }
    const int ncol = bx * 64;
    #pragma unroll
    for (int i = 0; i < 4; ++i) {
        long base = (long)kz * (BB*3072) + (long)(bm + ty*4 + i) * 3072 + ncol + tx*4;
        *(float4*)(part + base) = make_float4(acc[i][0], acc[i][1], acc[i][2], acc[i][3]);
    }
}

// ---------- combine init partials -> h0 (bf16), c0 (f32), gxb ----------
__global__ __launch_bounds__(256)
void init_combine_k(const float* __restrict__ part,
                    const float* __restrict__ b_ih, const float* __restrict__ b_hh,
                    const float* __restrict__ b_init_h, const float* __restrict__ b_init_c,
                    u16* __restrict__ h0b, float* __restrict__ c_cur, float* __restrict__ gxb)
{
    int idx = blockIdx.x * 256 + threadIdx.x;   // 128*3072
    int b = idx / 3072, n = idx - b * 3072;
    float s = part[idx] + part[393216 + idx] + part[2*393216 + idx] + part[3*393216 + idx];
    if (n < 512)       h0b[b*512 + n]         = f2bf(tanhf(s + b_init_h[n]));
    else if (n < 1024) c_cur[b*512 + (n-512)] = tanhf(s + b_init_c[n-512]);
    else               gxb[b*2048 + (n-1024)] = s + b_ih[n-1024] + b_hh[n-1024];
}

// ---------- bf16 MFMA GEMM (128x128 tile, 4 waves) ----------
// mtiles>0: 1D grid with bijective XCD chunking (m204), n-outer/m-inner decode.
template<int ACT, int OBF>   // ACT: 0 none, 2 relu; OBF: 1 = bf16 output
__global__ __launch_bounds__(256)
void gemm_mfma(const u16* __restrict__ A, int lda, const int* __restrict__ rowidx,
               const u16* __restrict__ W, const float* __restrict__ bias,
               const float* __restrict__ radd, int radd_div, int radd_ld,
               void* __restrict__ C, int cdiv, long csq, long csr,
               int mtiles, int N, int K)
{
    __shared__ u16 lA[4096];   // [128][32]
    __shared__ u16 lB[4096];
    int bxi, byi;
    if (mtiles > 0) {
        int nwg = gridDim.x, bid = blockIdx.x;
        int q = nwg >> 3, r = nwg & 7;
        int xcd = bid & 7, pos = bid >> 3;
        int lid = (xcd < r) ? (xcd * (q + 1) + pos)
                            : (r * (q + 1) + (xcd - r) * q + pos);
        byi = lid % mtiles;          // m-inner: same W-slice stays in this XCD's L2
        bxi = lid / mtiles;
    } else { bxi = blockIdx.x; byi = blockIdx.y; }

    const int t    = threadIdx.x;
    const int bm   = byi * 128;
    const int bn   = bxi * 128;
    const int lane = t & 63;
    const int wv   = t >> 6;
    const int wm   = (wv >> 1) * 64;
    const int wn   = (wv & 1) * 64;
    const int fr   = lane & 15;
    const int cc   = lane >> 4;

    const int q0 = t, q1 = t + 256;
    const int ra0 = q0 >> 2, ca0 = (q0 & 3) ^ ((ra0 >> 1) & 3);
    const int ra1 = q1 >> 2, ca1 = (q1 & 3) ^ ((ra1 >> 1) & 3);
    long arow0 = rowidx ? (long)rowidx[bm + ra0] : (long)(bm + ra0);
    long arow1 = rowidx ? (long)rowidx[bm + ra1] : (long)(bm + ra1);
    const u16* asrc0 = A + arow0 * lda + ca0 * 8;
    const u16* asrc1 = A + arow1 * lda + ca1 * 8;
    int brow0 = bn + ra0; if (brow0 > N - 1) brow0 = N - 1;
    int brow1 = bn + ra1; if (brow1 > N - 1) brow1 = N - 1;
    const u16* bsrc0 = W + (long)brow0 * K + ca0 * 8;
    const u16* bsrc1 = W + (long)brow1 * K + ca1 * 8;
    u16* adst0 = lA + q0 * 8;  u16* adst1 = lA + q1 * 8;
    u16* bdst0 = lB + q0 * 8;  u16* bdst1 = lB + q1 * 8;

    int aoff[4], boff[4];
    #pragma unroll
    for (int i = 0; i < 4; ++i) {
        int rA = wm + i * 16 + fr;
        aoff[i] = rA * 64 + ((cc ^ ((rA >> 1) & 3)) << 4);
        int rB = wn + i * 16 + fr;
        boff[i] = rB * 64 + ((cc ^ ((rB >> 1) & 3)) << 4);
    }
    const char* lac = (const char*)lA;
    const char* lbc = (const char*)lB;

    f32x4 acc[4][4] = {};
    for (int k0 = 0; k0 < K; k0 += 32) {
        gload16(asrc0 + k0, adst0);
        gload16(asrc1 + k0, adst1);
        gload16(bsrc0 + k0, bdst0);
        gload16(bsrc1 + k0, bdst1);
        __syncthreads();
        bfrag av[4], bv[4];
        #pragma unroll
        for (int i = 0; i < 4; ++i) av[i] = *(const bfrag*)(lac + aoff[i]);
        #pragma unroll
        for (int i = 0; i < 4; ++i) bv[i] = *(const bfrag*)(lbc + boff[i]);
        #pragma unroll
        for (int mi = 0; mi < 4; ++mi)
            #pragma unroll
            for (int ni = 0; ni < 4; ++ni)
                acc[mi][ni] = __builtin_amdgcn_mfma_f32_16x16x32_bf16(
                    av[mi], bv[ni], acc[mi][ni], 0, 0, 0);
        __syncthreads();
    }

    #pragma unroll
    for (int mi = 0; mi < 4; ++mi) {
        #pragma unroll
        for (int r = 0; r < 4; ++r) {
            int m = bm + wm + mi * 16 + (lane >> 4) * 4 + r;
            long cb = (long)(m / cdiv) * csq + (long)(m % cdiv) * csr;
            const float* rr = radd ? (radd + (long)(m / radd_div) * radd_ld) : nullptr;
            #pragma unroll
            for (int ni = 0; ni < 4; ++ni) {
                int n = bn + wn + ni * 16 + fr;
                if (n < N) {
                    float v = acc[mi][ni][r];
                    if (bias) v += bias[n];
                    if (rr)   v += rr[n];
                    if (ACT == 2) v = fmaxf(v, 0.f);
                    if (OBF) ((u16*)C)[cb + n] = f2bf(v);
                    else     ((float*)C)[cb + n] = v;
                }
            }
        }
    }
}

// ---------- persistent cooperative LSTM recurrence ----------
// 32 blocks x 256 thr. Block jb owns j-slice [jb*16, jb*16+16), all 4 gates.
// W_hh rows {g*512 + jb*16 + jj} packed ONCE into LDS frag-stream (64 KB, conflict-free
// ds_read_b128). h: bf16 B-frags loaded global->VGPR each step. c: fp32 in registers
// for all 35 steps. Gates i,f,g,o for one (b,j) land in the SAME lane (gate=mi,
// jj=cc*4+rr, b=ni*16+fr) -> fused elementwise with zero cross-lane traffic.
__global__ __launch_bounds__(256, 1)
void lstm_rec_k(const u16* __restrict__ h0b, const float* __restrict__ c0,
                const float* __restrict__ Whh, const float* __restrict__ gx,
                u16* __restrict__ h_b)
{
    __shared__ bfrag Wf[4096];          // 64 KB
    const int t256 = threadIdx.x;
    const int jb   = blockIdx.x;        // 0..31
    const int lane = t256 & 63;
    const int w    = t256 >> 6;         // wave -> batch slice w*32
    const int fr   = lane & 15;
    const int cc   = lane >> 4;

    // ---- one-time: pack W_hh (fp32) into LDS bf16 frag-stream ----
    // quad(flat) = (r, kg): r=0..63 (mi=gate=r>>4, jj=r&15), kg=0..63 (8-col group)
    // frag slot = (kk*4+mi)*64 + c2*16 + jj, kk=kg>>2, c2=kg&3
    for (int q = 0; q < 16; ++q) {
        int flat = t256 + q * 256;
        int r = flat >> 6, kg = flat & 63;
        int mi = r >> 4, jj = r & 15;
        int kk = kg >> 2, c2 = kg & 3;
        const float* src = Whh + (long)(mi * 512 + jb * 16 + jj) * 512 + kg * 8;
        float4 s0 = *(const float4*)src;
        float4 s1 = *(const float4*)(src + 4);
        bfrag p;
        p[0] = (short)f2bf(s0.x); p[1] = (short)f2bf(s0.y);
        p[2] = (short)f2bf(s0.z); p[3] = (short)f2bf(s0.w);
        p[4] = (short)f2bf(s1.x); p[5] = (short)f2bf(s1.y);
        p[6] = (short)f2bf(s1.z); p[7] = (short)f2bf(s1.w);
        Wf[(kk * 4 + mi) * 64 + c2 * 16 + jj] = p;
    }

    // ---- persistent c registers: c[b = w*32+ni*16+fr][j = jb*16+cc*4+rr] ----
    f32x4 creg[2];
    #pragma unroll
    for (int ni = 0; ni < 2; ++ni)
        creg[ni] = *(const f32x4*)(c0 + (long)(w*32 + ni*16 + fr) * 512 + jb*16 + cc*4);

    __syncthreads();

    cg::grid_group grid = cg::this_grid();
    const u16* hsrc = h0b;

    for (int t = 0; t < TB; ++t) {
        // h B-frags: hreg[ni][kk] = h[b][kk*32 + cc*8 .. +8]
        bfrag hreg[2][16];
        #pragma unroll
        for (int ni = 0; ni < 2; ++ni) {
            const u16* hp = hsrc + (long)(w*32 + ni*16 + fr) * 512 + cc * 8;
            #pragma unroll
            for (int kk = 0; kk < 16; ++kk)
                hreg[ni][kk] = *(const bfrag*)(hp + kk * 32);
        }
        // gx prefetch: gxv[gate][ni]
        f32x4 gxv[4][2];
        #pragma unroll
        for (int ni = 0; ni < 2; ++ni) {
            long row = (long)(w*32 + ni*16 + fr) * TB + t;
            const float* gp = gx + row * G4 + jb * 16 + cc * 4;
            #pragma unroll
            for (int g = 0; g < 4; ++g) gxv[g][ni] = *(const f32x4*)(gp + g * 512);
        }

        f32x4 acc[4][2] = {};
        #pragma unroll
        for (int kk = 0; kk < 16; ++kk) {
            bfrag av0 = Wf[(kk*4 + 0) * 64 + lane];
            bfrag av1 = Wf[(kk*4 + 1) * 64 + lane];
            bfrag av2 = Wf[(kk*4 + 2) * 64 + lane];
            bfrag av3 = Wf[(kk*4 + 3) * 64 + lane];
            #pragma unroll
            for (int ni = 0; ni < 2; ++ni) {
                acc[0][ni] = __builtin_amdgcn_mfma_f32_16x16x32_bf16(av0, hreg[ni][kk], acc[0][ni], 0,0,0);
                acc[1][ni] = __builtin_amdgcn_mfma_f32_16x16x32_bf16(av1, hreg[ni][kk], acc[1][ni], 0,0,0);
                acc[2][ni] = __builtin_amdgcn_mfma_f32_16x16x32_bf16(av2, hreg[ni][kk], acc[2][ni], 0,0,0);
                acc[3][ni] = __builtin_amdgcn_mfma_f32_16x16x32_bf16(av3, hreg[ni][kk], acc[3][ni], 0,0,0);
            }
        }

        // fused gates -> c,h ; write h (bf16)
        #pragma unroll
        for (int ni = 0; ni < 2; ++ni) {
            ushort4 hw;
            u16* hv = (u16*)&hw;
            #pragma unroll
            for (int rr = 0; rr < 4; ++rr) {
                float ig = fast_sig (acc[0][ni][rr] + gxv[0][ni][rr]);
                float fg = fast_sig (acc[1][ni][rr] + gxv[1][ni][rr]);
                float gg = fast_tanh(acc[2][ni][rr] + gxv[2][ni][rr]);
                float og = fast_sig (acc[3][ni][rr] + gxv[3][ni][rr]);
                float c  = fg * creg[ni][rr] + ig * gg;
                creg[ni][rr] = c;
                hv[rr] = f2bf(og * fast_tanh(c));
            }
            *(ushort4*)(h_b + (long)t * (BB*HH) + (long)(w*32 + ni*16 + fr) * 512
                        + jb * 16 + cc * 4) = hw;
        }
        hsrc = h_b + (long)t * (BB*HH);
        if (t < TB - 1) {
            __threadfence();
            grid.sync();
            __threadfence();
        }
    }
}

extern "C" void kernel_launch(void* const* d_in, const int* in_sizes, int n_in,
                              void* d_out, int out_size, void* d_ws, size_t ws_size,
                              hipStream_t stream)
{
    const float* img    = (const float*)d_in[0];
    const int*   seqs   = (const int*)d_in[1];
    const float* emb    = (const float*)d_in[3];
    const float* W_ih   = (const float*)d_in[4];
    const float* b_ih   = (const float*)d_in[5];
    const float* W_hh   = (const float*)d_in[6];
    const float* b_hh   = (const float*)d_in[7];
    const float* W_inh  = (const float*)d_in[8];
    const float* b_inh  = (const float*)d_in[9];
    const float* W_inc  = (const float*)d_in[10];
    const float* b_inc  = (const float*)d_in[11];
    const float* W_fc1  = (const float*)d_in[12];
    const float* b_fc1  = (const float*)d_in[13];
    const float* W_fc2  = (const float*)d_in[14];
    const float* b_fc2  = (const float*)d_in[15];
    float* out = (float*)d_out;

    float* ws    = (float*)d_ws;
    float* mf    = ws;                      // 180224
    float* c_cur = mf    + 180224;          // 65536
    float* gxb   = c_cur + 65536;           // 262144
    float* gx    = gxb   + 262144;          // 9175040  [b][t][2048] fp32
    float* ipart = gx;                      // alias (1572864 <= 9175040), dead before gx
    u16*   ub     = (u16*)(gx + 9175040);
    u16*   h_b    = ub;                     // 2293760  [t][b][512] bf16
    u16*   h0b    = h_b    + 2293760;       // 65536
    u16*   emb_b  = h0b    + 65536;         // 5120000
    u16*   wih_b  = emb_b  + 5120000;       // 1048576
    u16*   wfc1_b = wih_b  + 1048576;       // 262144
    u16*   wfc2_b = wfc1_b + 262144;        // 5120000
    u16*   o_b    = wfc2_b + 5120000;       // 2293760

    // weight / embedding casts to bf16
    cast512_k<<<5000, 256, 0, stream>>>(emb,   512,  emb_b,  1280000);
    cast512_k<<<1024, 256, 0, stream>>>(W_ih,  1920, wih_b,   262144);
    cast512_k<<< 256, 256, 0, stream>>>(W_fc1, 512,  wfc1_b,   65536);
    cast512_k<<<5000, 256, 0, stream>>>(W_fc2, 512,  wfc2_b, 1280000);

    mean_k<<<704, 256, 0, stream>>>(img, mf);
    init_partial_k<<<dim3(48, 2, 4), 256, 0, stream>>>(mf, W_inh, W_inc, W_ih, ipart);
    init_combine_k<<<1536, 256, 0, stream>>>(ipart, b_ih, b_hh, b_inh, b_inc,
                                             h0b, c_cur, gxb);

    // gx[(b*T+t)][n] = emb_b[seq[b][t]] . wih_b[n] + gxb[b][n]  (XCD-chunked 1D grid)
    gemm_mfma<0,0><<<dim3(16 * 35), 256, 0, stream>>>(emb_b, EE, seqs, wih_b, nullptr,
                                                      gxb, TB, G4, gx, 1 << 30, 0, G4,
                                                      35, G4, EE);

    // whole recurrence: ONE cooperative kernel, 35 grid.sync()s
    {
        void* args[] = {(void*)&h0b, (void*)&c_cur, (void*)&W_hh, (void*)&gx, (void*)&h_b};
        hipLaunchCooperativeKernel((void*)lstm_rec_k, dim3(32), dim3(256), args, 0, stream);
    }

    // o_b = relu(h_b @ W_fc1^T + b_fc1), bf16, rows m=(t*128+b)
    gemm_mfma<2,1><<<dim3(4, 35), 256, 0, stream>>>(h_b, HH, nullptr, wfc1_b, b_fc1,
                                                    nullptr, 1, 0, o_b, 1 << 30, 0, HH,
                                                    0, HH, HH);
    // logits: row m=(t*128+b) -> out[b][t][:]  (XCD-chunked 1D grid, n-outer)
    gemm_mfma<0,0><<<dim3(79 * 35), 256, 0, stream>>>(o_b, HH, nullptr, wfc2_b, b_fc2,
                                                      nullptr, 1, 0, out, BB, VV,
                                                      (long)TB * VV, 35, VV, HH);
}

// Round 5
// 576.587 us; speedup vs baseline: 5.0451x; 1.4586x over previous
//
#include <hip/hip_runtime.h>

#define TB 35
#define BB 128
#define VV 10000
#define FF 1408
#define EE 512
#define HH 512
#define G4 2048   // 4*H
#define NBLK 32   // recurrence blocks

typedef unsigned short u16;
typedef unsigned long long u64;
typedef __attribute__((ext_vector_type(8))) short bfrag;   // 8 bf16 = 4 VGPR
typedef __attribute__((ext_vector_type(4))) float f32x4;

__device__ __forceinline__ u16 f2bf(float f) {             // RNE f32->bf16
    unsigned u = __float_as_uint(f);
    return (u16)((u + 0x7FFFu + ((u >> 16) & 1u)) >> 16);
}
__device__ __forceinline__ float fast_sig(float x) {
    return __builtin_amdgcn_rcpf(1.f + __expf(-x));
}
__device__ __forceinline__ float fast_tanh(float x) {
    return 1.f - 2.f * __builtin_amdgcn_rcpf(1.f + __expf(2.f * x));
}

__device__ __forceinline__ void gload16(const void* g, void* l) {
    __builtin_amdgcn_global_load_lds(
        (const __attribute__((address_space(1))) void*)g,
        (__attribute__((address_space(3))) void*)l, 16, 0, 0);
}

// ---------- mean over R=81 regions ----------
__global__ __launch_bounds__(256)
void mean_k(const float* __restrict__ img, float* __restrict__ mf) {
    int idx = blockIdx.x * 256 + threadIdx.x;      // B*F = 180224
    int b = idx / FF, f = idx - b * FF;
    const float* p = img + (long)b * (81 * FF) + f;
    float s = 0.f;
    for (int r = 0; r < 81; ++r) s += p[r * FF];
    mf[idx] = s * (1.f / 81.f);
}

// ---------- fp32 -> bf16 cast (row length 512, vector-4) ----------
__global__ __launch_bounds__(256)
void cast512_k(const float* __restrict__ src, int lds, u16* __restrict__ dst, int n4) {
    int i = blockIdx.x * 256 + threadIdx.x;
    if (i >= n4) return;
    long e = (long)i * 4;
    long row = e >> 9; int col = (int)(e & 511);
    float4 v = *(const float4*)(src + row * lds + col);
    uint2 o;
    o.x = (unsigned)f2bf(v.x) | ((unsigned)f2bf(v.y) << 16);
    o.y = (unsigned)f2bf(v.z) | ((unsigned)f2bf(v.w) << 16);
    *(uint2*)(dst + e) = o;
}

// ---------- init partial GEMM (fp32): mf(128x1408) x {W_init_h|W_init_c|W_ih[:,E:]}^T ----------
__global__ __launch_bounds__(256)
void init_partial_k(const float* __restrict__ mf,
                    const float* __restrict__ Wh, const float* __restrict__ Wc,
                    const float* __restrict__ Wih,
                    float* __restrict__ part)
{
    __shared__ float As[16][68];
    __shared__ float Ws[16][68];
    const int t  = threadIdx.x;
    const int bx = blockIdx.x;              // 0..47
    const int bm = blockIdx.y * 64;
    const int kz = blockIdx.z;              // 0..3
    const float* W; int ldw; long wr0;
    if (bx < 8)       { W = Wh;       ldw = FF;   wr0 = (long)bx * 64; }
    else if (bx < 16) { W = Wc;       ldw = FF;   wr0 = (long)(bx - 8) * 64; }
    else              { W = Wih + EE; ldw = 1920; wr0 = (long)(bx - 16) * 64; }
    const int lrow = t >> 2, lc4 = (t & 3) << 2;
    const int ty = t >> 4, tx = t & 15;
    const float* arow = mf + (long)(bm + lrow) * FF;
    const float* wrow = W + (wr0 + lrow) * (long)ldw;
    float acc[4][4] = {};
    const int kbeg = kz * 352, kend2 = kbeg + 352;
    for (int k0 = kbeg; k0 < kend2; k0 += 16) {
        float4 av = *(const float4*)(arow + k0 + lc4);
        float4 wv = *(const float4*)(wrow + k0 + lc4);
        As[lc4+0][lrow]=av.x; As[lc4+1][lrow]=av.y; As[lc4+2][lrow]=av.z; As[lc4+3][lrow]=av.w;
        Ws[lc4+0][lrow]=wv.x; Ws[lc4+1][lrow]=wv.y; Ws[lc4+2][lrow]=wv.z; Ws[lc4+3][lrow]=wv.w;
        __syncthreads();
        #pragma unroll
        for (int kk = 0; kk < 16; ++kk) {
            float4 a = *(const float4*)&As[kk][ty*4];
            float4 w = *(const float4*)&Ws[kk][tx*4];
            acc[0][0]+=a.x*w.x; acc[0][1]+=a.x*w.y; acc[0][2]+=a.x*w.z; acc[0][3]+=a.x*w.w;
            acc[1][0]+=a.y*w.x; acc[1][1]+=a.y*w.y; acc[1][2]+=a.y*w.z; acc[1][3]+=a.y*w.w;
            acc[2][0]+=a.z*w.x; acc[2][1]+=a.z*w.y; acc[2][2]+=a.z*w.z; acc[2][3]+=a.z*w.w;
            acc[3][0]+=a.w*w.x; acc[3][1]+=a.w*w.y; acc[3][2]+=a.w*w.z; acc[3][3]+=a.w*w.w;
        }
        __syncthreads();
    }
    const int ncol = bx * 64;
    #pragma unroll
    for (int i = 0; i < 4; ++i) {
        long base = (long)kz * (BB*3072) + (long)(bm + ty*4 + i) * 3072 + ncol + tx*4;
        *(float4*)(part + base) = make_float4(acc[i][0], acc[i][1], acc[i][2], acc[i][3]);
    }
}

// ---------- combine init partials -> h0 (bf16), c0 (f32), gxb; zero barrier ctrs ----------
__global__ __launch_bounds__(256)
void init_combine_k(const float* __restrict__ part,
                    const float* __restrict__ b_ih, const float* __restrict__ b_hh,
                    const float* __restrict__ b_init_h, const float* __restrict__ b_init_c,
                    u16* __restrict__ h0b, float* __restrict__ c_cur, float* __restrict__ gxb,
                    unsigned* __restrict__ bar)
{
    int idx = blockIdx.x * 256 + threadIdx.x;   // 128*3072
    if (idx < 1024) bar[idx] = 0;               // FIX: covers all 35*16 counters (was <560 on 256 thr)
    int b = idx / 3072, n = idx - b * 3072;
    float s = part[idx] + part[393216 + idx] + part[2*393216 + idx] + part[3*393216 + idx];
    if (n < 512)       h0b[b*512 + n]         = f2bf(tanhf(s + b_init_h[n]));
    else if (n < 1024) c_cur[b*512 + (n-512)] = tanhf(s + b_init_c[n-512]);
    else               gxb[b*2048 + (n-1024)] = s + b_ih[n-1024] + b_hh[n-1024];
}

// ---------- bf16 MFMA GEMM (128x128 tile, 4 waves) ----------
// mtiles>0: 1D grid with bijective XCD chunking (m204), n-outer/m-inner decode.
template<int ACT, int OBF>   // ACT: 0 none, 2 relu; OBF: 1 = bf16 output
__global__ __launch_bounds__(256)
void gemm_mfma(const u16* __restrict__ A, int lda, const int* __restrict__ rowidx,
               const u16* __restrict__ W, const float* __restrict__ bias,
               const float* __restrict__ radd, int radd_div, int radd_ld,
               void* __restrict__ C, int cdiv, long csq, long csr,
               int mtiles, int N, int K)
{
    __shared__ u16 lA[4096];   // [128][32]
    __shared__ u16 lB[4096];
    int bxi, byi;
    if (mtiles > 0) {
        int nwg = gridDim.x, bid = blockIdx.x;
        int q = nwg >> 3, r = nwg & 7;
        int xcd = bid & 7, pos = bid >> 3;
        int lid = (xcd < r) ? (xcd * (q + 1) + pos)
                            : (r * (q + 1) + (xcd - r) * q + pos);
        byi = lid % mtiles;          // m-inner: same W-slice stays in this XCD's L2
        bxi = lid / mtiles;
    } else { bxi = blockIdx.x; byi = blockIdx.y; }

    const int t    = threadIdx.x;
    const int bm   = byi * 128;
    const int bn   = bxi * 128;
    const int lane = t & 63;
    const int wv   = t >> 6;
    const int wm   = (wv >> 1) * 64;
    const int wn   = (wv & 1) * 64;
    const int fr   = lane & 15;
    const int cc   = lane >> 4;

    const int q0 = t, q1 = t + 256;
    const int ra0 = q0 >> 2, ca0 = (q0 & 3) ^ ((ra0 >> 1) & 3);
    const int ra1 = q1 >> 2, ca1 = (q1 & 3) ^ ((ra1 >> 1) & 3);
    long arow0 = rowidx ? (long)rowidx[bm + ra0] : (long)(bm + ra0);
    long arow1 = rowidx ? (long)rowidx[bm + ra1] : (long)(bm + ra1);
    const u16* asrc0 = A + arow0 * lda + ca0 * 8;
    const u16* asrc1 = A + arow1 * lda + ca1 * 8;
    int brow0 = bn + ra0; if (brow0 > N - 1) brow0 = N - 1;
    int brow1 = bn + ra1; if (brow1 > N - 1) brow1 = N - 1;
    const u16* bsrc0 = W + (long)brow0 * K + ca0 * 8;
    const u16* bsrc1 = W + (long)brow1 * K + ca1 * 8;
    u16* adst0 = lA + q0 * 8;  u16* adst1 = lA + q1 * 8;
    u16* bdst0 = lB + q0 * 8;  u16* bdst1 = lB + q1 * 8;

    int aoff[4], boff[4];
    #pragma unroll
    for (int i = 0; i < 4; ++i) {
        int rA = wm + i * 16 + fr;
        aoff[i] = rA * 64 + ((cc ^ ((rA >> 1) & 3)) << 4);
        int rB = wn + i * 16 + fr;
        boff[i] = rB * 64 + ((cc ^ ((rB >> 1) & 3)) << 4);
    }
    const char* lac = (const char*)lA;
    const char* lbc = (const char*)lB;

    f32x4 acc[4][4] = {};
    for (int k0 = 0; k0 < K; k0 += 32) {
        gload16(asrc0 + k0, adst0);
        gload16(asrc1 + k0, adst1);
        gload16(bsrc0 + k0, bdst0);
        gload16(bsrc1 + k0, bdst1);
        __syncthreads();
        bfrag av[4], bv[4];
        #pragma unroll
        for (int i = 0; i < 4; ++i) av[i] = *(const bfrag*)(lac + aoff[i]);
        #pragma unroll
        for (int i = 0; i < 4; ++i) bv[i] = *(const bfrag*)(lbc + boff[i]);
        #pragma unroll
        for (int mi = 0; mi < 4; ++mi)
            #pragma unroll
            for (int ni = 0; ni < 4; ++ni)
                acc[mi][ni] = __builtin_amdgcn_mfma_f32_16x16x32_bf16(
                    av[mi], bv[ni], acc[mi][ni], 0, 0, 0);
        __syncthreads();
    }

    #pragma unroll
    for (int mi = 0; mi < 4; ++mi) {
        #pragma unroll
        for (int r = 0; r < 4; ++r) {
            int m = bm + wm + mi * 16 + (lane >> 4) * 4 + r;
            long cb = (long)(m / cdiv) * csq + (long)(m % cdiv) * csr;
            const float* rr = radd ? (radd + (long)(m / radd_div) * radd_ld) : nullptr;
            #pragma unroll
            for (int ni = 0; ni < 4; ++ni) {
                int n = bn + wn + ni * 16 + fr;
                if (n < N) {
                    float v = acc[mi][ni][r];
                    if (bias) v += bias[n];
                    if (rr)   v += rr[n];
                    if (ACT == 2) v = fmaxf(v, 0.f);
                    if (OBF) ((u16*)C)[cb + n] = f2bf(v);
                    else     ((float*)C)[cb + n] = v;
                }
            }
        }
    }
}

// ---------- persistent LSTM recurrence with lightweight fine-grained barrier ----------
// 32 blocks x 256 thr. Block jb owns j-slice [jb*16, jb*16+16), all 4 gates; W_hh in
// LDS (packed once). c in registers. h exchanged via agent-scope write-through stores
// (no L2 writeback!): __syncthreads drains vmcnt -> relaxed atomic arrive -> spin ->
// acquire fence (buffer_inv only). gx for t+1 prefetched before the barrier.
__global__ __launch_bounds__(256, 1)
void lstm_rec_k(const u16* __restrict__ h0b, const float* __restrict__ c0,
                const float* __restrict__ Whh, const float* __restrict__ gx,
                u16* __restrict__ h_b, unsigned* __restrict__ bar)
{
    __shared__ bfrag Wf[4096];          // 64 KB
    const int t256 = threadIdx.x;
    const int jb   = blockIdx.x;        // 0..31
    const int lane = t256 & 63;
    const int w    = t256 >> 6;         // wave -> batch slice w*32
    const int fr   = lane & 15;
    const int cc   = lane >> 4;

    // one-time: pack W_hh (fp32) into LDS bf16 frag-stream
    for (int q = 0; q < 16; ++q) {
        int flat = t256 + q * 256;
        int r = flat >> 6, kg = flat & 63;
        int mi = r >> 4, jj = r & 15;
        int kk = kg >> 2, c2 = kg & 3;
        const float* src = Whh + (long)(mi * 512 + jb * 16 + jj) * 512 + kg * 8;
        float4 s0 = *(const float4*)src;
        float4 s1 = *(const float4*)(src + 4);
        bfrag p;
        p[0] = (short)f2bf(s0.x); p[1] = (short)f2bf(s0.y);
        p[2] = (short)f2bf(s0.z); p[3] = (short)f2bf(s0.w);
        p[4] = (short)f2bf(s1.x); p[5] = (short)f2bf(s1.y);
        p[6] = (short)f2bf(s1.z); p[7] = (short)f2bf(s1.w);
        Wf[(kk * 4 + mi) * 64 + c2 * 16 + jj] = p;
    }

    const int b0   = w * 32 + fr;       // batch row (ni adds 16)
    const int jcol = jb * 16 + cc * 4;  // j column of this lane's outputs

    f32x4 creg[2];
    #pragma unroll
    for (int ni = 0; ni < 2; ++ni)
        creg[ni] = *(const f32x4*)(c0 + (long)(b0 + ni*16) * 512 + jcol);

    // gx for t=0 (layout [t][b][2048])
    f32x4 gxc[4][2];
    #pragma unroll
    for (int ni = 0; ni < 2; ++ni) {
        const float* gp = gx + (long)(b0 + ni*16) * G4 + jcol;
        #pragma unroll
        for (int g = 0; g < 4; ++g) gxc[g][ni] = *(const f32x4*)(gp + g * 512);
    }

    __syncthreads();

    const u16* hsrc = h0b;
    for (int t = 0; t < TB; ++t) {
        // h B-frags (plain vector loads; caches were invalidated by acquire fence)
        bfrag hreg[2][16];
        #pragma unroll
        for (int ni = 0; ni < 2; ++ni) {
            const u16* hp = hsrc + (long)(b0 + ni*16) * 512 + cc * 8;
            #pragma unroll
            for (int kk = 0; kk < 16; ++kk)
                hreg[ni][kk] = *(const bfrag*)(hp + kk * 32);
        }

        f32x4 acc[4][2] = {};
        #pragma unroll
        for (int kk = 0; kk < 16; ++kk) {
            bfrag av0 = Wf[(kk*4 + 0) * 64 + lane];
            bfrag av1 = Wf[(kk*4 + 1) * 64 + lane];
            bfrag av2 = Wf[(kk*4 + 2) * 64 + lane];
            bfrag av3 = Wf[(kk*4 + 3) * 64 + lane];
            #pragma unroll
            for (int ni = 0; ni < 2; ++ni) {
                acc[0][ni] = __builtin_amdgcn_mfma_f32_16x16x32_bf16(av0, hreg[ni][kk], acc[0][ni], 0,0,0);
                acc[1][ni] = __builtin_amdgcn_mfma_f32_16x16x32_bf16(av1, hreg[ni][kk], acc[1][ni], 0,0,0);
                acc[2][ni] = __builtin_amdgcn_mfma_f32_16x16x32_bf16(av2, hreg[ni][kk], acc[2][ni], 0,0,0);
                acc[3][ni] = __builtin_amdgcn_mfma_f32_16x16x32_bf16(av3, hreg[ni][kk], acc[3][ni], 0,0,0);
            }
        }

        // gates -> c,h ; h written as agent-scope write-through u64 (no L2 dirty lines)
        u16* hd = h_b + (long)t * (BB*HH);
        #pragma unroll
        for (int ni = 0; ni < 2; ++ni) {
            u64 hq = 0;
            #pragma unroll
            for (int rr = 0; rr < 4; ++rr) {
                float ig = fast_sig (acc[0][ni][rr] + gxc[0][ni][rr]);
                float fg = fast_sig (acc[1][ni][rr] + gxc[1][ni][rr]);
                float gg = fast_tanh(acc[2][ni][rr] + gxc[2][ni][rr]);
                float og = fast_sig (acc[3][ni][rr] + gxc[3][ni][rr]);
                float c  = fg * creg[ni][rr] + ig * gg;
                creg[ni][rr] = c;
                hq |= (u64)f2bf(og * fast_tanh(c)) << (rr * 16);
            }
            __hip_atomic_store((u64*)(hd + (long)(b0 + ni*16) * 512 + jcol), hq,
                               __ATOMIC_RELAXED, __HIP_MEMORY_SCOPE_AGENT);
        }
        hsrc = hd;

        if (t < TB - 1) {
            // prefetch next step's gx BEFORE the barrier (latency hides under spin)
            f32x4 gxn[4][2];
            #pragma unroll
            for (int ni = 0; ni < 2; ++ni) {
                const float* gp = gx + ((long)(t+1) * BB + b0 + ni*16) * G4 + jcol;
                #pragma unroll
                for (int g = 0; g < 4; ++g) gxn[g][ni] = *(const f32x4*)(gp + g * 512);
            }
            __syncthreads();            // drains vmcnt per wave -> h stores visible
            if (t256 == 0) {
                unsigned* ctr = bar + t * 16;
                __hip_atomic_fetch_add(ctr, 1u, __ATOMIC_RELAXED, __HIP_MEMORY_SCOPE_AGENT);
                while (__hip_atomic_load(ctr, __ATOMIC_RELAXED, __HIP_MEMORY_SCOPE_AGENT) < NBLK)
                    __builtin_amdgcn_s_sleep(2);
            }
            __syncthreads();
            __builtin_amdgcn_fence(__ATOMIC_ACQUIRE, "agent");  // inv L1/L2, no writeback
            #pragma unroll
            for (int g = 0; g < 4; ++g)
                #pragma unroll
                for (int ni = 0; ni < 2; ++ni) gxc[g][ni] = gxn[g][ni];
        }
    }
}

extern "C" void kernel_launch(void* const* d_in, const int* in_sizes, int n_in,
                              void* d_out, int out_size, void* d_ws, size_t ws_size,
                              hipStream_t stream)
{
    const float* img    = (const float*)d_in[0];
    const int*   seqs   = (const int*)d_in[1];
    const float* emb    = (const float*)d_in[3];
    const float* W_ih   = (const float*)d_in[4];
    const float* b_ih   = (const float*)d_in[5];
    const float* W_hh   = (const float*)d_in[6];
    const float* b_hh   = (const float*)d_in[7];
    const float* W_inh  = (const float*)d_in[8];
    const float* b_inh  = (const float*)d_in[9];
    const float* W_inc  = (const float*)d_in[10];
    const float* b_inc  = (const float*)d_in[11];
    const float* W_fc1  = (const float*)d_in[12];
    const float* b_fc1  = (const float*)d_in[13];
    const float* W_fc2  = (const float*)d_in[14];
    const float* b_fc2  = (const float*)d_in[15];
    float* out = (float*)d_out;

    float*    ws  = (float*)d_ws;
    unsigned* bar = (unsigned*)ws;          // 1024 reserved, 35*16 used
    float* mf    = ws    + 1024;            // 180224
    float* c_cur = mf    + 180224;          // 65536
    float* gxb   = c_cur + 65536;           // 262144
    float* gx    = gxb   + 262144;          // 9175040  [t][b][2048] fp32
    float* ipart = gx;                      // alias (1572864 <= 9175040), dead before gx
    u16*   h_b    = (u16*)(gx + 9175040);   // 2293760  [t][b][512] bf16
    u16*   h0b    = h_b    + 2293760;       // 65536
    u16*   emb_b  = h0b    + 65536;         // 5120000
    u16*   wih_b  = emb_b  + 5120000;       // 1048576
    u16*   wfc1_b = wih_b  + 1048576;       // 262144
    u16*   wfc2_b = wfc1_b + 262144;        // 5120000
    u16*   o_b    = wfc2_b + 5120000;       // 2293760

    // weight / embedding casts to bf16
    cast512_k<<<5000, 256, 0, stream>>>(emb,   512,  emb_b,  1280000);
    cast512_k<<<1024, 256, 0, stream>>>(W_ih,  1920, wih_b,   262144);
    cast512_k<<< 256, 256, 0, stream>>>(W_fc1, 512,  wfc1_b,   65536);
    cast512_k<<<5000, 256, 0, stream>>>(W_fc2, 512,  wfc2_b, 1280000);

    mean_k<<<704, 256, 0, stream>>>(img, mf);
    init_partial_k<<<dim3(48, 2, 4), 256, 0, stream>>>(mf, W_inh, W_inc, W_ih, ipart);
    init_combine_k<<<1536, 256, 0, stream>>>(ipart, b_ih, b_hh, b_inh, b_inc,
                                             h0b, c_cur, gxb, bar);

    // gx[t][b][n] = emb_b[seq[b][t]] . wih_b[n] + gxb[b][n]
    // row m = b*T + t  ->  offset (m/T)*G4 + (m%T)*(BB*G4)
    gemm_mfma<0,0><<<dim3(16 * 35), 256, 0, stream>>>(emb_b, EE, seqs, wih_b, nullptr,
                                                      gxb, TB, G4, gx, TB, G4,
                                                      (long)BB * G4, 35, G4, EE);

    // whole recurrence: ONE cooperative-style persistent kernel, custom barriers
    {
        void* args[] = {(void*)&h0b, (void*)&c_cur, (void*)&W_hh, (void*)&gx,
                        (void*)&h_b, (void*)&bar};
        hipLaunchCooperativeKernel((void*)lstm_rec_k, dim3(NBLK), dim3(256), args, 0, stream);
    }

    // o_b = relu(h_b @ W_fc1^T + b_fc1), bf16, rows m=(t*128+b)
    gemm_mfma<2,1><<<dim3(4, 35), 256, 0, stream>>>(h_b, HH, nullptr, wfc1_b, b_fc1,
                                                    nullptr, 1, 0, o_b, 1 << 30, 0, HH,
                                                    0, HH, HH);
    // logits: row m=(t*128+b) -> out[b][t][:]  (XCD-chunked 1D grid, n-outer)
    gemm_mfma<0,0><<<dim3(79 * 35), 256, 0, stream>>>(o_b, HH, nullptr, wfc2_b, b_fc2,
                                                      nullptr, 1, 0, out, BB, VV,
                                                      (long)TB * VV, 35, VV, HH);
}

// Round 8
// 557.375 us; speedup vs baseline: 5.2190x; 1.0345x over previous
//
#include <hip/hip_runtime.h>

#define TB 35
#define BB 128
#define VV 10000
#define FF 1408
#define EE 512
#define HH 512
#define G4 2048   // 4*H
#define NBLK 32   // recurrence blocks

typedef unsigned short u16;
typedef unsigned long long u64;
typedef __attribute__((ext_vector_type(8))) short bfrag;   // 8 bf16 = 4 VGPR
typedef __attribute__((ext_vector_type(4))) float f32x4;

__device__ __forceinline__ u16 f2bf(float f) {             // RNE f32->bf16
    unsigned u = __float_as_uint(f);
    return (u16)((u + 0x7FFFu + ((u >> 16) & 1u)) >> 16);
}
__device__ __forceinline__ float fast_sig(float x) {
    return __builtin_amdgcn_rcpf(1.f + __expf(-x));
}
__device__ __forceinline__ float fast_tanh(float x) {
    return 1.f - 2.f * __builtin_amdgcn_rcpf(1.f + __expf(2.f * x));
}

__device__ __forceinline__ void gload16(const void* g, void* l) {
    __builtin_amdgcn_global_load_lds(
        (const __attribute__((address_space(1))) void*)g,
        (__attribute__((address_space(3))) void*)l, 16, 0, 0);
}

// ---------- mean over R=81 regions ----------
__global__ __launch_bounds__(256)
void mean_k(const float* __restrict__ img, float* __restrict__ mf) {
    int idx = blockIdx.x * 256 + threadIdx.x;      // B*F = 180224
    int b = idx / FF, f = idx - b * FF;
    const float* p = img + (long)b * (81 * FF) + f;
    float s = 0.f;
    for (int r = 0; r < 81; ++r) s += p[r * FF];
    mf[idx] = s * (1.f / 81.f);
}

// ---------- fp32 -> bf16 cast (row length 512, vector-4) ----------
__global__ __launch_bounds__(256)
void cast512_k(const float* __restrict__ src, int lds, u16* __restrict__ dst, int n4) {
    int i = blockIdx.x * 256 + threadIdx.x;
    if (i >= n4) return;
    long e = (long)i * 4;
    long row = e >> 9; int col = (int)(e & 511);
    float4 v = *(const float4*)(src + row * lds + col);
    uint2 o;
    o.x = (unsigned)f2bf(v.x) | ((unsigned)f2bf(v.y) << 16);
    o.y = (unsigned)f2bf(v.z) | ((unsigned)f2bf(v.w) << 16);
    *(uint2*)(dst + e) = o;
}

// ---------- init partial GEMM (fp32): mf(128x1408) x {W_init_h|W_init_c|W_ih[:,E:]}^T ----------
__global__ __launch_bounds__(256)
void init_partial_k(const float* __restrict__ mf,
                    const float* __restrict__ Wh, const float* __restrict__ Wc,
                    const float* __restrict__ Wih,
                    float* __restrict__ part)
{
    __shared__ float As[16][68];
    __shared__ float Ws[16][68];
    const int t  = threadIdx.x;
    const int bx = blockIdx.x;              // 0..47
    const int bm = blockIdx.y * 64;
    const int kz = blockIdx.z;              // 0..3
    const float* W; int ldw; long wr0;
    if (bx < 8)       { W = Wh;       ldw = FF;   wr0 = (long)bx * 64; }
    else if (bx < 16) { W = Wc;       ldw = FF;   wr0 = (long)(bx - 8) * 64; }
    else              { W = Wih + EE; ldw = 1920; wr0 = (long)(bx - 16) * 64; }
    const int lrow = t >> 2, lc4 = (t & 3) << 2;
    const int ty = t >> 4, tx = t & 15;
    const float* arow = mf + (long)(bm + lrow) * FF;
    const float* wrow = W + (wr0 + lrow) * (long)ldw;
    float acc[4][4] = {};
    const int kbeg = kz * 352, kend2 = kbeg + 352;
    for (int k0 = kbeg; k0 < kend2; k0 += 16) {
        float4 av = *(const float4*)(arow + k0 + lc4);
        float4 wv = *(const float4*)(wrow + k0 + lc4);
        As[lc4+0][lrow]=av.x; As[lc4+1][lrow]=av.y; As[lc4+2][lrow]=av.z; As[lc4+3][lrow]=av.w;
        Ws[lc4+0][lrow]=wv.x; Ws[lc4+1][lrow]=wv.y; Ws[lc4+2][lrow]=wv.z; Ws[lc4+3][lrow]=wv.w;
        __syncthreads();
        #pragma unroll
        for (int kk = 0; kk < 16; ++kk) {
            float4 a = *(const float4*)&As[kk][ty*4];
            float4 w = *(const float4*)&Ws[kk][tx*4];
            acc[0][0]+=a.x*w.x; acc[0][1]+=a.x*w.y; acc[0][2]+=a.x*w.z; acc[0][3]+=a.x*w.w;
            acc[1][0]+=a.y*w.x; acc[1][1]+=a.y*w.y; acc[1][2]+=a.y*w.z; acc[1][3]+=a.y*w.w;
            acc[2][0]+=a.z*w.x; acc[2][1]+=a.z*w.y; acc[2][2]+=a.z*w.z; acc[2][3]+=a.z*w.w;
            acc[3][0]+=a.w*w.x; acc[3][1]+=a.w*w.y; acc[3][2]+=a.w*w.z; acc[3][3]+=a.w*w.w;
        }
        __syncthreads();
    }
    const int ncol = bx * 64;
    #pragma unroll
    for (int i = 0; i < 4; ++i) {
        long base = (long)kz * (BB*3072) + (long)(bm + ty*4 + i) * 3072 + ncol + tx*4;
        *(float4*)(part + base) = make_float4(acc[i][0], acc[i][1], acc[i][2], acc[i][3]);
    }
}

// ---------- combine init partials -> h0 (bf16), c0 (f32), gxb; zero barrier ctrs ----------
__global__ __launch_bounds__(256)
void init_combine_k(const float* __restrict__ part,
                    const float* __restrict__ b_ih, const float* __restrict__ b_hh,
                    const float* __restrict__ b_init_h, const float* __restrict__ b_init_c,
                    u16* __restrict__ h0b, float* __restrict__ c_cur, float* __restrict__ gxb,
                    unsigned* __restrict__ bar)
{
    int idx = blockIdx.x * 256 + threadIdx.x;   // 128*3072
    if (idx < 1024) bar[idx] = 0;               // covers all 35*16 step counters
    int b = idx / 3072, n = idx - b * 3072;
    float s = part[idx] + part[393216 + idx] + part[2*393216 + idx] + part[3*393216 + idx];
    if (n < 512)       h0b[b*512 + n]         = f2bf(tanhf(s + b_init_h[n]));
    else if (n < 1024) c_cur[b*512 + (n-512)] = tanhf(s + b_init_c[n-512]);
    else               gxb[b*2048 + (n-1024)] = s + b_ih[n-1024] + b_hh[n-1024];
}

// ---------- bf16 MFMA GEMM (128x128 tile, 4 waves) ----------
// mtiles>0: 1D grid with bijective XCD chunking (m204), n-outer/m-inner decode.
template<int ACT, int OBF>   // ACT: 0 none, 2 relu; OBF: 1 = bf16 output
__global__ __launch_bounds__(256)
void gemm_mfma(const u16* __restrict__ A, int lda, const int* __restrict__ rowidx,
               const u16* __restrict__ W, const float* __restrict__ bias,
               const float* __restrict__ radd, int radd_div, int radd_ld,
               void* __restrict__ C, int cdiv, long csq, long csr,
               int mtiles, int N, int K)
{
    __shared__ u16 lA[4096];   // [128][32]
    __shared__ u16 lB[4096];
    int bxi, byi;
    if (mtiles > 0) {
        int nwg = gridDim.x, bid = blockIdx.x;
        int q = nwg >> 3, r = nwg & 7;
        int xcd = bid & 7, pos = bid >> 3;
        int lid = (xcd < r) ? (xcd * (q + 1) + pos)
                            : (r * (q + 1) + (xcd - r) * q + pos);
        byi = lid % mtiles;          // m-inner: same W-slice stays in this XCD's L2
        bxi = lid / mtiles;
    } else { bxi = blockIdx.x; byi = blockIdx.y; }

    const int t    = threadIdx.x;
    const int bm   = byi * 128;
    const int bn   = bxi * 128;
    const int lane = t & 63;
    const int wv   = t >> 6;
    const int wm   = (wv >> 1) * 64;
    const int wn   = (wv & 1) * 64;
    const int fr   = lane & 15;
    const int cc   = lane >> 4;

    const int q0 = t, q1 = t + 256;
    const int ra0 = q0 >> 2, ca0 = (q0 & 3) ^ ((ra0 >> 1) & 3);
    const int ra1 = q1 >> 2, ca1 = (q1 & 3) ^ ((ra1 >> 1) & 3);
    long arow0 = rowidx ? (long)rowidx[bm + ra0] : (long)(bm + ra0);
    long arow1 = rowidx ? (long)rowidx[bm + ra1] : (long)(bm + ra1);
    const u16* asrc0 = A + arow0 * lda + ca0 * 8;
    const u16* asrc1 = A + arow1 * lda + ca1 * 8;
    int brow0 = bn + ra0; if (brow0 > N - 1) brow0 = N - 1;
    int brow1 = bn + ra1; if (brow1 > N - 1) brow1 = N - 1;
    const u16* bsrc0 = W + (long)brow0 * K + ca0 * 8;
    const u16* bsrc1 = W + (long)brow1 * K + ca1 * 8;
    u16* adst0 = lA + q0 * 8;  u16* adst1 = lA + q1 * 8;
    u16* bdst0 = lB + q0 * 8;  u16* bdst1 = lB + q1 * 8;

    int aoff[4], boff[4];
    #pragma unroll
    for (int i = 0; i < 4; ++i) {
        int rA = wm + i * 16 + fr;
        aoff[i] = rA * 64 + ((cc ^ ((rA >> 1) & 3)) << 4);
        int rB = wn + i * 16 + fr;
        boff[i] = rB * 64 + ((cc ^ ((rB >> 1) & 3)) << 4);
    }
    const char* lac = (const char*)lA;
    const char* lbc = (const char*)lB;

    f32x4 acc[4][4] = {};
    for (int k0 = 0; k0 < K; k0 += 32) {
        gload16(asrc0 + k0, adst0);
        gload16(asrc1 + k0, adst1);
        gload16(bsrc0 + k0, bdst0);
        gload16(bsrc1 + k0, bdst1);
        __syncthreads();
        bfrag av[4], bv[4];
        #pragma unroll
        for (int i = 0; i < 4; ++i) av[i] = *(const bfrag*)(lac + aoff[i]);
        #pragma unroll
        for (int i = 0; i < 4; ++i) bv[i] = *(const bfrag*)(lbc + boff[i]);
        #pragma unroll
        for (int mi = 0; mi < 4; ++mi)
            #pragma unroll
            for (int ni = 0; ni < 4; ++ni)
                acc[mi][ni] = __builtin_amdgcn_mfma_f32_16x16x32_bf16(
                    av[mi], bv[ni], acc[mi][ni], 0, 0, 0);
        __syncthreads();
    }

    #pragma unroll
    for (int mi = 0; mi < 4; ++mi) {
        #pragma unroll
        for (int r = 0; r < 4; ++r) {
            int m = bm + wm + mi * 16 + (lane >> 4) * 4 + r;
            long cb = (long)(m / cdiv) * csq + (long)(m % cdiv) * csr;
            const float* rr = radd ? (radd + (long)(m / radd_div) * radd_ld) : nullptr;
            #pragma unroll
            for (int ni = 0; ni < 4; ++ni) {
                int n = bn + wn + ni * 16 + fr;
                if (n < N) {
                    float v = acc[mi][ni][r];
                    if (bias) v += bias[n];
                    if (rr)   v += rr[n];
                    if (ACT == 2) v = fmaxf(v, 0.f);
                    if (OBF) ((u16*)C)[cb + n] = f2bf(v);
                    else     ((float*)C)[cb + n] = v;
                }
            }
        }
    }
}

// ---------- persistent LSTM recurrence (R5 body, UNCHANGED; plain launch now) ----------
// 32 blocks x 256 thr. Block jb owns j-slice [jb*16,+16), all 4 gates; W_hh in LDS.
// c in registers; h exchanged via WT agent stores (no L2 writeback). Per step:
// gx(t+1) prefetch -> sync1 (drains vmcnt) -> t256==0: fetch_add + spin on per-step
// counter -> sync2 -> agent acquire fence (inv caches) -> next step.
__global__ __launch_bounds__(256, 1)
void lstm_rec_k(const u16* __restrict__ h0b, const float* __restrict__ c0,
                const float* __restrict__ Whh, const float* __restrict__ gx,
                u16* __restrict__ h_b, unsigned* __restrict__ bar)
{
    __shared__ bfrag Wf[4096];          // 64 KB
    const int t256 = threadIdx.x;
    const int jb   = blockIdx.x;        // 0..31
    const int lane = t256 & 63;
    const int w    = t256 >> 6;         // wave -> batch slice w*32
    const int fr   = lane & 15;
    const int cc   = lane >> 4;

    // one-time: pack W_hh (fp32) into LDS bf16 frag-stream
    for (int q = 0; q < 16; ++q) {
        int flat = t256 + q * 256;
        int r = flat >> 6, kg = flat & 63;
        int mi = r >> 4, jj = r & 15;
        int kk = kg >> 2, c2 = kg & 3;
        const float* src = Whh + (long)(mi * 512 + jb * 16 + jj) * 512 + kg * 8;
        float4 s0 = *(const float4*)src;
        float4 s1 = *(const float4*)(src + 4);
        bfrag p;
        p[0] = (short)f2bf(s0.x); p[1] = (short)f2bf(s0.y);
        p[2] = (short)f2bf(s0.z); p[3] = (short)f2bf(s0.w);
        p[4] = (short)f2bf(s1.x); p[5] = (short)f2bf(s1.y);
        p[6] = (short)f2bf(s1.z); p[7] = (short)f2bf(s1.w);
        Wf[(kk * 4 + mi) * 64 + c2 * 16 + jj] = p;
    }

    const int b0   = w * 32 + fr;       // batch row (ni adds 16)
    const int jcol = jb * 16 + cc * 4;  // j column of this lane's outputs

    f32x4 creg[2];
    #pragma unroll
    for (int ni = 0; ni < 2; ++ni)
        creg[ni] = *(const f32x4*)(c0 + (long)(b0 + ni*16) * 512 + jcol);

    // gx for t=0 (layout [t][b][2048])
    f32x4 gxc[4][2];
    #pragma unroll
    for (int ni = 0; ni < 2; ++ni) {
        const float* gp = gx + (long)(b0 + ni*16) * G4 + jcol;
        #pragma unroll
        for (int g = 0; g < 4; ++g) gxc[g][ni] = *(const f32x4*)(gp + g * 512);
    }

    __syncthreads();                    // Wf ready

    const u16* hsrc = h0b;
    for (int t = 0; t < TB; ++t) {
        // h B-frags for this step
        bfrag hreg[2][16];
        #pragma unroll
        for (int ni = 0; ni < 2; ++ni) {
            const u16* hp = hsrc + (long)(b0 + ni*16) * 512 + cc * 8;
            #pragma unroll
            for (int kk = 0; kk < 16; ++kk)
                hreg[ni][kk] = *(const bfrag*)(hp + kk * 32);
        }

        f32x4 acc[4][2] = {};
        #pragma unroll
        for (int kk = 0; kk < 16; ++kk) {
            bfrag av0 = Wf[(kk*4 + 0) * 64 + lane];
            bfrag av1 = Wf[(kk*4 + 1) * 64 + lane];
            bfrag av2 = Wf[(kk*4 + 2) * 64 + lane];
            bfrag av3 = Wf[(kk*4 + 3) * 64 + lane];
            #pragma unroll
            for (int ni = 0; ni < 2; ++ni) {
                acc[0][ni] = __builtin_amdgcn_mfma_f32_16x16x32_bf16(av0, hreg[ni][kk], acc[0][ni], 0,0,0);
                acc[1][ni] = __builtin_amdgcn_mfma_f32_16x16x32_bf16(av1, hreg[ni][kk], acc[1][ni], 0,0,0);
                acc[2][ni] = __builtin_amdgcn_mfma_f32_16x16x32_bf16(av2, hreg[ni][kk], acc[2][ni], 0,0,0);
                acc[3][ni] = __builtin_amdgcn_mfma_f32_16x16x32_bf16(av3, hreg[ni][kk], acc[3][ni], 0,0,0);
            }
        }

        // gates -> c,h ; h written write-through agent-scope (no dirty L2 lines)
        u16* hd = h_b + (long)t * (BB*HH);
        #pragma unroll
        for (int ni = 0; ni < 2; ++ni) {
            u64 hq = 0;
            #pragma unroll
            for (int rr = 0; rr < 4; ++rr) {
                float ig = fast_sig (acc[0][ni][rr] + gxc[0][ni][rr]);
                float fg = fast_sig (acc[1][ni][rr] + gxc[1][ni][rr]);
                float gg = fast_tanh(acc[2][ni][rr] + gxc[2][ni][rr]);
                float og = fast_sig (acc[3][ni][rr] + gxc[3][ni][rr]);
                float c  = fg * creg[ni][rr] + ig * gg;
                creg[ni][rr] = c;
                hq |= (u64)f2bf(og * fast_tanh(c)) << (rr * 16);
            }
            __hip_atomic_store((u64*)(hd + (long)(b0 + ni*16) * 512 + jcol), hq,
                               __ATOMIC_RELAXED, __HIP_MEMORY_SCOPE_AGENT);
        }
        hsrc = hd;

        if (t < TB - 1) {
            // prefetch next step's gx BEFORE the barrier (latency hides under spin)
            f32x4 gxn[4][2];
            #pragma unroll
            for (int ni = 0; ni < 2; ++ni) {
                const float* gp = gx + ((long)(t+1) * BB + b0 + ni*16) * G4 + jcol;
                #pragma unroll
                for (int g = 0; g < 4; ++g) gxn[g][ni] = *(const f32x4*)(gp + g * 512);
            }
            __syncthreads();            // drains vmcnt per wave -> h stores visible
            if (t256 == 0) {
                unsigned* ctr = bar + t * 16;
                __hip_atomic_fetch_add(ctr, 1u, __ATOMIC_RELAXED, __HIP_MEMORY_SCOPE_AGENT);
                while (__hip_atomic_load(ctr, __ATOMIC_RELAXED, __HIP_MEMORY_SCOPE_AGENT) < NBLK)
                    __builtin_amdgcn_s_sleep(2);
            }
            __syncthreads();
            __builtin_amdgcn_fence(__ATOMIC_ACQUIRE, "agent");  // inv caches, no wb
            #pragma unroll
            for (int g = 0; g < 4; ++g)
                #pragma unroll
                for (int ni = 0; ni < 2; ++ni) gxc[g][ni] = gxn[g][ni];
        }
    }
}

extern "C" void kernel_launch(void* const* d_in, const int* in_sizes, int n_in,
                              void* d_out, int out_size, void* d_ws, size_t ws_size,
                              hipStream_t stream)
{
    const float* img    = (const float*)d_in[0];
    const int*   seqs   = (const int*)d_in[1];
    const float* emb    = (const float*)d_in[3];
    const float* W_ih   = (const float*)d_in[4];
    const float* b_ih   = (const float*)d_in[5];
    const float* W_hh   = (const float*)d_in[6];
    const float* b_hh   = (const float*)d_in[7];
    const float* W_inh  = (const float*)d_in[8];
    const float* b_inh  = (const float*)d_in[9];
    const float* W_inc  = (const float*)d_in[10];
    const float* b_inc  = (const float*)d_in[11];
    const float* W_fc1  = (const float*)d_in[12];
    const float* b_fc1  = (const float*)d_in[13];
    const float* W_fc2  = (const float*)d_in[14];
    const float* b_fc2  = (const float*)d_in[15];
    float* out = (float*)d_out;

    float*    ws  = (float*)d_ws;
    unsigned* bar = (unsigned*)ws;          // 1024 reserved; counters bar[t*16]
    float* mf    = ws    + 1024;            // 180224
    float* c_cur = mf    + 180224;          // 65536
    float* gxb   = c_cur + 65536;           // 262144
    float* gx    = gxb   + 262144;          // 9175040  [t][b][2048] fp32
    float* ipart = gx;                      // alias (1572864 <= 9175040), dead before gx
    u16*   h_b    = (u16*)(gx + 9175040);   // 2293760  [t][b][512] bf16
    u16*   h0b    = h_b    + 2293760;       // 65536
    u16*   emb_b  = h0b    + 65536;         // 5120000
    u16*   wih_b  = emb_b  + 5120000;       // 1048576
    u16*   wfc1_b = wih_b  + 1048576;       // 262144
    u16*   wfc2_b = wfc1_b + 262144;        // 5120000
    u16*   o_b    = wfc2_b + 5120000;       // 2293760

    // weight / embedding casts to bf16
    cast512_k<<<5000, 256, 0, stream>>>(emb,   512,  emb_b,  1280000);
    cast512_k<<<1024, 256, 0, stream>>>(W_ih,  1920, wih_b,   262144);
    cast512_k<<< 256, 256, 0, stream>>>(W_fc1, 512,  wfc1_b,   65536);
    cast512_k<<<5000, 256, 0, stream>>>(W_fc2, 512,  wfc2_b, 1280000);

    mean_k<<<704, 256, 0, stream>>>(img, mf);
    init_partial_k<<<dim3(48, 2, 4), 256, 0, stream>>>(mf, W_inh, W_inc, W_ih, ipart);
    init_combine_k<<<1536, 256, 0, stream>>>(ipart, b_ih, b_hh, b_inh, b_inc,
                                             h0b, c_cur, gxb, bar);

    // gx[t][b][n] = emb_b[seq[b][t]] . wih_b[n] + gxb[b][n]
    // row m = b*T + t  ->  offset (m/T)*G4 + (m%T)*(BB*G4)
    gemm_mfma<0,0><<<dim3(16 * 35), 256, 0, stream>>>(emb_b, EE, seqs, wih_b, nullptr,
                                                      gxb, TB, G4, gx, TB, G4,
                                                      (long)BB * G4, 35, G4, EE);

    // whole recurrence: ONE persistent kernel, PLAIN launch (no cg:: usage inside;
    // 32 blocks @ 64KB LDS are trivially co-resident on 256 CUs)
    lstm_rec_k<<<dim3(NBLK), dim3(256), 0, stream>>>(h0b, c_cur, W_hh, gx, h_b, bar);

    // o_b = relu(h_b @ W_fc1^T + b_fc1), bf16, rows m=(t*128+b)
    gemm_mfma<2,1><<<dim3(4, 35), 256, 0, stream>>>(h_b, HH, nullptr, wfc1_b, b_fc1,
                                                    nullptr, 1, 0, o_b, 1 << 30, 0, HH,
                                                    0, HH, HH);
    // logits: row m=(t*128+b) -> out[b][t][:]  (XCD-chunked 1D grid, n-outer)
    gemm_mfma<0,0><<<dim3(79 * 35), 256, 0, stream>>>(o_b, HH, nullptr, wfc2_b, b_fc2,
                                                      nullptr, 1, 0, out, BB, VV,
                                                      (long)TB * VV, 35, VV, HH);
}

// Round 9
// 556.532 us; speedup vs baseline: 5.2269x; 1.0015x over previous
//
#include <hip/hip_runtime.h>

#define TB 35
#define BB 128
#define VV 10000
#define FF 1408
#define EE 512
#define HH 512
#define G4 2048   // 4*H
#define NBLK 32   // recurrence blocks

typedef unsigned short u16;
typedef unsigned long long u64;
typedef __attribute__((ext_vector_type(8))) short bfrag;   // 8 bf16 = 4 VGPR
typedef __attribute__((ext_vector_type(4))) float f32x4;

__device__ __forceinline__ u16 f2bf(float f) {             // RNE f32->bf16
    unsigned u = __float_as_uint(f);
    return (u16)((u + 0x7FFFu + ((u >> 16) & 1u)) >> 16);
}
__device__ __forceinline__ float fast_sig(float x) {
    return __builtin_amdgcn_rcpf(1.f + __expf(-x));
}
__device__ __forceinline__ float fast_tanh(float x) {
    return 1.f - 2.f * __builtin_amdgcn_rcpf(1.f + __expf(2.f * x));
}

__device__ __forceinline__ void gload16(const void* g, void* l) {
    __builtin_amdgcn_global_load_lds(
        (const __attribute__((address_space(1))) void*)g,
        (__attribute__((address_space(3))) void*)l, 16, 0, 0);
}

// ---------- mean over R=81 regions ----------
__global__ __launch_bounds__(256)
void mean_k(const float* __restrict__ img, float* __restrict__ mf) {
    int idx = blockIdx.x * 256 + threadIdx.x;      // B*F = 180224
    int b = idx / FF, f = idx - b * FF;
    const float* p = img + (long)b * (81 * FF) + f;
    float s = 0.f;
    for (int r = 0; r < 81; ++r) s += p[r * FF];
    mf[idx] = s * (1.f / 81.f);
}

// ---------- fp32 -> bf16 cast (row length 512, vector-4) ----------
__global__ __launch_bounds__(256)
void cast512_k(const float* __restrict__ src, int lds, u16* __restrict__ dst, int n4) {
    int i = blockIdx.x * 256 + threadIdx.x;
    if (i >= n4) return;
    long e = (long)i * 4;
    long row = e >> 9; int col = (int)(e & 511);
    float4 v = *(const float4*)(src + row * lds + col);
    uint2 o;
    o.x = (unsigned)f2bf(v.x) | ((unsigned)f2bf(v.y) << 16);
    o.y = (unsigned)f2bf(v.z) | ((unsigned)f2bf(v.w) << 16);
    *(uint2*)(dst + e) = o;
}

// ---------- init partial GEMM (fp32): mf(128x1408) x {W_init_h|W_init_c|W_ih[:,E:]}^T ----------
__global__ __launch_bounds__(256)
void init_partial_k(const float* __restrict__ mf,
                    const float* __restrict__ Wh, const float* __restrict__ Wc,
                    const float* __restrict__ Wih,
                    float* __restrict__ part)
{
    __shared__ float As[16][68];
    __shared__ float Ws[16][68];
    const int t  = threadIdx.x;
    const int bx = blockIdx.x;              // 0..47
    const int bm = blockIdx.y * 64;
    const int kz = blockIdx.z;              // 0..3
    const float* W; int ldw; long wr0;
    if (bx < 8)       { W = Wh;       ldw = FF;   wr0 = (long)bx * 64; }
    else if (bx < 16) { W = Wc;       ldw = FF;   wr0 = (long)(bx - 8) * 64; }
    else              { W = Wih + EE; ldw = 1920; wr0 = (long)(bx - 16) * 64; }
    const int lrow = t >> 2, lc4 = (t & 3) << 2;
    const int ty = t >> 4, tx = t & 15;
    const float* arow = mf + (long)(bm + lrow) * FF;
    const float* wrow = W + (wr0 + lrow) * (long)ldw;
    float acc[4][4] = {};
    const int kbeg = kz * 352, kend2 = kbeg + 352;
    for (int k0 = kbeg; k0 < kend2; k0 += 16) {
        float4 av = *(const float4*)(arow + k0 + lc4);
        float4 wv = *(const float4*)(wrow + k0 + lc4);
        As[lc4+0][lrow]=av.x; As[lc4+1][lrow]=av.y; As[lc4+2][lrow]=av.z; As[lc4+3][lrow]=av.w;
        Ws[lc4+0][lrow]=wv.x; Ws[lc4+1][lrow]=wv.y; Ws[lc4+2][lrow]=wv.z; Ws[lc4+3][lrow]=wv.w;
        __syncthreads();
        #pragma unroll
        for (int kk = 0; kk < 16; ++kk) {
            float4 a = *(const float4*)&As[kk][ty*4];
            float4 w = *(const float4*)&Ws[kk][tx*4];
            acc[0][0]+=a.x*w.x; acc[0][1]+=a.x*w.y; acc[0][2]+=a.x*w.z; acc[0][3]+=a.x*w.w;
            acc[1][0]+=a.y*w.x; acc[1][1]+=a.y*w.y; acc[1][2]+=a.y*w.z; acc[1][3]+=a.y*w.w;
            acc[2][0]+=a.z*w.x; acc[2][1]+=a.z*w.y; acc[2][2]+=a.z*w.z; acc[2][3]+=a.z*w.w;
            acc[3][0]+=a.w*w.x; acc[3][1]+=a.w*w.y; acc[3][2]+=a.w*w.z; acc[3][3]+=a.w*w.w;
        }
        __syncthreads();
    }
    const int ncol = bx * 64;
    #pragma unroll
    for (int i = 0; i < 4; ++i) {
        long base = (long)kz * (BB*3072) + (long)(bm + ty*4 + i) * 3072 + ncol + tx*4;
        *(float4*)(part + base) = make_float4(acc[i][0], acc[i][1], acc[i][2], acc[i][3]);
    }
}

// ---------- combine init partials -> h0 (bf16), c0 (f32), gxb; zero all flags ----------
__global__ __launch_bounds__(256)
void init_combine_k(const float* __restrict__ part,
                    const float* __restrict__ b_ih, const float* __restrict__ b_hh,
                    const float* __restrict__ b_init_h, const float* __restrict__ b_init_c,
                    u16* __restrict__ h0b, float* __restrict__ c_cur, float* __restrict__ gxb,
                    unsigned* __restrict__ bar)
{
    int idx = blockIdx.x * 256 + threadIdx.x;   // 128*3072
    if (idx < 1024) bar[idx] = 0;               // step ctrs bar[t*16], o_ctr bar[600+t]
    int b = idx / 3072, n = idx - b * 3072;
    float s = part[idx] + part[393216 + idx] + part[2*393216 + idx] + part[3*393216 + idx];
    if (n < 512)       h0b[b*512 + n]         = f2bf(tanhf(s + b_init_h[n]));
    else if (n < 1024) c_cur[b*512 + (n-512)] = tanhf(s + b_init_c[n-512]);
    else               gxb[b*2048 + (n-1024)] = s + b_ih[n-1024] + b_hh[n-1024];
}

// ---------- bf16 MFMA GEMM (128x128 tile, 4 waves) — used for gx ----------
template<int ACT, int OBF>
__global__ __launch_bounds__(256)
void gemm_mfma(const u16* __restrict__ A, int lda, const int* __restrict__ rowidx,
               const u16* __restrict__ W, const float* __restrict__ bias,
               const float* __restrict__ radd, int radd_div, int radd_ld,
               void* __restrict__ C, int cdiv, long csq, long csr,
               int mtiles, int N, int K)
{
    __shared__ u16 lA[4096];   // [128][32]
    __shared__ u16 lB[4096];
    int bxi, byi;
    if (mtiles > 0) {
        int nwg = gridDim.x, bid = blockIdx.x;
        int q = nwg >> 3, r = nwg & 7;
        int xcd = bid & 7, pos = bid >> 3;
        int lid = (xcd < r) ? (xcd * (q + 1) + pos)
                            : (r * (q + 1) + (xcd - r) * q + pos);
        byi = lid % mtiles;
        bxi = lid / mtiles;
    } else { bxi = blockIdx.x; byi = blockIdx.y; }

    const int t    = threadIdx.x;
    const int bm   = byi * 128;
    const int bn   = bxi * 128;
    const int lane = t & 63;
    const int wv   = t >> 6;
    const int wm   = (wv >> 1) * 64;
    const int wn   = (wv & 1) * 64;
    const int fr   = lane & 15;
    const int cc   = lane >> 4;

    const int q0 = t, q1 = t + 256;
    const int ra0 = q0 >> 2, ca0 = (q0 & 3) ^ ((ra0 >> 1) & 3);
    const int ra1 = q1 >> 2, ca1 = (q1 & 3) ^ ((ra1 >> 1) & 3);
    long arow0 = rowidx ? (long)rowidx[bm + ra0] : (long)(bm + ra0);
    long arow1 = rowidx ? (long)rowidx[bm + ra1] : (long)(bm + ra1);
    const u16* asrc0 = A + arow0 * lda + ca0 * 8;
    const u16* asrc1 = A + arow1 * lda + ca1 * 8;
    int brow0 = bn + ra0; if (brow0 > N - 1) brow0 = N - 1;
    int brow1 = bn + ra1; if (brow1 > N - 1) brow1 = N - 1;
    const u16* bsrc0 = W + (long)brow0 * K + ca0 * 8;
    const u16* bsrc1 = W + (long)brow1 * K + ca1 * 8;
    u16* adst0 = lA + q0 * 8;  u16* adst1 = lA + q1 * 8;
    u16* bdst0 = lB + q0 * 8;  u16* bdst1 = lB + q1 * 8;

    int aoff[4], boff[4];
    #pragma unroll
    for (int i = 0; i < 4; ++i) {
        int rA = wm + i * 16 + fr;
        aoff[i] = rA * 64 + ((cc ^ ((rA >> 1) & 3)) << 4);
        int rB = wn + i * 16 + fr;
        boff[i] = rB * 64 + ((cc ^ ((rB >> 1) & 3)) << 4);
    }
    const char* lac = (const char*)lA;
    const char* lbc = (const char*)lB;

    f32x4 acc[4][4] = {};
    for (int k0 = 0; k0 < K; k0 += 32) {
        gload16(asrc0 + k0, adst0);
        gload16(asrc1 + k0, adst1);
        gload16(bsrc0 + k0, bdst0);
        gload16(bsrc1 + k0, bdst1);
        __syncthreads();
        bfrag av[4], bv[4];
        #pragma unroll
        for (int i = 0; i < 4; ++i) av[i] = *(const bfrag*)(lac + aoff[i]);
        #pragma unroll
        for (int i = 0; i < 4; ++i) bv[i] = *(const bfrag*)(lbc + boff[i]);
        #pragma unroll
        for (int mi = 0; mi < 4; ++mi)
            #pragma unroll
            for (int ni = 0; ni < 4; ++ni)
                acc[mi][ni] = __builtin_amdgcn_mfma_f32_16x16x32_bf16(
                    av[mi], bv[ni], acc[mi][ni], 0, 0, 0);
        __syncthreads();
    }

    #pragma unroll
    for (int mi = 0; mi < 4; ++mi) {
        #pragma unroll
        for (int r = 0; r < 4; ++r) {
            int m = bm + wm + mi * 16 + (lane >> 4) * 4 + r;
            long cb = (long)(m / cdiv) * csq + (long)(m % cdiv) * csr;
            const float* rr = radd ? (radd + (long)(m / radd_div) * radd_ld) : nullptr;
            #pragma unroll
            for (int ni = 0; ni < 4; ++ni) {
                int n = bn + wn + ni * 16 + fr;
                if (n < N) {
                    float v = acc[mi][ni][r];
                    if (bias) v += bias[n];
                    if (rr)   v += rr[n];
                    if (ACT == 2) v = fmaxf(v, 0.f);
                    if (OBF) ((u16*)C)[cb + n] = f2bf(v);
                    else     ((float*)C)[cb + n] = v;
                }
            }
        }
    }
}

// ---------- worker tile GEMM: 128x128, K=512, A=[128][512] bf16 ----------
// ACT: 0 none, 2 relu. OBF: 1 = bf16 WT(agent) store, 0 = f32 nontemporal store.
template<int ACT, int OBF>
__device__ __forceinline__ void tile_gemm(u16* shm, const u16* Abase, const u16* W,
                                          int bn, int N, const float* bias,
                                          char* Cbase, long crs /*bytes*/)
{
    u16* lA = shm;
    u16* lB = shm + 4096;
    const int t    = threadIdx.x;
    const int lane = t & 63;
    const int wv   = t >> 6;
    const int wm   = (wv >> 1) * 64;
    const int wn   = (wv & 1) * 64;
    const int fr   = lane & 15;
    const int cc   = lane >> 4;

    const int q0 = t, q1 = t + 256;
    const int ra0 = q0 >> 2, ca0 = (q0 & 3) ^ ((ra0 >> 1) & 3);
    const int ra1 = q1 >> 2, ca1 = (q1 & 3) ^ ((ra1 >> 1) & 3);
    const u16* asrc0 = Abase + (long)ra0 * 512 + ca0 * 8;
    const u16* asrc1 = Abase + (long)ra1 * 512 + ca1 * 8;
    int brow0 = bn + ra0; if (brow0 > N - 1) brow0 = N - 1;
    int brow1 = bn + ra1; if (brow1 > N - 1) brow1 = N - 1;
    const u16* bsrc0 = W + (long)brow0 * 512 + ca0 * 8;
    const u16* bsrc1 = W + (long)brow1 * 512 + ca1 * 8;
    u16* adst0 = lA + q0 * 8;  u16* adst1 = lA + q1 * 8;
    u16* bdst0 = lB + q0 * 8;  u16* bdst1 = lB + q1 * 8;

    int aoff[4], boff[4];
    #pragma unroll
    for (int i = 0; i < 4; ++i) {
        int rA = wm + i * 16 + fr;
        aoff[i] = rA * 64 + ((cc ^ ((rA >> 1) & 3)) << 4);
        int rB = wn + i * 16 + fr;
        boff[i] = 8192 + rB * 64 + ((cc ^ ((rB >> 1) & 3)) << 4);
    }
    const char* lc = (const char*)lA;

    f32x4 acc[4][4] = {};
    for (int k0 = 0; k0 < 512; k0 += 32) {
        gload16(asrc0 + k0, adst0);
        gload16(asrc1 + k0, adst1);
        gload16(bsrc0 + k0, bdst0);
        gload16(bsrc1 + k0, bdst1);
        __syncthreads();
        bfrag av[4], bv[4];
        #pragma unroll
        for (int i = 0; i < 4; ++i) av[i] = *(const bfrag*)(lc + aoff[i]);
        #pragma unroll
        for (int i = 0; i < 4; ++i) bv[i] = *(const bfrag*)(lc + boff[i]);
        #pragma unroll
        for (int mi = 0; mi < 4; ++mi)
            #pragma unroll
            for (int ni = 0; ni < 4; ++ni)
                acc[mi][ni] = __builtin_amdgcn_mfma_f32_16x16x32_bf16(
                    av[mi], bv[ni], acc[mi][ni], 0, 0, 0);
        __syncthreads();
    }

    #pragma unroll
    for (int mi = 0; mi < 4; ++mi) {
        #pragma unroll
        for (int r = 0; r < 4; ++r) {
            int m = wm + mi * 16 + (lane >> 4) * 4 + r;
            char* crow = Cbase + (long)m * crs;
            #pragma unroll
            for (int ni = 0; ni < 4; ++ni) {
                int n = bn + wn + ni * 16 + fr;
                if (n < N) {
                    float v = acc[mi][ni][r] + bias[n];
                    if (ACT == 2) v = fmaxf(v, 0.f);
                    if (OBF)
                        __hip_atomic_store((u16*)crow + n, f2bf(v),
                                           __ATOMIC_RELAXED, __HIP_MEMORY_SCOPE_AGENT);
                    else
                        __builtin_nontemporal_store(v, (float*)crow + n);
                }
            }
        }
    }
}

// ---------- mega kernel: blocks 0-31 recurrence (R8 body), 32-63 fc1, 64-287 fc2 ----------
__global__ __launch_bounds__(256, 1)
void mega_k(const u16* __restrict__ h0b, const float* __restrict__ c0,
            const float* __restrict__ Whh, const float* __restrict__ gx,
            u16* __restrict__ h_b, unsigned* __restrict__ bar,
            const u16* __restrict__ wfc1, const float* __restrict__ b_fc1,
            u16* __restrict__ o_b,
            const u16* __restrict__ wfc2, const float* __restrict__ b_fc2,
            float* __restrict__ out)
{
    __shared__ alignas(16) u16 shm[32768];   // 64 KB: rec Wf / worker lA+lB
    const int bid  = blockIdx.x;
    const int t256 = threadIdx.x;
    const int lane = t256 & 63;

    if (bid < NBLK) {
        // ======== recurrence role (R8-proven body; only t=34 signal added) ========
        bfrag* Wf = (bfrag*)shm;
        const int jb = bid;
        const int w  = t256 >> 6;
        const int fr = lane & 15;
        const int cc = lane >> 4;

        for (int q = 0; q < 16; ++q) {
            int flat = t256 + q * 256;
            int r = flat >> 6, kg = flat & 63;
            int mi = r >> 4, jj = r & 15;
            int kk = kg >> 2, c2 = kg & 3;
            const float* src = Whh + (long)(mi * 512 + jb * 16 + jj) * 512 + kg * 8;
            float4 s0 = *(const float4*)src;
            float4 s1 = *(const float4*)(src + 4);
            bfrag p;
            p[0] = (short)f2bf(s0.x); p[1] = (short)f2bf(s0.y);
            p[2] = (short)f2bf(s0.z); p[3] = (short)f2bf(s0.w);
            p[4] = (short)f2bf(s1.x); p[5] = (short)f2bf(s1.y);
            p[6] = (short)f2bf(s1.z); p[7] = (short)f2bf(s1.w);
            Wf[(kk * 4 + mi) * 64 + c2 * 16 + jj] = p;
        }

        const int b0   = w * 32 + fr;
        const int jcol = jb * 16 + cc * 4;

        f32x4 creg[2];
        #pragma unroll
        for (int ni = 0; ni < 2; ++ni)
            creg[ni] = *(const f32x4*)(c0 + (long)(b0 + ni*16) * 512 + jcol);

        f32x4 gxc[4][2];
        #pragma unroll
        for (int ni = 0; ni < 2; ++ni) {
            const float* gp = gx + (long)(b0 + ni*16) * G4 + jcol;
            #pragma unroll
            for (int g = 0; g < 4; ++g) gxc[g][ni] = *(const f32x4*)(gp + g * 512);
        }

        __syncthreads();

        const u16* hsrc = h0b;
        for (int t = 0; t < TB; ++t) {
            bfrag hreg[2][16];
            #pragma unroll
            for (int ni = 0; ni < 2; ++ni) {
                const u16* hp = hsrc + (long)(b0 + ni*16) * 512 + cc * 8;
                #pragma unroll
                for (int kk = 0; kk < 16; ++kk)
                    hreg[ni][kk] = *(const bfrag*)(hp + kk * 32);
            }

            f32x4 acc[4][2] = {};
            #pragma unroll
            for (int kk = 0; kk < 16; ++kk) {
                bfrag av0 = Wf[(kk*4 + 0) * 64 + lane];
                bfrag av1 = Wf[(kk*4 + 1) * 64 + lane];
                bfrag av2 = Wf[(kk*4 + 2) * 64 + lane];
                bfrag av3 = Wf[(kk*4 + 3) * 64 + lane];
                #pragma unroll
                for (int ni = 0; ni < 2; ++ni) {
                    acc[0][ni] = __builtin_amdgcn_mfma_f32_16x16x32_bf16(av0, hreg[ni][kk], acc[0][ni], 0,0,0);
                    acc[1][ni] = __builtin_amdgcn_mfma_f32_16x16x32_bf16(av1, hreg[ni][kk], acc[1][ni], 0,0,0);
                    acc[2][ni] = __builtin_amdgcn_mfma_f32_16x16x32_bf16(av2, hreg[ni][kk], acc[2][ni], 0,0,0);
                    acc[3][ni] = __builtin_amdgcn_mfma_f32_16x16x32_bf16(av3, hreg[ni][kk], acc[3][ni], 0,0,0);
                }
            }

            u16* hd = h_b + (long)t * (BB*HH);
            #pragma unroll
            for (int ni = 0; ni < 2; ++ni) {
                u64 hq = 0;
                #pragma unroll
                for (int rr = 0; rr < 4; ++rr) {
                    float ig = fast_sig (acc[0][ni][rr] + gxc[0][ni][rr]);
                    float fg = fast_sig (acc[1][ni][rr] + gxc[1][ni][rr]);
                    float gg = fast_tanh(acc[2][ni][rr] + gxc[2][ni][rr]);
                    float og = fast_sig (acc[3][ni][rr] + gxc[3][ni][rr]);
                    float c  = fg * creg[ni][rr] + ig * gg;
                    creg[ni][rr] = c;
                    hq |= (u64)f2bf(og * fast_tanh(c)) << (rr * 16);
                }
                __hip_atomic_store((u64*)(hd + (long)(b0 + ni*16) * 512 + jcol), hq,
                                   __ATOMIC_RELAXED, __HIP_MEMORY_SCOPE_AGENT);
            }
            hsrc = hd;

            if (t < TB - 1) {
                f32x4 gxn[4][2];
                #pragma unroll
                for (int ni = 0; ni < 2; ++ni) {
                    const float* gp = gx + ((long)(t+1) * BB + b0 + ni*16) * G4 + jcol;
                    #pragma unroll
                    for (int g = 0; g < 4; ++g) gxn[g][ni] = *(const f32x4*)(gp + g * 512);
                }
                __syncthreads();            // drains vmcnt per wave -> h stores visible
                if (t256 == 0) {
                    unsigned* ctr = bar + t * 16;
                    __hip_atomic_fetch_add(ctr, 1u, __ATOMIC_RELAXED, __HIP_MEMORY_SCOPE_AGENT);
                    while (__hip_atomic_load(ctr, __ATOMIC_RELAXED, __HIP_MEMORY_SCOPE_AGENT) < NBLK)
                        __builtin_amdgcn_s_sleep(2);
                }
                __syncthreads();
                __builtin_amdgcn_fence(__ATOMIC_ACQUIRE, "agent");
                #pragma unroll
                for (int g = 0; g < 4; ++g)
                    #pragma unroll
                    for (int ni = 0; ni < 2; ++ni) gxc[g][ni] = gxn[g][ni];
            } else {
                __syncthreads();            // drain final h stores
                if (t256 == 0)
                    __hip_atomic_fetch_add(bar + t * 16, 1u,
                                           __ATOMIC_RELAXED, __HIP_MEMORY_SCOPE_AGENT);
            }
        }
    } else if (bid < 64) {
        // ======== fc1 workers: o_t = relu(h_t @ Wfc1^T + b), 4 tiles/step ========
        const int wkr = bid - 32;                 // 0..31
        for (int g = wkr; g < TB * 4; g += 32) {
            int tt = g >> 2, nt4 = g & 3;
            if (t256 == 0) {
                while (__hip_atomic_load(bar + tt * 16, __ATOMIC_RELAXED,
                                         __HIP_MEMORY_SCOPE_AGENT) < NBLK)
                    __builtin_amdgcn_s_sleep(10);
            }
            __syncthreads();
            __builtin_amdgcn_fence(__ATOMIC_ACQUIRE, "agent");
            tile_gemm<2,1>(shm, h_b + (long)tt * (BB*HH), wfc1, nt4 * 128, HH, b_fc1,
                           (char*)(o_b + (long)tt * (BB*HH)), HH * 2);
            __syncthreads();                      // drain WT o stores (all waves)
            if (t256 == 0)
                __hip_atomic_fetch_add(bar + 600 + tt, 1u,
                                       __ATOMIC_RELAXED, __HIP_MEMORY_SCOPE_AGENT);
        }
    } else {
        // ======== fc2 workers: out[:,t,:] = o_t @ Wfc2^T + b, 79 tiles/step ========
        const int wkr = bid - 64;                 // 0..223
        for (int g = wkr; g < TB * 79; g += 224) {
            int tt = g / 79, nt = g - tt * 79;
            if (t256 == 0) {
                while (__hip_atomic_load(bar + 600 + tt, __ATOMIC_RELAXED,
                                         __HIP_MEMORY_SCOPE_AGENT) < 4)
                    __builtin_amdgcn_s_sleep(10);
            }
            __syncthreads();
            __builtin_amdgcn_fence(__ATOMIC_ACQUIRE, "agent");
            tile_gemm<0,0>(shm, o_b + (long)tt * (BB*HH), wfc2, nt * 128, VV, b_fc2,
                           (char*)(out + (long)tt * VV), (long)TB * VV * 4);
        }
    }
}

extern "C" void kernel_launch(void* const* d_in, const int* in_sizes, int n_in,
                              void* d_out, int out_size, void* d_ws, size_t ws_size,
                              hipStream_t stream)
{
    const float* img    = (const float*)d_in[0];
    const int*   seqs   = (const int*)d_in[1];
    const float* emb    = (const float*)d_in[3];
    const float* W_ih   = (const float*)d_in[4];
    const float* b_ih   = (const float*)d_in[5];
    const float* W_hh   = (const float*)d_in[6];
    const float* b_hh   = (const float*)d_in[7];
    const float* W_inh  = (const float*)d_in[8];
    const float* b_inh  = (const float*)d_in[9];
    const float* W_inc  = (const float*)d_in[10];
    const float* b_inc  = (const float*)d_in[11];
    const float* W_fc1  = (const float*)d_in[12];
    const float* b_fc1  = (const float*)d_in[13];
    const float* W_fc2  = (const float*)d_in[14];
    const float* b_fc2  = (const float*)d_in[15];
    float* out = (float*)d_out;

    float*    ws  = (float*)d_ws;
    unsigned* bar = (unsigned*)ws;          // 1024 reserved; step ctrs bar[t*16], o_ctr bar[600+t]
    float* mf    = ws    + 1024;            // 180224
    float* c_cur = mf    + 180224;          // 65536
    float* gxb   = c_cur + 65536;           // 262144
    float* gx    = gxb   + 262144;          // 9175040  [t][b][2048] fp32
    float* ipart = gx;                      // alias (1572864 <= 9175040), dead before gx
    u16*   h_b    = (u16*)(gx + 9175040);   // 2293760  [t][b][512] bf16
    u16*   h0b    = h_b    + 2293760;       // 65536
    u16*   emb_b  = h0b    + 65536;         // 5120000
    u16*   wih_b  = emb_b  + 5120000;       // 1048576
    u16*   wfc1_b = wih_b  + 1048576;       // 262144
    u16*   wfc2_b = wfc1_b + 262144;        // 5120000
    u16*   o_b    = wfc2_b + 5120000;       // 2293760

    // weight / embedding casts to bf16
    cast512_k<<<5000, 256, 0, stream>>>(emb,   512,  emb_b,  1280000);
    cast512_k<<<1024, 256, 0, stream>>>(W_ih,  1920, wih_b,   262144);
    cast512_k<<< 256, 256, 0, stream>>>(W_fc1, 512,  wfc1_b,   65536);
    cast512_k<<<5000, 256, 0, stream>>>(W_fc2, 512,  wfc2_b, 1280000);

    mean_k<<<704, 256, 0, stream>>>(img, mf);
    init_partial_k<<<dim3(48, 2, 4), 256, 0, stream>>>(mf, W_inh, W_inc, W_ih, ipart);
    init_combine_k<<<1536, 256, 0, stream>>>(ipart, b_ih, b_hh, b_inh, b_inc,
                                             h0b, c_cur, gxb, bar);

    // gx[t][b][n] = emb_b[seq[b][t]] . wih_b[n] + gxb[b][n]
    gemm_mfma<0,0><<<dim3(16 * 35), 256, 0, stream>>>(emb_b, EE, seqs, wih_b, nullptr,
                                                      gxb, TB, G4, gx, TB, G4,
                                                      (long)BB * G4, 35, G4, EE);

    // recurrence + overlapped fc1/fc2: ONE plain-launched persistent kernel
    mega_k<<<dim3(288), dim3(256), 0, stream>>>(h0b, c_cur, W_hh, gx, h_b, bar,
                                                wfc1_b, b_fc1, o_b, wfc2_b, b_fc2, out);
}

// Round 10
// 485.850 us; speedup vs baseline: 5.9874x; 1.1455x over previous
//
#include <hip/hip_runtime.h>

#define TB 35
#define BB 128
#define VV 10000
#define FF 1408
#define EE 512
#define HH 512
#define G4 2048   // 4*H
#define NBLK 32   // recurrence blocks

typedef unsigned short u16;
typedef unsigned long long u64;
typedef __attribute__((ext_vector_type(8))) short bfrag;   // 8 bf16 = 4 VGPR
typedef __attribute__((ext_vector_type(4))) float f32x4;

__device__ __forceinline__ u16 f2bf(float f) {             // RNE f32->bf16
    unsigned u = __float_as_uint(f);
    return (u16)((u + 0x7FFFu + ((u >> 16) & 1u)) >> 16);
}
__device__ __forceinline__ float fast_sig(float x) {
    return __builtin_amdgcn_rcpf(1.f + __expf(-x));
}
__device__ __forceinline__ float fast_tanh(float x) {
    return 1.f - 2.f * __builtin_amdgcn_rcpf(1.f + __expf(2.f * x));
}

__device__ __forceinline__ void gload16(const void* g, void* l) {
    __builtin_amdgcn_global_load_lds(
        (const __attribute__((address_space(1))) void*)g,
        (__attribute__((address_space(3))) void*)l, 16, 0, 0);
}

// ---------- mean over R=81 regions ----------
__global__ __launch_bounds__(256)
void mean_k(const float* __restrict__ img, float* __restrict__ mf) {
    int idx = blockIdx.x * 256 + threadIdx.x;      // B*F = 180224
    int b = idx / FF, f = idx - b * FF;
    const float* p = img + (long)b * (81 * FF) + f;
    float s = 0.f;
    for (int r = 0; r < 81; ++r) s += p[r * FF];
    mf[idx] = s * (1.f / 81.f);
}

// ---------- fp32 -> bf16 cast (row length 512, vector-4) ----------
__global__ __launch_bounds__(256)
void cast512_k(const float* __restrict__ src, int lds, u16* __restrict__ dst, int n4) {
    int i = blockIdx.x * 256 + threadIdx.x;
    if (i >= n4) return;
    long e = (long)i * 4;
    long row = e >> 9; int col = (int)(e & 511);
    float4 v = *(const float4*)(src + row * lds + col);
    uint2 o;
    o.x = (unsigned)f2bf(v.x) | ((unsigned)f2bf(v.y) << 16);
    o.y = (unsigned)f2bf(v.z) | ((unsigned)f2bf(v.w) << 16);
    *(uint2*)(dst + e) = o;
}

// ---------- init partial GEMM (fp32): mf(128x1408) x {W_init_h|W_init_c|W_ih[:,E:]}^T ----------
__global__ __launch_bounds__(256)
void init_partial_k(const float* __restrict__ mf,
                    const float* __restrict__ Wh, const float* __restrict__ Wc,
                    const float* __restrict__ Wih,
                    float* __restrict__ part)
{
    __shared__ float As[16][68];
    __shared__ float Ws[16][68];
    const int t  = threadIdx.x;
    const int bx = blockIdx.x;              // 0..47
    const int bm = blockIdx.y * 64;
    const int kz = blockIdx.z;              // 0..3
    const float* W; int ldw; long wr0;
    if (bx < 8)       { W = Wh;       ldw = FF;   wr0 = (long)bx * 64; }
    else if (bx < 16) { W = Wc;       ldw = FF;   wr0 = (long)(bx - 8) * 64; }
    else              { W = Wih + EE; ldw = 1920; wr0 = (long)(bx - 16) * 64; }
    const int lrow = t >> 2, lc4 = (t & 3) << 2;
    const int ty = t >> 4, tx = t & 15;
    const float* arow = mf + (long)(bm + lrow) * FF;
    const float* wrow = W + (wr0 + lrow) * (long)ldw;
    float acc[4][4] = {};
    const int kbeg = kz * 352, kend2 = kbeg + 352;
    for (int k0 = kbeg; k0 < kend2; k0 += 16) {
        float4 av = *(const float4*)(arow + k0 + lc4);
        float4 wv = *(const float4*)(wrow + k0 + lc4);
        As[lc4+0][lrow]=av.x; As[lc4+1][lrow]=av.y; As[lc4+2][lrow]=av.z; As[lc4+3][lrow]=av.w;
        Ws[lc4+0][lrow]=wv.x; Ws[lc4+1][lrow]=wv.y; Ws[lc4+2][lrow]=wv.z; Ws[lc4+3][lrow]=wv.w;
        __syncthreads();
        #pragma unroll
        for (int kk = 0; kk < 16; ++kk) {
            float4 a = *(const float4*)&As[kk][ty*4];
            float4 w = *(const float4*)&Ws[kk][tx*4];
            acc[0][0]+=a.x*w.x; acc[0][1]+=a.x*w.y; acc[0][2]+=a.x*w.z; acc[0][3]+=a.x*w.w;
            acc[1][0]+=a.y*w.x; acc[1][1]+=a.y*w.y; acc[1][2]+=a.y*w.z; acc[1][3]+=a.y*w.w;
            acc[2][0]+=a.z*w.x; acc[2][1]+=a.z*w.y; acc[2][2]+=a.z*w.z; acc[2][3]+=a.z*w.w;
            acc[3][0]+=a.w*w.x; acc[3][1]+=a.w*w.y; acc[3][2]+=a.w*w.z; acc[3][3]+=a.w*w.w;
        }
        __syncthreads();
    }
    const int ncol = bx * 64;
    #pragma unroll
    for (int i = 0; i < 4; ++i) {
        long base = (long)kz * (BB*3072) + (long)(bm + ty*4 + i) * 3072 + ncol + tx*4;
        *(float4*)(part + base) = make_float4(acc[i][0], acc[i][1], acc[i][2], acc[i][3]);
    }
}

// ---------- combine init partials -> h0 (bf16), c0 (f32), gxb; zero all flags ----------
__global__ __launch_bounds__(256)
void init_combine_k(const float* __restrict__ part,
                    const float* __restrict__ b_ih, const float* __restrict__ b_hh,
                    const float* __restrict__ b_init_h, const float* __restrict__ b_init_c,
                    u16* __restrict__ h0b, float* __restrict__ c_cur, float* __restrict__ gxb,
                    unsigned* __restrict__ bar)
{
    int idx = blockIdx.x * 256 + threadIdx.x;   // 128*3072
    if (idx < 1024) bar[idx] = 0;               // rec flags bar[0..31], o_ctr bar[600+t]
    int b = idx / 3072, n = idx - b * 3072;
    float s = part[idx] + part[393216 + idx] + part[2*393216 + idx] + part[3*393216 + idx];
    if (n < 512)       h0b[b*512 + n]         = f2bf(tanhf(s + b_init_h[n]));
    else if (n < 1024) c_cur[b*512 + (n-512)] = tanhf(s + b_init_c[n-512]);
    else               gxb[b*2048 + (n-1024)] = s + b_ih[n-1024] + b_hh[n-1024];
}

// ---------- bf16 MFMA GEMM (128x128 tile, 4 waves) — used for gx ----------
template<int ACT, int OBF>
__global__ __launch_bounds__(256)
void gemm_mfma(const u16* __restrict__ A, int lda, const int* __restrict__ rowidx,
               const u16* __restrict__ W, const float* __restrict__ bias,
               const float* __restrict__ radd, int radd_div, int radd_ld,
               void* __restrict__ C, int cdiv, long csq, long csr,
               int mtiles, int N, int K)
{
    __shared__ u16 lA[4096];   // [128][32]
    __shared__ u16 lB[4096];
    int bxi, byi;
    if (mtiles > 0) {
        int nwg = gridDim.x, bid = blockIdx.x;
        int q = nwg >> 3, r = nwg & 7;
        int xcd = bid & 7, pos = bid >> 3;
        int lid = (xcd < r) ? (xcd * (q + 1) + pos)
                            : (r * (q + 1) + (xcd - r) * q + pos);
        byi = lid % mtiles;
        bxi = lid / mtiles;
    } else { bxi = blockIdx.x; byi = blockIdx.y; }

    const int t    = threadIdx.x;
    const int bm   = byi * 128;
    const int bn   = bxi * 128;
    const int lane = t & 63;
    const int wv   = t >> 6;
    const int wm   = (wv >> 1) * 64;
    const int wn   = (wv & 1) * 64;
    const int fr   = lane & 15;
    const int cc   = lane >> 4;

    const int q0 = t, q1 = t + 256;
    const int ra0 = q0 >> 2, ca0 = (q0 & 3) ^ ((ra0 >> 1) & 3);
    const int ra1 = q1 >> 2, ca1 = (q1 & 3) ^ ((ra1 >> 1) & 3);
    long arow0 = rowidx ? (long)rowidx[bm + ra0] : (long)(bm + ra0);
    long arow1 = rowidx ? (long)rowidx[bm + ra1] : (long)(bm + ra1);
    const u16* asrc0 = A + arow0 * lda + ca0 * 8;
    const u16* asrc1 = A + arow1 * lda + ca1 * 8;
    int brow0 = bn + ra0; if (brow0 > N - 1) brow0 = N - 1;
    int brow1 = bn + ra1; if (brow1 > N - 1) brow1 = N - 1;
    const u16* bsrc0 = W + (long)brow0 * K + ca0 * 8;
    const u16* bsrc1 = W + (long)brow1 * K + ca1 * 8;
    u16* adst0 = lA + q0 * 8;  u16* adst1 = lA + q1 * 8;
    u16* bdst0 = lB + q0 * 8;  u16* bdst1 = lB + q1 * 8;

    int aoff[4], boff[4];
    #pragma unroll
    for (int i = 0; i < 4; ++i) {
        int rA = wm + i * 16 + fr;
        aoff[i] = rA * 64 + ((cc ^ ((rA >> 1) & 3)) << 4);
        int rB = wn + i * 16 + fr;
        boff[i] = rB * 64 + ((cc ^ ((rB >> 1) & 3)) << 4);
    }
    const char* lac = (const char*)lA;
    const char* lbc = (const char*)lB;

    f32x4 acc[4][4] = {};
    for (int k0 = 0; k0 < K; k0 += 32) {
        gload16(asrc0 + k0, adst0);
        gload16(asrc1 + k0, adst1);
        gload16(bsrc0 + k0, bdst0);
        gload16(bsrc1 + k0, bdst1);
        __syncthreads();
        bfrag av[4], bv[4];
        #pragma unroll
        for (int i = 0; i < 4; ++i) av[i] = *(const bfrag*)(lac + aoff[i]);
        #pragma unroll
        for (int i = 0; i < 4; ++i) bv[i] = *(const bfrag*)(lbc + boff[i]);
        #pragma unroll
        for (int mi = 0; mi < 4; ++mi)
            #pragma unroll
            for (int ni = 0; ni < 4; ++ni)
                acc[mi][ni] = __builtin_amdgcn_mfma_f32_16x16x32_bf16(
                    av[mi], bv[ni], acc[mi][ni], 0, 0, 0);
        __syncthreads();
    }

    #pragma unroll
    for (int mi = 0; mi < 4; ++mi) {
        #pragma unroll
        for (int r = 0; r < 4; ++r) {
            int m = bm + wm + mi * 16 + (lane >> 4) * 4 + r;
            long cb = (long)(m / cdiv) * csq + (long)(m % cdiv) * csr;
            const float* rr = radd ? (radd + (long)(m / radd_div) * radd_ld) : nullptr;
            #pragma unroll
            for (int ni = 0; ni < 4; ++ni) {
                int n = bn + wn + ni * 16 + fr;
                if (n < N) {
                    float v = acc[mi][ni][r];
                    if (bias) v += bias[n];
                    if (rr)   v += rr[n];
                    if (ACT == 2) v = fmaxf(v, 0.f);
                    if (OBF) ((u16*)C)[cb + n] = f2bf(v);
                    else     ((float*)C)[cb + n] = v;
                }
            }
        }
    }
}

// ---------- worker tile GEMM: 128x128, K=512, A=[128][512] bf16 ----------
template<int ACT, int OBF>
__device__ __forceinline__ void tile_gemm(u16* shm, const u16* Abase, const u16* W,
                                          int bn, int N, const float* bias,
                                          char* Cbase, long crs /*bytes*/)
{
    u16* lA = shm;
    u16* lB = shm + 4096;
    const int t    = threadIdx.x;
    const int lane = t & 63;
    const int wv   = t >> 6;
    const int wm   = (wv >> 1) * 64;
    const int wn   = (wv & 1) * 64;
    const int fr   = lane & 15;
    const int cc   = lane >> 4;

    const int q0 = t, q1 = t + 256;
    const int ra0 = q0 >> 2, ca0 = (q0 & 3) ^ ((ra0 >> 1) & 3);
    const int ra1 = q1 >> 2, ca1 = (q1 & 3) ^ ((ra1 >> 1) & 3);
    const u16* asrc0 = Abase + (long)ra0 * 512 + ca0 * 8;
    const u16* asrc1 = Abase + (long)ra1 * 512 + ca1 * 8;
    int brow0 = bn + ra0; if (brow0 > N - 1) brow0 = N - 1;
    int brow1 = bn + ra1; if (brow1 > N - 1) brow1 = N - 1;
    const u16* bsrc0 = W + (long)brow0 * 512 + ca0 * 8;
    const u16* bsrc1 = W + (long)brow1 * 512 + ca1 * 8;
    u16* adst0 = lA + q0 * 8;  u16* adst1 = lA + q1 * 8;
    u16* bdst0 = lB + q0 * 8;  u16* bdst1 = lB + q1 * 8;

    int aoff[4], boff[4];
    #pragma unroll
    for (int i = 0; i < 4; ++i) {
        int rA = wm + i * 16 + fr;
        aoff[i] = rA * 64 + ((cc ^ ((rA >> 1) & 3)) << 4);
        int rB = wn + i * 16 + fr;
        boff[i] = 8192 + rB * 64 + ((cc ^ ((rB >> 1) & 3)) << 4);
    }
    const char* lc = (const char*)lA;

    f32x4 acc[4][4] = {};
    for (int k0 = 0; k0 < 512; k0 += 32) {
        gload16(asrc0 + k0, adst0);
        gload16(asrc1 + k0, adst1);
        gload16(bsrc0 + k0, bdst0);
        gload16(bsrc1 + k0, bdst1);
        __syncthreads();
        bfrag av[4], bv[4];
        #pragma unroll
        for (int i = 0; i < 4; ++i) av[i] = *(const bfrag*)(lc + aoff[i]);
        #pragma unroll
        for (int i = 0; i < 4; ++i) bv[i] = *(const bfrag*)(lc + boff[i]);
        #pragma unroll
        for (int mi = 0; mi < 4; ++mi)
            #pragma unroll
            for (int ni = 0; ni < 4; ++ni)
                acc[mi][ni] = __builtin_amdgcn_mfma_f32_16x16x32_bf16(
                    av[mi], bv[ni], acc[mi][ni], 0, 0, 0);
        __syncthreads();
    }

    #pragma unroll
    for (int mi = 0; mi < 4; ++mi) {
        #pragma unroll
        for (int r = 0; r < 4; ++r) {
            int m = wm + mi * 16 + (lane >> 4) * 4 + r;
            char* crow = Cbase + (long)m * crs;
            #pragma unroll
            for (int ni = 0; ni < 4; ++ni) {
                int n = bn + wn + ni * 16 + fr;
                if (n < N) {
                    float v = acc[mi][ni][r] + bias[n];
                    if (ACT == 2) v = fmaxf(v, 0.f);
                    if (OBF)
                        __hip_atomic_store((u16*)crow + n, f2bf(v),
                                           __ATOMIC_RELAXED, __HIP_MEMORY_SCOPE_AGENT);
                    else
                        __builtin_nontemporal_store(v, (float*)crow + n);
                }
            }
        }
    }
}

// ---------- mega kernel: blocks 0-31 recurrence, 32-63 fc1, 64-255 fc2 ----------
// Rec signal: per-block monotonic flag bar[jb]=t+1 (plain relaxed store, NO RMW
// convoy); consumers poll 32 flags in parallel (one coalesced line read per poll).
__global__ __launch_bounds__(256, 1)
void mega_k(const u16* __restrict__ h0b, const float* __restrict__ c0,
            const float* __restrict__ Whh, const float* __restrict__ gx,
            u16* __restrict__ h_b, unsigned* __restrict__ bar,
            const u16* __restrict__ wfc1, const float* __restrict__ b_fc1,
            u16* __restrict__ o_b,
            const u16* __restrict__ wfc2, const float* __restrict__ b_fc2,
            float* __restrict__ out)
{
    __shared__ alignas(16) u16 shm[32768];   // 64 KB: rec Wf / worker lA+lB
    const int bid  = blockIdx.x;
    const int t256 = threadIdx.x;
    const int lane = t256 & 63;

    if (bid < NBLK) {
        // ======== recurrence role (R8 body; signal = flag store, poll = parallel) ========
        bfrag* Wf = (bfrag*)shm;
        const int jb = bid;
        const int w  = t256 >> 6;
        const int fr = lane & 15;
        const int cc = lane >> 4;

        for (int q = 0; q < 16; ++q) {
            int flat = t256 + q * 256;
            int r = flat >> 6, kg = flat & 63;
            int mi = r >> 4, jj = r & 15;
            int kk = kg >> 2, c2 = kg & 3;
            const float* src = Whh + (long)(mi * 512 + jb * 16 + jj) * 512 + kg * 8;
            float4 s0 = *(const float4*)src;
            float4 s1 = *(const float4*)(src + 4);
            bfrag p;
            p[0] = (short)f2bf(s0.x); p[1] = (short)f2bf(s0.y);
            p[2] = (short)f2bf(s0.z); p[3] = (short)f2bf(s0.w);
            p[4] = (short)f2bf(s1.x); p[5] = (short)f2bf(s1.y);
            p[6] = (short)f2bf(s1.z); p[7] = (short)f2bf(s1.w);
            Wf[(kk * 4 + mi) * 64 + c2 * 16 + jj] = p;
        }

        const int b0   = w * 32 + fr;
        const int jcol = jb * 16 + cc * 4;

        f32x4 creg[2];
        #pragma unroll
        for (int ni = 0; ni < 2; ++ni)
            creg[ni] = *(const f32x4*)(c0 + (long)(b0 + ni*16) * 512 + jcol);

        f32x4 gxc[4][2];
        #pragma unroll
        for (int ni = 0; ni < 2; ++ni) {
            const float* gp = gx + (long)(b0 + ni*16) * G4 + jcol;
            #pragma unroll
            for (int g = 0; g < 4; ++g) gxc[g][ni] = *(const f32x4*)(gp + g * 512);
        }

        __syncthreads();

        const u16* hsrc = h0b;
        for (int t = 0; t < TB; ++t) {
            bfrag hreg[2][16];
            #pragma unroll
            for (int ni = 0; ni < 2; ++ni) {
                const u16* hp = hsrc + (long)(b0 + ni*16) * 512 + cc * 8;
                #pragma unroll
                for (int kk = 0; kk < 16; ++kk)
                    hreg[ni][kk] = *(const bfrag*)(hp + kk * 32);
            }

            f32x4 acc[4][2] = {};
            #pragma unroll
            for (int kk = 0; kk < 16; ++kk) {
                bfrag av0 = Wf[(kk*4 + 0) * 64 + lane];
                bfrag av1 = Wf[(kk*4 + 1) * 64 + lane];
                bfrag av2 = Wf[(kk*4 + 2) * 64 + lane];
                bfrag av3 = Wf[(kk*4 + 3) * 64 + lane];
                #pragma unroll
                for (int ni = 0; ni < 2; ++ni) {
                    acc[0][ni] = __builtin_amdgcn_mfma_f32_16x16x32_bf16(av0, hreg[ni][kk], acc[0][ni], 0,0,0);
                    acc[1][ni] = __builtin_amdgcn_mfma_f32_16x16x32_bf16(av1, hreg[ni][kk], acc[1][ni], 0,0,0);
                    acc[2][ni] = __builtin_amdgcn_mfma_f32_16x16x32_bf16(av2, hreg[ni][kk], acc[2][ni], 0,0,0);
                    acc[3][ni] = __builtin_amdgcn_mfma_f32_16x16x32_bf16(av3, hreg[ni][kk], acc[3][ni], 0,0,0);
                }
            }

            u16* hd = h_b + (long)t * (BB*HH);
            #pragma unroll
            for (int ni = 0; ni < 2; ++ni) {
                u64 hq = 0;
                #pragma unroll
                for (int rr = 0; rr < 4; ++rr) {
                    float ig = fast_sig (acc[0][ni][rr] + gxc[0][ni][rr]);
                    float fg = fast_sig (acc[1][ni][rr] + gxc[1][ni][rr]);
                    float gg = fast_tanh(acc[2][ni][rr] + gxc[2][ni][rr]);
                    float og = fast_sig (acc[3][ni][rr] + gxc[3][ni][rr]);
                    float c  = fg * creg[ni][rr] + ig * gg;
                    creg[ni][rr] = c;
                    hq |= (u64)f2bf(og * fast_tanh(c)) << (rr * 16);
                }
                __hip_atomic_store((u64*)(hd + (long)(b0 + ni*16) * 512 + jcol), hq,
                                   __ATOMIC_RELAXED, __HIP_MEMORY_SCOPE_AGENT);
            }
            hsrc = hd;

            if (t < TB - 1) {
                f32x4 gxn[4][2];
                #pragma unroll
                for (int ni = 0; ni < 2; ++ni) {
                    const float* gp = gx + ((long)(t+1) * BB + b0 + ni*16) * G4 + jcol;
                    #pragma unroll
                    for (int g = 0; g < 4; ++g) gxn[g][ni] = *(const f32x4*)(gp + g * 512);
                }
                __syncthreads();            // drains vmcnt for ALL waves -> h stores done
                if (t256 < 64) {            // wave 0: flag store + parallel poll
                    if (lane == 0)
                        __hip_atomic_store(&bar[jb], (unsigned)(t + 1),
                                           __ATOMIC_RELAXED, __HIP_MEMORY_SCOPE_AGENT);
                    while (true) {
                        unsigned v = __hip_atomic_load(&bar[lane & 31],
                                                       __ATOMIC_RELAXED, __HIP_MEMORY_SCOPE_AGENT);
                        if (__all(v > (unsigned)t)) break;
                        __builtin_amdgcn_s_sleep(1);
                    }
                }
                __syncthreads();
                __builtin_amdgcn_fence(__ATOMIC_ACQUIRE, "agent");
                #pragma unroll
                for (int g = 0; g < 4; ++g)
                    #pragma unroll
                    for (int ni = 0; ni < 2; ++ni) gxc[g][ni] = gxn[g][ni];
            } else {
                __syncthreads();            // drain final h stores
                if (t256 == 0)
                    __hip_atomic_store(&bar[jb], (unsigned)TB,
                                       __ATOMIC_RELAXED, __HIP_MEMORY_SCOPE_AGENT);
            }
        }
    } else if (bid < 64) {
        // ======== fc1 workers: o_t = relu(h_t @ Wfc1^T + b), 4 tiles/step ========
        const int wkr = bid - 32;                 // 0..31
        for (int g = wkr; g < TB * 4; g += 32) {
            int tt = g >> 2, nt4 = g & 3;
            if (t256 < 64) {                       // parallel poll of 32 rec flags
                while (true) {
                    unsigned v = __hip_atomic_load(&bar[lane & 31],
                                                   __ATOMIC_RELAXED, __HIP_MEMORY_SCOPE_AGENT);
                    if (__all(v > (unsigned)tt)) break;
                    __builtin_amdgcn_s_sleep(8);
                }
            }
            __syncthreads();
            __builtin_amdgcn_fence(__ATOMIC_ACQUIRE, "agent");
            tile_gemm<2,1>(shm, h_b + (long)tt * (BB*HH), wfc1, nt4 * 128, HH, b_fc1,
                           (char*)(o_b + (long)tt * (BB*HH)), HH * 2);
            __syncthreads();                      // drain WT o stores (all waves)
            if (t256 == 0)
                __hip_atomic_fetch_add(bar + 600 + tt, 1u,
                                       __ATOMIC_RELAXED, __HIP_MEMORY_SCOPE_AGENT);
        }
    } else {
        // ======== fc2 workers: out[:,t,:] = o_t @ Wfc2^T + b, 79 tiles/step ========
        const int wkr = bid - 64;                 // 0..191
        for (int g = wkr; g < TB * 79; g += 192) {
            int tt = g / 79, nt = g - tt * 79;
            if (t256 == 0) {
                while (__hip_atomic_load(bar + 600 + tt, __ATOMIC_RELAXED,
                                         __HIP_MEMORY_SCOPE_AGENT) < 4)
                    __builtin_amdgcn_s_sleep(8);
            }
            __syncthreads();
            __builtin_amdgcn_fence(__ATOMIC_ACQUIRE, "agent");
            tile_gemm<0,0>(shm, o_b + (long)tt * (BB*HH), wfc2, nt * 128, VV, b_fc2,
                           (char*)(out + (long)tt * VV), (long)TB * VV * 4);
        }
    }
}

extern "C" void kernel_launch(void* const* d_in, const int* in_sizes, int n_in,
                              void* d_out, int out_size, void* d_ws, size_t ws_size,
                              hipStream_t stream)
{
    const float* img    = (const float*)d_in[0];
    const int*   seqs   = (const int*)d_in[1];
    const float* emb    = (const float*)d_in[3];
    const float* W_ih   = (const float*)d_in[4];
    const float* b_ih   = (const float*)d_in[5];
    const float* W_hh   = (const float*)d_in[6];
    const float* b_hh   = (const float*)d_in[7];
    const float* W_inh  = (const float*)d_in[8];
    const float* b_inh  = (const float*)d_in[9];
    const float* W_inc  = (const float*)d_in[10];
    const float* b_inc  = (const float*)d_in[11];
    const float* W_fc1  = (const float*)d_in[12];
    const float* b_fc1  = (const float*)d_in[13];
    const float* W_fc2  = (const float*)d_in[14];
    const float* b_fc2  = (const float*)d_in[15];
    float* out = (float*)d_out;

    float*    ws  = (float*)d_ws;
    unsigned* bar = (unsigned*)ws;          // 1024 reserved; rec flags bar[0..31], o_ctr bar[600+t]
    float* mf    = ws    + 1024;            // 180224
    float* c_cur = mf    + 180224;          // 65536
    float* gxb   = c_cur + 65536;           // 262144
    float* gx    = gxb   + 262144;          // 9175040  [t][b][2048] fp32
    float* ipart = gx;                      // alias (1572864 <= 9175040), dead before gx
    u16*   h_b    = (u16*)(gx + 9175040);   // 2293760  [t][b][512] bf16
    u16*   h0b    = h_b    + 2293760;       // 65536
    u16*   emb_b  = h0b    + 65536;         // 5120000
    u16*   wih_b  = emb_b  + 5120000;       // 1048576
    u16*   wfc1_b = wih_b  + 1048576;       // 262144
    u16*   wfc2_b = wfc1_b + 262144;        // 5120000
    u16*   o_b    = wfc2_b + 5120000;       // 2293760

    // weight / embedding casts to bf16
    cast512_k<<<5000, 256, 0, stream>>>(emb,   512,  emb_b,  1280000);
    cast512_k<<<1024, 256, 0, stream>>>(W_ih,  1920, wih_b,   262144);
    cast512_k<<< 256, 256, 0, stream>>>(W_fc1, 512,  wfc1_b,   65536);
    cast512_k<<<5000, 256, 0, stream>>>(W_fc2, 512,  wfc2_b, 1280000);

    mean_k<<<704, 256, 0, stream>>>(img, mf);
    init_partial_k<<<dim3(48, 2, 4), 256, 0, stream>>>(mf, W_inh, W_inc, W_ih, ipart);
    init_combine_k<<<1536, 256, 0, stream>>>(ipart, b_ih, b_hh, b_inh, b_inc,
                                             h0b, c_cur, gxb, bar);

    // gx[t][b][n] = emb_b[seq[b][t]] . wih_b[n] + gxb[b][n]
    gemm_mfma<0,0><<<dim3(16 * 35), 256, 0, stream>>>(emb_b, EE, seqs, wih_b, nullptr,
                                                      gxb, TB, G4, gx, TB, G4,
                                                      (long)BB * G4, 35, G4, EE);

    // recurrence + overlapped fc1/fc2: ONE plain-launched persistent kernel (256 = 1/CU)
    mega_k<<<dim3(256), dim3(256), 0, stream>>>(h0b, c_cur, W_hh, gx, h_b, bar,
                                                wfc1_b, b_fc1, o_b, wfc2_b, b_fc2, out);
}

// Round 11
// 481.637 us; speedup vs baseline: 6.0397x; 1.0087x over previous
//
#include <hip/hip_runtime.h>

#define TB 35
#define BB 128
#define VV 10000
#define FF 1408
#define EE 512
#define HH 512
#define G4 2048   // 4*H
#define NBLK 32   // recurrence blocks

typedef unsigned short u16;
typedef unsigned long long u64;
typedef __attribute__((ext_vector_type(8))) short bfrag;   // 8 bf16 = 4 VGPR
typedef __attribute__((ext_vector_type(4))) float f32x4;

__device__ __forceinline__ u16 f2bf(float f) {             // RNE f32->bf16
    unsigned u = __float_as_uint(f);
    return (u16)((u + 0x7FFFu + ((u >> 16) & 1u)) >> 16);
}
__device__ __forceinline__ float fast_sig(float x) {
    return __builtin_amdgcn_rcpf(1.f + __expf(-x));
}
__device__ __forceinline__ float fast_tanh(float x) {
    return 1.f - 2.f * __builtin_amdgcn_rcpf(1.f + __expf(2.f * x));
}

__device__ __forceinline__ void gload16(const void* g, void* l) {
    __builtin_amdgcn_global_load_lds(
        (const __attribute__((address_space(1))) void*)g,
        (__attribute__((address_space(3))) void*)l, 16, 0, 0);
}

__device__ __forceinline__ void cast4(const float* __restrict__ src, int lds,
                                      u16* __restrict__ dst, long i) {
    long e = i * 4;
    long row = e >> 9; int col = (int)(e & 511);
    float4 v = *(const float4*)(src + row * lds + col);
    uint2 o;
    o.x = (unsigned)f2bf(v.x) | ((unsigned)f2bf(v.y) << 16);
    o.y = (unsigned)f2bf(v.z) | ((unsigned)f2bf(v.w) << 16);
    *(uint2*)(dst + e) = o;
}

// ---------- merged prologue: all 4 bf16 casts + region mean, one launch ----------
__global__ __launch_bounds__(256)
void prolog_k(const float* __restrict__ emb, const float* __restrict__ W_ih,
              const float* __restrict__ W_fc1, const float* __restrict__ W_fc2,
              u16* __restrict__ emb_b, u16* __restrict__ wih_b,
              u16* __restrict__ wfc1_b, u16* __restrict__ wfc2_b,
              const float* __restrict__ img, float* __restrict__ mf)
{
    long i = (long)blockIdx.x * 256 + threadIdx.x;
    if (i < 1280000)      cast4(emb,   512,  emb_b,  i);
    else if (i < 1542144) cast4(W_ih,  1920, wih_b,  i - 1280000);
    else if (i < 1607680) cast4(W_fc1, 512,  wfc1_b, i - 1542144);
    else if (i < 2887680) cast4(W_fc2, 512,  wfc2_b, i - 1607680);
    else if (i < 3067904) {
        int idx = (int)(i - 2887680);              // B*F = 180224
        int b = idx / FF, f = idx - b * FF;
        const float* p = img + (long)b * (81 * FF) + f;
        float s = 0.f;
        for (int r = 0; r < 81; ++r) s += p[r * FF];
        mf[idx] = s * (1.f / 81.f);
    }
}

// ---------- init partial GEMM (fp32): mf(128x1408) x {W_init_h|W_init_c|W_ih[:,E:]}^T ----------
__global__ __launch_bounds__(256)
void init_partial_k(const float* __restrict__ mf,
                    const float* __restrict__ Wh, const float* __restrict__ Wc,
                    const float* __restrict__ Wih,
                    float* __restrict__ part)
{
    __shared__ float As[16][68];
    __shared__ float Ws[16][68];
    const int t  = threadIdx.x;
    const int bx = blockIdx.x;              // 0..47
    const int bm = blockIdx.y * 64;
    const int kz = blockIdx.z;              // 0..3
    const float* W; int ldw; long wr0;
    if (bx < 8)       { W = Wh;       ldw = FF;   wr0 = (long)bx * 64; }
    else if (bx < 16) { W = Wc;       ldw = FF;   wr0 = (long)(bx - 8) * 64; }
    else              { W = Wih + EE; ldw = 1920; wr0 = (long)(bx - 16) * 64; }
    const int lrow = t >> 2, lc4 = (t & 3) << 2;
    const int ty = t >> 4, tx = t & 15;
    const float* arow = mf + (long)(bm + lrow) * FF;
    const float* wrow = W + (wr0 + lrow) * (long)ldw;
    float acc[4][4] = {};
    const int kbeg = kz * 352, kend2 = kbeg + 352;
    for (int k0 = kbeg; k0 < kend2; k0 += 16) {
        float4 av = *(const float4*)(arow + k0 + lc4);
        float4 wv = *(const float4*)(wrow + k0 + lc4);
        As[lc4+0][lrow]=av.x; As[lc4+1][lrow]=av.y; As[lc4+2][lrow]=av.z; As[lc4+3][lrow]=av.w;
        Ws[lc4+0][lrow]=wv.x; Ws[lc4+1][lrow]=wv.y; Ws[lc4+2][lrow]=wv.z; Ws[lc4+3][lrow]=wv.w;
        __syncthreads();
        #pragma unroll
        for (int kk = 0; kk < 16; ++kk) {
            float4 a = *(const float4*)&As[kk][ty*4];
            float4 w = *(const float4*)&Ws[kk][tx*4];
            acc[0][0]+=a.x*w.x; acc[0][1]+=a.x*w.y; acc[0][2]+=a.x*w.z; acc[0][3]+=a.x*w.w;
            acc[1][0]+=a.y*w.x; acc[1][1]+=a.y*w.y; acc[1][2]+=a.y*w.z; acc[1][3]+=a.y*w.w;
            acc[2][0]+=a.z*w.x; acc[2][1]+=a.z*w.y; acc[2][2]+=a.z*w.z; acc[2][3]+=a.z*w.w;
            acc[3][0]+=a.w*w.x; acc[3][1]+=a.w*w.y; acc[3][2]+=a.w*w.z; acc[3][3]+=a.w*w.w;
        }
        __syncthreads();
    }
    const int ncol = bx * 64;
    #pragma unroll
    for (int i = 0; i < 4; ++i) {
        long base = (long)kz * (BB*3072) + (long)(bm + ty*4 + i) * 3072 + ncol + tx*4;
        *(float4*)(part + base) = make_float4(acc[i][0], acc[i][1], acc[i][2], acc[i][3]);
    }
}

// ---------- combine init partials -> h0 (bf16), c0 (f32), gxb; zero all flags ----------
__global__ __launch_bounds__(256)
void init_combine_k(const float* __restrict__ part,
                    const float* __restrict__ b_ih, const float* __restrict__ b_hh,
                    const float* __restrict__ b_init_h, const float* __restrict__ b_init_c,
                    u16* __restrict__ h0b, float* __restrict__ c_cur, float* __restrict__ gxb,
                    unsigned* __restrict__ bar)
{
    int idx = blockIdx.x * 256 + threadIdx.x;   // 128*3072
    if (idx < 1024) bar[idx] = 0;               // rec flags bar[0..127], o_ctr bar[600+t]
    int b = idx / 3072, n = idx - b * 3072;
    float s = part[idx] + part[393216 + idx] + part[2*393216 + idx] + part[3*393216 + idx];
    if (n < 512)       h0b[b*512 + n]         = f2bf(tanhf(s + b_init_h[n]));
    else if (n < 1024) c_cur[b*512 + (n-512)] = tanhf(s + b_init_c[n-512]);
    else               gxb[b*2048 + (n-1024)] = s + b_ih[n-1024] + b_hh[n-1024];
}

// ---------- bf16 MFMA GEMM (128x128 tile, 4 waves) — used for gx ----------
template<int ACT, int OBF>
__global__ __launch_bounds__(256)
void gemm_mfma(const u16* __restrict__ A, int lda, const int* __restrict__ rowidx,
               const u16* __restrict__ W, const float* __restrict__ bias,
               const float* __restrict__ radd, int radd_div, int radd_ld,
               void* __restrict__ C, int cdiv, long csq, long csr,
               int mtiles, int N, int K)
{
    __shared__ u16 lA[4096];   // [128][32]
    __shared__ u16 lB[4096];
    int bxi, byi;
    if (mtiles > 0) {
        int nwg = gridDim.x, bid = blockIdx.x;
        int q = nwg >> 3, r = nwg & 7;
        int xcd = bid & 7, pos = bid >> 3;
        int lid = (xcd < r) ? (xcd * (q + 1) + pos)
                            : (r * (q + 1) + (xcd - r) * q + pos);
        byi = lid % mtiles;
        bxi = lid / mtiles;
    } else { bxi = blockIdx.x; byi = blockIdx.y; }

    const int t    = threadIdx.x;
    const int bm   = byi * 128;
    const int bn   = bxi * 128;
    const int lane = t & 63;
    const int wv   = t >> 6;
    const int wm   = (wv >> 1) * 64;
    const int wn   = (wv & 1) * 64;
    const int fr   = lane & 15;
    const int cc   = lane >> 4;

    const int q0 = t, q1 = t + 256;
    const int ra0 = q0 >> 2, ca0 = (q0 & 3) ^ ((ra0 >> 1) & 3);
    const int ra1 = q1 >> 2, ca1 = (q1 & 3) ^ ((ra1 >> 1) & 3);
    long arow0 = rowidx ? (long)rowidx[bm + ra0] : (long)(bm + ra0);
    long arow1 = rowidx ? (long)rowidx[bm + ra1] : (long)(bm + ra1);
    const u16* asrc0 = A + arow0 * lda + ca0 * 8;
    const u16* asrc1 = A + arow1 * lda + ca1 * 8;
    int brow0 = bn + ra0; if (brow0 > N - 1) brow0 = N - 1;
    int brow1 = bn + ra1; if (brow1 > N - 1) brow1 = N - 1;
    const u16* bsrc0 = W + (long)brow0 * K + ca0 * 8;
    const u16* bsrc1 = W + (long)brow1 * K + ca1 * 8;
    u16* adst0 = lA + q0 * 8;  u16* adst1 = lA + q1 * 8;
    u16* bdst0 = lB + q0 * 8;  u16* bdst1 = lB + q1 * 8;

    int aoff[4], boff[4];
    #pragma unroll
    for (int i = 0; i < 4; ++i) {
        int rA = wm + i * 16 + fr;
        aoff[i] = rA * 64 + ((cc ^ ((rA >> 1) & 3)) << 4);
        int rB = wn + i * 16 + fr;
        boff[i] = rB * 64 + ((cc ^ ((rB >> 1) & 3)) << 4);
    }
    const char* lac = (const char*)lA;
    const char* lbc = (const char*)lB;

    f32x4 acc[4][4] = {};
    for (int k0 = 0; k0 < K; k0 += 32) {
        gload16(asrc0 + k0, adst0);
        gload16(asrc1 + k0, adst1);
        gload16(bsrc0 + k0, bdst0);
        gload16(bsrc1 + k0, bdst1);
        __syncthreads();
        bfrag av[4], bv[4];
        #pragma unroll
        for (int i = 0; i < 4; ++i) av[i] = *(const bfrag*)(lac + aoff[i]);
        #pragma unroll
        for (int i = 0; i < 4; ++i) bv[i] = *(const bfrag*)(lbc + boff[i]);
        #pragma unroll
        for (int mi = 0; mi < 4; ++mi)
            #pragma unroll
            for (int ni = 0; ni < 4; ++ni)
                acc[mi][ni] = __builtin_amdgcn_mfma_f32_16x16x32_bf16(
                    av[mi], bv[ni], acc[mi][ni], 0, 0, 0);
        __syncthreads();
    }

    #pragma unroll
    for (int mi = 0; mi < 4; ++mi) {
        #pragma unroll
        for (int r = 0; r < 4; ++r) {
            int m = bm + wm + mi * 16 + (lane >> 4) * 4 + r;
            long cb = (long)(m / cdiv) * csq + (long)(m % cdiv) * csr;
            const float* rr = radd ? (radd + (long)(m / radd_div) * radd_ld) : nullptr;
            #pragma unroll
            for (int ni = 0; ni < 4; ++ni) {
                int n = bn + wn + ni * 16 + fr;
                if (n < N) {
                    float v = acc[mi][ni][r];
                    if (bias) v += bias[n];
                    if (rr)   v += rr[n];
                    if (ACT == 2) v = fmaxf(v, 0.f);
                    if (OBF) ((u16*)C)[cb + n] = f2bf(v);
                    else     ((float*)C)[cb + n] = v;
                }
            }
        }
    }
}

// ---------- worker tile GEMM: 128x128, K=512, A=[128][512] bf16 ----------
template<int ACT, int OBF>
__device__ __forceinline__ void tile_gemm(u16* shm, const u16* Abase, const u16* W,
                                          int bn, int N, const float* bias,
                                          char* Cbase, long crs /*bytes*/)
{
    u16* lA = shm;
    u16* lB = shm + 4096;
    const int t    = threadIdx.x;
    const int lane = t & 63;
    const int wv   = t >> 6;
    const int wm   = (wv >> 1) * 64;
    const int wn   = (wv & 1) * 64;
    const int fr   = lane & 15;
    const int cc   = lane >> 4;

    const int q0 = t, q1 = t + 256;
    const int ra0 = q0 >> 2, ca0 = (q0 & 3) ^ ((ra0 >> 1) & 3);
    const int ra1 = q1 >> 2, ca1 = (q1 & 3) ^ ((ra1 >> 1) & 3);
    const u16* asrc0 = Abase + (long)ra0 * 512 + ca0 * 8;
    const u16* asrc1 = Abase + (long)ra1 * 512 + ca1 * 8;
    int brow0 = bn + ra0; if (brow0 > N - 1) brow0 = N - 1;
    int brow1 = bn + ra1; if (brow1 > N - 1) brow1 = N - 1;
    const u16* bsrc0 = W + (long)brow0 * 512 + ca0 * 8;
    const u16* bsrc1 = W + (long)brow1 * 512 + ca1 * 8;
    u16* adst0 = lA + q0 * 8;  u16* adst1 = lA + q1 * 8;
    u16* bdst0 = lB + q0 * 8;  u16* bdst1 = lB + q1 * 8;

    int aoff[4], boff[4];
    #pragma unroll
    for (int i = 0; i < 4; ++i) {
        int rA = wm + i * 16 + fr;
        aoff[i] = rA * 64 + ((cc ^ ((rA >> 1) & 3)) << 4);
        int rB = wn + i * 16 + fr;
        boff[i] = 8192 + rB * 64 + ((cc ^ ((rB >> 1) & 3)) << 4);
    }
    const char* lc = (const char*)lA;

    f32x4 acc[4][4] = {};
    for (int k0 = 0; k0 < 512; k0 += 32) {
        gload16(asrc0 + k0, adst0);
        gload16(asrc1 + k0, adst1);
        gload16(bsrc0 + k0, bdst0);
        gload16(bsrc1 + k0, bdst1);
        __syncthreads();
        bfrag av[4], bv[4];
        #pragma unroll
        for (int i = 0; i < 4; ++i) av[i] = *(const bfrag*)(lc + aoff[i]);
        #pragma unroll
        for (int i = 0; i < 4; ++i) bv[i] = *(const bfrag*)(lc + boff[i]);
        #pragma unroll
        for (int mi = 0; mi < 4; ++mi)
            #pragma unroll
            for (int ni = 0; ni < 4; ++ni)
                acc[mi][ni] = __builtin_amdgcn_mfma_f32_16x16x32_bf16(
                    av[mi], bv[ni], acc[mi][ni], 0, 0, 0);
        __syncthreads();
    }

    #pragma unroll
    for (int mi = 0; mi < 4; ++mi) {
        #pragma unroll
        for (int r = 0; r < 4; ++r) {
            int m = wm + mi * 16 + (lane >> 4) * 4 + r;
            char* crow = Cbase + (long)m * crs;
            #pragma unroll
            for (int ni = 0; ni < 4; ++ni) {
                int n = bn + wn + ni * 16 + fr;
                if (n < N) {
                    float v = acc[mi][ni][r] + bias[n];
                    if (ACT == 2) v = fmaxf(v, 0.f);
                    if (OBF)
                        __hip_atomic_store((u16*)crow + n, f2bf(v),
                                           __ATOMIC_RELAXED, __HIP_MEMORY_SCOPE_AGENT);
                    else
                        __builtin_nontemporal_store(v, (float*)crow + n);
                }
            }
        }
    }
}

// ---------- mega kernel: blocks 0-31 recurrence (PER-WAVE barrier), 32-63 fc1, 64-255 fc2 ----------
// Per-wave sync: wave w of block jb computes batch rows [32w,32w+32) x j-slice jb and
// needs only wave-w rows of h from all blocks -> sync group {wave w of all 32 blocks},
// flags bar[w*32+jb] (monotonic t+1). Producer: WT h stores -> s_waitcnt vmcnt(0) +
// sched_barrier -> lane0 flag store. Consumer: 32-lane parallel poll, __all(v>t),
// per-wave agent acquire fence. NO __syncthreads in the loop (skew absorbed per wave).
__global__ __launch_bounds__(256, 1)
void mega_k(const u16* __restrict__ h0b, const float* __restrict__ c0,
            const float* __restrict__ Whh, const float* __restrict__ gx,
            u16* __restrict__ h_b, unsigned* __restrict__ bar,
            const u16* __restrict__ wfc1, const float* __restrict__ b_fc1,
            u16* __restrict__ o_b,
            const u16* __restrict__ wfc2, const float* __restrict__ b_fc2,
            float* __restrict__ out)
{
    __shared__ alignas(16) u16 shm[32768];   // 64 KB: rec Wf / worker lA+lB
    const int bid  = blockIdx.x;
    const int t256 = threadIdx.x;
    const int lane = t256 & 63;

    if (bid < NBLK) {
        // ======== recurrence role ========
        bfrag* Wf = (bfrag*)shm;
        const int jb = bid;
        const int w  = t256 >> 6;
        const int fr = lane & 15;
        const int cc = lane >> 4;

        for (int q = 0; q < 16; ++q) {
            int flat = t256 + q * 256;
            int r = flat >> 6, kg = flat & 63;
            int mi = r >> 4, jj = r & 15;
            int kk = kg >> 2, c2 = kg & 3;
            const float* src = Whh + (long)(mi * 512 + jb * 16 + jj) * 512 + kg * 8;
            float4 s0 = *(const float4*)src;
            float4 s1 = *(const float4*)(src + 4);
            bfrag p;
            p[0] = (short)f2bf(s0.x); p[1] = (short)f2bf(s0.y);
            p[2] = (short)f2bf(s0.z); p[3] = (short)f2bf(s0.w);
            p[4] = (short)f2bf(s1.x); p[5] = (short)f2bf(s1.y);
            p[6] = (short)f2bf(s1.z); p[7] = (short)f2bf(s1.w);
            Wf[(kk * 4 + mi) * 64 + c2 * 16 + jj] = p;
        }

        const int b0    = w * 32 + fr;
        const int jcol  = jb * 16 + cc * 4;
        unsigned* fl    = bar + w * 32;     // this wave-group's 32 flags

        f32x4 creg[2];
        #pragma unroll
        for (int ni = 0; ni < 2; ++ni)
            creg[ni] = *(const f32x4*)(c0 + (long)(b0 + ni*16) * 512 + jcol);

        f32x4 gxc[4][2];
        #pragma unroll
        for (int ni = 0; ni < 2; ++ni) {
            const float* gp = gx + (long)(b0 + ni*16) * G4 + jcol;
            #pragma unroll
            for (int g = 0; g < 4; ++g) gxc[g][ni] = *(const f32x4*)(gp + g * 512);
        }

        __syncthreads();                    // Wf ready (only block-level sync)

        const u16* hsrc = h0b;
        for (int t = 0; t < TB; ++t) {
            bfrag hreg[2][16];
            #pragma unroll
            for (int ni = 0; ni < 2; ++ni) {
                const u16* hp = hsrc + (long)(b0 + ni*16) * 512 + cc * 8;
                #pragma unroll
                for (int kk = 0; kk < 16; ++kk)
                    hreg[ni][kk] = *(const bfrag*)(hp + kk * 32);
            }
            // prefetch next gx early: its latency hides under MFMA, so the
            // vmcnt(0) drain below sees it already landed
            f32x4 gxn[4][2];
            if (t < TB - 1) {
                #pragma unroll
                for (int ni = 0; ni < 2; ++ni) {
                    const float* gp = gx + ((long)(t+1) * BB + b0 + ni*16) * G4 + jcol;
                    #pragma unroll
                    for (int g = 0; g < 4; ++g) gxn[g][ni] = *(const f32x4*)(gp + g * 512);
                }
            }

            f32x4 acc[4][2] = {};
            #pragma unroll
            for (int kk = 0; kk < 16; ++kk) {
                bfrag av0 = Wf[(kk*4 + 0) * 64 + lane];
                bfrag av1 = Wf[(kk*4 + 1) * 64 + lane];
                bfrag av2 = Wf[(kk*4 + 2) * 64 + lane];
                bfrag av3 = Wf[(kk*4 + 3) * 64 + lane];
                #pragma unroll
                for (int ni = 0; ni < 2; ++ni) {
                    acc[0][ni] = __builtin_amdgcn_mfma_f32_16x16x32_bf16(av0, hreg[ni][kk], acc[0][ni], 0,0,0);
                    acc[1][ni] = __builtin_amdgcn_mfma_f32_16x16x32_bf16(av1, hreg[ni][kk], acc[1][ni], 0,0,0);
                    acc[2][ni] = __builtin_amdgcn_mfma_f32_16x16x32_bf16(av2, hreg[ni][kk], acc[2][ni], 0,0,0);
                    acc[3][ni] = __builtin_amdgcn_mfma_f32_16x16x32_bf16(av3, hreg[ni][kk], acc[3][ni], 0,0,0);
                }
            }

            u16* hd = h_b + (long)t * (BB*HH);
            #pragma unroll
            for (int ni = 0; ni < 2; ++ni) {
                u64 hq = 0;
                #pragma unroll
                for (int rr = 0; rr < 4; ++rr) {
                    float ig = fast_sig (acc[0][ni][rr] + gxc[0][ni][rr]);
                    float fg = fast_sig (acc[1][ni][rr] + gxc[1][ni][rr]);
                    float gg = fast_tanh(acc[2][ni][rr] + gxc[2][ni][rr]);
                    float og = fast_sig (acc[3][ni][rr] + gxc[3][ni][rr]);
                    float c  = fg * creg[ni][rr] + ig * gg;
                    creg[ni][rr] = c;
                    hq |= (u64)f2bf(og * fast_tanh(c)) << (rr * 16);
                }
                __hip_atomic_store((u64*)(hd + (long)(b0 + ni*16) * 512 + jcol), hq,
                                   __ATOMIC_RELAXED, __HIP_MEMORY_SCOPE_AGENT);
            }
            hsrc = hd;

            // release: drain THIS wave's stores (gx prefetch already landed), then flag
            asm volatile("s_waitcnt vmcnt(0)" ::: "memory");
            __builtin_amdgcn_sched_barrier(0);
            if (lane == 0)
                __hip_atomic_store(&fl[jb], (unsigned)(t + 1),
                                   __ATOMIC_RELAXED, __HIP_MEMORY_SCOPE_AGENT);
            if (t < TB - 1) {
                // acquire: 32 lanes poll this group's 32 flags in parallel
                while (true) {
                    unsigned v = __hip_atomic_load(&fl[lane & 31],
                                                   __ATOMIC_RELAXED, __HIP_MEMORY_SCOPE_AGENT);
                    if (__all(v > (unsigned)t)) break;
                    __builtin_amdgcn_s_sleep(1);
                }
                __builtin_amdgcn_fence(__ATOMIC_ACQUIRE, "agent");  // inv caches, no wb
                #pragma unroll
                for (int g = 0; g < 4; ++g)
                    #pragma unroll
                    for (int ni = 0; ni < 2; ++ni) gxc[g][ni] = gxn[g][ni];
            }
        }
    } else if (bid < 64) {
        // ======== fc1 workers: o_t = relu(h_t @ Wfc1^T + b), 4 tiles/step ========
        const int wkr = bid - 32;                 // 0..31
        for (int g = wkr; g < TB * 4; g += 32) {
            int tt = g >> 2, nt4 = g & 3;
            if (t256 < 64) {                       // wave 0: poll ALL 128 per-wave flags
                while (true) {
                    unsigned v0 = __hip_atomic_load(&bar[lane],
                                                    __ATOMIC_RELAXED, __HIP_MEMORY_SCOPE_AGENT);
                    unsigned v1 = __hip_atomic_load(&bar[64 + lane],
                                                    __ATOMIC_RELAXED, __HIP_MEMORY_SCOPE_AGENT);
                    if (__all((v0 > (unsigned)tt) && (v1 > (unsigned)tt))) break;
                    __builtin_amdgcn_s_sleep(8);
                }
            }
            __syncthreads();
            __builtin_amdgcn_fence(__ATOMIC_ACQUIRE, "agent");
            tile_gemm<2,1>(shm, h_b + (long)tt * (BB*HH), wfc1, nt4 * 128, HH, b_fc1,
                           (char*)(o_b + (long)tt * (BB*HH)), HH * 2);
            __syncthreads();                      // drain WT o stores (all waves)
            if (t256 == 0)
                __hip_atomic_fetch_add(bar + 600 + tt, 1u,
                                       __ATOMIC_RELAXED, __HIP_MEMORY_SCOPE_AGENT);
        }
    } else {
        // ======== fc2 workers: out[:,t,:] = o_t @ Wfc2^T + b, 79 tiles/step ========
        const int wkr = bid - 64;                 // 0..191
        for (int g = wkr; g < TB * 79; g += 192) {
            int tt = g / 79, nt = g - tt * 79;
            if (t256 == 0) {
                while (__hip_atomic_load(bar + 600 + tt, __ATOMIC_RELAXED,
                                         __HIP_MEMORY_SCOPE_AGENT) < 4)
                    __builtin_amdgcn_s_sleep(8);
            }
            __syncthreads();
            __builtin_amdgcn_fence(__ATOMIC_ACQUIRE, "agent");
            tile_gemm<0,0>(shm, o_b + (long)tt * (BB*HH), wfc2, nt * 128, VV, b_fc2,
                           (char*)(out + (long)tt * VV), (long)TB * VV * 4);
        }
    }
}

extern "C" void kernel_launch(void* const* d_in, const int* in_sizes, int n_in,
                              void* d_out, int out_size, void* d_ws, size_t ws_size,
                              hipStream_t stream)
{
    const float* img    = (const float*)d_in[0];
    const int*   seqs   = (const int*)d_in[1];
    const float* emb    = (const float*)d_in[3];
    const float* W_ih   = (const float*)d_in[4];
    const float* b_ih   = (const float*)d_in[5];
    const float* W_hh   = (const float*)d_in[6];
    const float* b_hh   = (const float*)d_in[7];
    const float* W_inh  = (const float*)d_in[8];
    const float* b_inh  = (const float*)d_in[9];
    const float* W_inc  = (const float*)d_in[10];
    const float* b_inc  = (const float*)d_in[11];
    const float* W_fc1  = (const float*)d_in[12];
    const float* b_fc1  = (const float*)d_in[13];
    const float* W_fc2  = (const float*)d_in[14];
    const float* b_fc2  = (const float*)d_in[15];
    float* out = (float*)d_out;

    float*    ws  = (float*)d_ws;
    unsigned* bar = (unsigned*)ws;          // 1024 reserved; rec flags bar[0..127], o_ctr bar[600+t]
    float* mf    = ws    + 1024;            // 180224
    float* c_cur = mf    + 180224;          // 65536
    float* gxb   = c_cur + 65536;           // 262144
    float* gx    = gxb   + 262144;          // 9175040  [t][b][2048] fp32
    float* ipart = gx;                      // alias (1572864 <= 9175040), dead before gx
    u16*   h_b    = (u16*)(gx + 9175040);   // 2293760  [t][b][512] bf16
    u16*   h0b    = h_b    + 2293760;       // 65536
    u16*   emb_b  = h0b    + 65536;         // 5120000
    u16*   wih_b  = emb_b  + 5120000;       // 1048576
    u16*   wfc1_b = wih_b  + 1048576;       // 262144
    u16*   wfc2_b = wfc1_b + 262144;        // 5120000
    u16*   o_b    = wfc2_b + 5120000;       // 2293760

    // merged prologue: 4 casts + region mean in one launch
    prolog_k<<<11984, 256, 0, stream>>>(emb, W_ih, W_fc1, W_fc2,
                                        emb_b, wih_b, wfc1_b, wfc2_b, img, mf);

    init_partial_k<<<dim3(48, 2, 4), 256, 0, stream>>>(mf, W_inh, W_inc, W_ih, ipart);
    init_combine_k<<<1536, 256, 0, stream>>>(ipart, b_ih, b_hh, b_inh, b_inc,
                                             h0b, c_cur, gxb, bar);

    // gx[t][b][n] = emb_b[seq[b][t]] . wih_b[n] + gxb[b][n]
    gemm_mfma<0,0><<<dim3(16 * 35), 256, 0, stream>>>(emb_b, EE, seqs, wih_b, nullptr,
                                                      gxb, TB, G4, gx, TB, G4,
                                                      (long)BB * G4, 35, G4, EE);

    // recurrence + overlapped fc1/fc2: ONE plain-launched persistent kernel (256 = 1/CU)
    mega_k<<<dim3(256), dim3(256), 0, stream>>>(h0b, c_cur, W_hh, gx, h_b, bar,
                                                wfc1_b, b_fc1, o_b, wfc2_b, b_fc2, out);
}

// Round 13
// 481.590 us; speedup vs baseline: 6.0403x; 1.0001x over previous
//
#include <hip/hip_runtime.h>

#define TB 35
#define BB 128
#define VV 10000
#define FF 1408
#define EE 512
#define HH 512
#define G4 2048   // 4*H
#define NBLK 32   // recurrence blocks

typedef unsigned short u16;
typedef unsigned long long u64;
typedef __attribute__((ext_vector_type(8))) short bfrag;   // 8 bf16 = 4 VGPR
typedef __attribute__((ext_vector_type(4))) float f32x4;

__device__ __forceinline__ u16 f2bf(float f) {             // RNE f32->bf16
    unsigned u = __float_as_uint(f);
    return (u16)((u + 0x7FFFu + ((u >> 16) & 1u)) >> 16);
}
__device__ __forceinline__ float fast_sig(float x) {
    return __builtin_amdgcn_rcpf(1.f + __expf(-x));
}
__device__ __forceinline__ float fast_tanh(float x) {
    return 1.f - 2.f * __builtin_amdgcn_rcpf(1.f + __expf(2.f * x));
}

__device__ __forceinline__ void gload16(const void* g, void* l) {
    __builtin_amdgcn_global_load_lds(
        (const __attribute__((address_space(1))) void*)g,
        (__attribute__((address_space(3))) void*)l, 16, 0, 0);
}

__device__ __forceinline__ void cast4(const float* __restrict__ src, int lds,
                                      u16* __restrict__ dst, long i) {
    long e = i * 4;
    long row = e >> 9; int col = (int)(e & 511);
    float4 v = *(const float4*)(src + row * lds + col);
    uint2 o;
    o.x = (unsigned)f2bf(v.x) | ((unsigned)f2bf(v.y) << 16);
    o.y = (unsigned)f2bf(v.z) | ((unsigned)f2bf(v.w) << 16);
    *(uint2*)(dst + e) = o;
}

// ---------- merged prologue: all 4 bf16 casts + region mean, one launch ----------
__global__ __launch_bounds__(256)
void prolog_k(const float* __restrict__ emb, const float* __restrict__ W_ih,
              const float* __restrict__ W_fc1, const float* __restrict__ W_fc2,
              u16* __restrict__ emb_b, u16* __restrict__ wih_b,
              u16* __restrict__ wfc1_b, u16* __restrict__ wfc2_b,
              const float* __restrict__ img, float* __restrict__ mf)
{
    long i = (long)blockIdx.x * 256 + threadIdx.x;
    if (i < 1280000)      cast4(emb,   512,  emb_b,  i);
    else if (i < 1542144) cast4(W_ih,  1920, wih_b,  i - 1280000);
    else if (i < 1607680) cast4(W_fc1, 512,  wfc1_b, i - 1542144);
    else if (i < 2887680) cast4(W_fc2, 512,  wfc2_b, i - 1607680);
    else if (i < 3067904) {
        int idx = (int)(i - 2887680);              // B*F = 180224
        int b = idx / FF, f = idx - b * FF;
        const float* p = img + (long)b * (81 * FF) + f;
        float s = 0.f;
        for (int r = 0; r < 81; ++r) s += p[r * FF];
        mf[idx] = s * (1.f / 81.f);
    }
}

// ---------- init partial GEMM (fp32): mf(128x1408) x {W_init_h|W_init_c|W_ih[:,E:]}^T ----------
__global__ __launch_bounds__(256)
void init_partial_k(const float* __restrict__ mf,
                    const float* __restrict__ Wh, const float* __restrict__ Wc,
                    const float* __restrict__ Wih,
                    float* __restrict__ part)
{
    __shared__ float As[16][68];
    __shared__ float Ws[16][68];
    const int t  = threadIdx.x;
    const int bx = blockIdx.x;              // 0..47
    const int bm = blockIdx.y * 64;
    const int kz = blockIdx.z;              // 0..3
    const float* W; int ldw; long wr0;
    if (bx < 8)       { W = Wh;       ldw = FF;   wr0 = (long)bx * 64; }
    else if (bx < 16) { W = Wc;       ldw = FF;   wr0 = (long)(bx - 8) * 64; }
    else              { W = Wih + EE; ldw = 1920; wr0 = (long)(bx - 16) * 64; }
    const int lrow = t >> 2, lc4 = (t & 3) << 2;
    const int ty = t >> 4, tx = t & 15;
    const float* arow = mf + (long)(bm + lrow) * FF;
    const float* wrow = W + (wr0 + lrow) * (long)ldw;
    float acc[4][4] = {};
    const int kbeg = kz * 352, kend2 = kbeg + 352;
    for (int k0 = kbeg; k0 < kend2; k0 += 16) {
        float4 av = *(const float4*)(arow + k0 + lc4);
        float4 wv = *(const float4*)(wrow + k0 + lc4);
        As[lc4+0][lrow]=av.x; As[lc4+1][lrow]=av.y; As[lc4+2][lrow]=av.z; As[lc4+3][lrow]=av.w;
        Ws[lc4+0][lrow]=wv.x; Ws[lc4+1][lrow]=wv.y; Ws[lc4+2][lrow]=wv.z; Ws[lc4+3][lrow]=wv.w;
        __syncthreads();
        #pragma unroll
        for (int kk = 0; kk < 16; ++kk) {
            float4 a = *(const float4*)&As[kk][ty*4];
            float4 w = *(const float4*)&Ws[kk][tx*4];
            acc[0][0]+=a.x*w.x; acc[0][1]+=a.x*w.y; acc[0][2]+=a.x*w.z; acc[0][3]+=a.x*w.w;
            acc[1][0]+=a.y*w.x; acc[1][1]+=a.y*w.y; acc[1][2]+=a.y*w.z; acc[1][3]+=a.y*w.w;
            acc[2][0]+=a.z*w.x; acc[2][1]+=a.z*w.y; acc[2][2]+=a.z*w.z; acc[2][3]+=a.z*w.w;
            acc[3][0]+=a.w*w.x; acc[3][1]+=a.w*w.y; acc[3][2]+=a.w*w.z; acc[3][3]+=a.w*w.w;
        }
        __syncthreads();
    }
    const int ncol = bx * 64;
    #pragma unroll
    for (int i = 0; i < 4; ++i) {
        long base = (long)kz * (BB*3072) + (long)(bm + ty*4 + i) * 3072 + ncol + tx*4;
        *(float4*)(part + base) = make_float4(acc[i][0], acc[i][1], acc[i][2], acc[i][3]);
    }
}

// ---------- combine init partials -> h0 (bf16), c0 (f32), gxb; zero all flags ----------
__global__ __launch_bounds__(256)
void init_combine_k(const float* __restrict__ part,
                    const float* __restrict__ b_ih, const float* __restrict__ b_hh,
                    const float* __restrict__ b_init_h, const float* __restrict__ b_init_c,
                    u16* __restrict__ h0b, float* __restrict__ c_cur, float* __restrict__ gxb,
                    unsigned* __restrict__ bar)
{
    int idx = blockIdx.x * 256 + threadIdx.x;   // 128*3072
    if (idx < 1024) bar[idx] = 0;               // rec flags bar[0..127], o_ctr bar[600+t]
    int b = idx / 3072, n = idx - b * 3072;
    float s = part[idx] + part[393216 + idx] + part[2*393216 + idx] + part[3*393216 + idx];
    if (n < 512)       h0b[b*512 + n]         = f2bf(tanhf(s + b_init_h[n]));
    else if (n < 1024) c_cur[b*512 + (n-512)] = tanhf(s + b_init_c[n-512]);
    else               gxb[b*2048 + (n-1024)] = s + b_ih[n-1024] + b_hh[n-1024];
}

// ---------- bf16 MFMA GEMM (128x128 tile, 4 waves) — used for gx ----------
template<int ACT, int OBF>
__global__ __launch_bounds__(256)
void gemm_mfma(const u16* __restrict__ A, int lda, const int* __restrict__ rowidx,
               const u16* __restrict__ W, const float* __restrict__ bias,
               const float* __restrict__ radd, int radd_div, int radd_ld,
               void* __restrict__ C, int cdiv, long csq, long csr,
               int mtiles, int N, int K)
{
    __shared__ u16 lA[4096];   // [128][32]
    __shared__ u16 lB[4096];
    int bxi, byi;
    if (mtiles > 0) {
        int nwg = gridDim.x, bid = blockIdx.x;
        int q = nwg >> 3, r = nwg & 7;
        int xcd = bid & 7, pos = bid >> 3;
        int lid = (xcd < r) ? (xcd * (q + 1) + pos)
                            : (r * (q + 1) + (xcd - r) * q + pos);
        byi = lid % mtiles;
        bxi = lid / mtiles;
    } else { bxi = blockIdx.x; byi = blockIdx.y; }

    const int t    = threadIdx.x;
    const int bm   = byi * 128;
    const int bn   = bxi * 128;
    const int lane = t & 63;
    const int wv   = t >> 6;
    const int wm   = (wv >> 1) * 64;
    const int wn   = (wv & 1) * 64;
    const int fr   = lane & 15;
    const int cc   = lane >> 4;

    const int q0 = t, q1 = t + 256;
    const int ra0 = q0 >> 2, ca0 = (q0 & 3) ^ ((ra0 >> 1) & 3);
    const int ra1 = q1 >> 2, ca1 = (q1 & 3) ^ ((ra1 >> 1) & 3);
    long arow0 = rowidx ? (long)rowidx[bm + ra0] : (long)(bm + ra0);
    long arow1 = rowidx ? (long)rowidx[bm + ra1] : (long)(bm + ra1);
    const u16* asrc0 = A + arow0 * lda + ca0 * 8;
    const u16* asrc1 = A + arow1 * lda + ca1 * 8;
    int brow0 = bn + ra0; if (brow0 > N - 1) brow0 = N - 1;
    int brow1 = bn + ra1; if (brow1 > N - 1) brow1 = N - 1;
    const u16* bsrc0 = W + (long)brow0 * K + ca0 * 8;
    const u16* bsrc1 = W + (long)brow1 * K + ca1 * 8;
    u16* adst0 = lA + q0 * 8;  u16* adst1 = lA + q1 * 8;
    u16* bdst0 = lB + q0 * 8;  u16* bdst1 = lB + q1 * 8;

    int aoff[4], boff[4];
    #pragma unroll
    for (int i = 0; i < 4; ++i) {
        int rA = wm + i * 16 + fr;
        aoff[i] = rA * 64 + ((cc ^ ((rA >> 1) & 3)) << 4);
        int rB = wn + i * 16 + fr;
        boff[i] = rB * 64 + ((cc ^ ((rB >> 1) & 3)) << 4);
    }
    const char* lac = (const char*)lA;
    const char* lbc = (const char*)lB;

    f32x4 acc[4][4] = {};
    for (int k0 = 0; k0 < K; k0 += 32) {
        gload16(asrc0 + k0, adst0);
        gload16(asrc1 + k0, adst1);
        gload16(bsrc0 + k0, bdst0);
        gload16(bsrc1 + k0, bdst1);
        __syncthreads();
        bfrag av[4], bv[4];
        #pragma unroll
        for (int i = 0; i < 4; ++i) av[i] = *(const bfrag*)(lac + aoff[i]);
        #pragma unroll
        for (int i = 0; i < 4; ++i) bv[i] = *(const bfrag*)(lbc + boff[i]);
        #pragma unroll
        for (int mi = 0; mi < 4; ++mi)
            #pragma unroll
            for (int ni = 0; ni < 4; ++ni)
                acc[mi][ni] = __builtin_amdgcn_mfma_f32_16x16x32_bf16(
                    av[mi], bv[ni], acc[mi][ni], 0, 0, 0);
        __syncthreads();
    }

    #pragma unroll
    for (int mi = 0; mi < 4; ++mi) {
        #pragma unroll
        for (int r = 0; r < 4; ++r) {
            int m = bm + wm + mi * 16 + (lane >> 4) * 4 + r;
            long cb = (long)(m / cdiv) * csq + (long)(m % cdiv) * csr;
            const float* rr = radd ? (radd + (long)(m / radd_div) * radd_ld) : nullptr;
            #pragma unroll
            for (int ni = 0; ni < 4; ++ni) {
                int n = bn + wn + ni * 16 + fr;
                if (n < N) {
                    float v = acc[mi][ni][r];
                    if (bias) v += bias[n];
                    if (rr)   v += rr[n];
                    if (ACT == 2) v = fmaxf(v, 0.f);
                    if (OBF) ((u16*)C)[cb + n] = f2bf(v);
                    else     ((float*)C)[cb + n] = v;
                }
            }
        }
    }
}

// ---------- worker tile GEMM: 128x128, K=512, A=[128][512] bf16 ----------
template<int ACT, int OBF>
__device__ __forceinline__ void tile_gemm(u16* shm, const u16* Abase, const u16* W,
                                          int bn, int N, const float* bias,
                                          char* Cbase, long crs /*bytes*/)
{
    u16* lA = shm;
    u16* lB = shm + 4096;
    const int t    = threadIdx.x;
    const int lane = t & 63;
    const int wv   = t >> 6;
    const int wm   = (wv >> 1) * 64;
    const int wn   = (wv & 1) * 64;
    const int fr   = lane & 15;
    const int cc   = lane >> 4;

    const int q0 = t, q1 = t + 256;
    const int ra0 = q0 >> 2, ca0 = (q0 & 3) ^ ((ra0 >> 1) & 3);
    const int ra1 = q1 >> 2, ca1 = (q1 & 3) ^ ((ra1 >> 1) & 3);
    const u16* asrc0 = Abase + (long)ra0 * 512 + ca0 * 8;
    const u16* asrc1 = Abase + (long)ra1 * 512 + ca1 * 8;
    int brow0 = bn + ra0; if (brow0 > N - 1) brow0 = N - 1;
    int brow1 = bn + ra1; if (brow1 > N - 1) brow1 = N - 1;
    const u16* bsrc0 = W + (long)brow0 * 512 + ca0 * 8;
    const u16* bsrc1 = W + (long)brow1 * 512 + ca1 * 8;
    u16* adst0 = lA + q0 * 8;  u16* adst1 = lA + q1 * 8;
    u16* bdst0 = lB + q0 * 8;  u16* bdst1 = lB + q1 * 8;

    int aoff[4], boff[4];
    #pragma unroll
    for (int i = 0; i < 4; ++i) {
        int rA = wm + i * 16 + fr;
        aoff[i] = rA * 64 + ((cc ^ ((rA >> 1) & 3)) << 4);
        int rB = wn + i * 16 + fr;
        boff[i] = 8192 + rB * 64 + ((cc ^ ((rB >> 1) & 3)) << 4);
    }
    const char* lc = (const char*)lA;

    f32x4 acc[4][4] = {};
    for (int k0 = 0; k0 < 512; k0 += 32) {
        gload16(asrc0 + k0, adst0);
        gload16(asrc1 + k0, adst1);
        gload16(bsrc0 + k0, bdst0);
        gload16(bsrc1 + k0, bdst1);
        __syncthreads();
        bfrag av[4], bv[4];
        #pragma unroll
        for (int i = 0; i < 4; ++i) av[i] = *(const bfrag*)(lc + aoff[i]);
        #pragma unroll
        for (int i = 0; i < 4; ++i) bv[i] = *(const bfrag*)(lc + boff[i]);
        #pragma unroll
        for (int mi = 0; mi < 4; ++mi)
            #pragma unroll
            for (int ni = 0; ni < 4; ++ni)
                acc[mi][ni] = __builtin_amdgcn_mfma_f32_16x16x32_bf16(
                    av[mi], bv[ni], acc[mi][ni], 0, 0, 0);
        __syncthreads();
    }

    #pragma unroll
    for (int mi = 0; mi < 4; ++mi) {
        #pragma unroll
        for (int r = 0; r < 4; ++r) {
            int m = wm + mi * 16 + (lane >> 4) * 4 + r;
            char* crow = Cbase + (long)m * crs;
            #pragma unroll
            for (int ni = 0; ni < 4; ++ni) {
                int n = bn + wn + ni * 16 + fr;
                if (n < N) {
                    float v = acc[mi][ni][r] + bias[n];
                    if (ACT == 2) v = fmaxf(v, 0.f);
                    if (OBF)
                        __hip_atomic_store((u16*)crow + n, f2bf(v),
                                           __ATOMIC_RELAXED, __HIP_MEMORY_SCOPE_AGENT);
                    else
                        __builtin_nontemporal_store(v, (float*)crow + n);
                }
            }
        }
    }
}

// ---------- mega kernel: blocks 0-31 recurrence (PER-WAVE barrier), 32-63 fc1, 64-255 fc2 ----------
// R11 configuration (last known replay-stable): per-wave flag barrier + per-step
// agent acquire fences on every consumer. The fence-free variant (R12) passed the
// first call but failed graph-replay re-validation -> fences are REQUIRED.
__global__ __launch_bounds__(256, 1)
void mega_k(const u16* __restrict__ h0b, const float* __restrict__ c0,
            const float* __restrict__ Whh, const float* __restrict__ gx,
            u16* __restrict__ h_b, unsigned* __restrict__ bar,
            const u16* __restrict__ wfc1, const float* __restrict__ b_fc1,
            u16* __restrict__ o_b,
            const u16* __restrict__ wfc2, const float* __restrict__ b_fc2,
            float* __restrict__ out)
{
    __shared__ alignas(16) u16 shm[32768];   // 64 KB: rec Wf / worker lA+lB
    const int bid  = blockIdx.x;
    const int t256 = threadIdx.x;
    const int lane = t256 & 63;

    if (bid < NBLK) {
        // ======== recurrence role ========
        bfrag* Wf = (bfrag*)shm;
        const int jb = bid;
        const int w  = t256 >> 6;
        const int fr = lane & 15;
        const int cc = lane >> 4;

        for (int q = 0; q < 16; ++q) {
            int flat = t256 + q * 256;
            int r = flat >> 6, kg = flat & 63;
            int mi = r >> 4, jj = r & 15;
            int kk = kg >> 2, c2 = kg & 3;
            const float* src = Whh + (long)(mi * 512 + jb * 16 + jj) * 512 + kg * 8;
            float4 s0 = *(const float4*)src;
            float4 s1 = *(const float4*)(src + 4);
            bfrag p;
            p[0] = (short)f2bf(s0.x); p[1] = (short)f2bf(s0.y);
            p[2] = (short)f2bf(s0.z); p[3] = (short)f2bf(s0.w);
            p[4] = (short)f2bf(s1.x); p[5] = (short)f2bf(s1.y);
            p[6] = (short)f2bf(s1.z); p[7] = (short)f2bf(s1.w);
            Wf[(kk * 4 + mi) * 64 + c2 * 16 + jj] = p;
        }

        const int b0    = w * 32 + fr;
        const int jcol  = jb * 16 + cc * 4;
        unsigned* fl    = bar + w * 32;     // this wave-group's 32 flags

        f32x4 creg[2];
        #pragma unroll
        for (int ni = 0; ni < 2; ++ni)
            creg[ni] = *(const f32x4*)(c0 + (long)(b0 + ni*16) * 512 + jcol);

        f32x4 gxc[4][2];
        #pragma unroll
        for (int ni = 0; ni < 2; ++ni) {
            const float* gp = gx + (long)(b0 + ni*16) * G4 + jcol;
            #pragma unroll
            for (int g = 0; g < 4; ++g) gxc[g][ni] = *(const f32x4*)(gp + g * 512);
        }

        __syncthreads();                    // Wf ready (only block-level sync)

        const u16* hsrc = h0b;
        for (int t = 0; t < TB; ++t) {
            bfrag hreg[2][16];
            #pragma unroll
            for (int ni = 0; ni < 2; ++ni) {
                const u16* hp = hsrc + (long)(b0 + ni*16) * 512 + cc * 8;
                #pragma unroll
                for (int kk = 0; kk < 16; ++kk)
                    hreg[ni][kk] = *(const bfrag*)(hp + kk * 32);
            }
            // prefetch next gx early: its latency hides under MFMA, so the
            // vmcnt(0) drain below sees it already landed
            f32x4 gxn[4][2];
            if (t < TB - 1) {
                #pragma unroll
                for (int ni = 0; ni < 2; ++ni) {
                    const float* gp = gx + ((long)(t+1) * BB + b0 + ni*16) * G4 + jcol;
                    #pragma unroll
                    for (int g = 0; g < 4; ++g) gxn[g][ni] = *(const f32x4*)(gp + g * 512);
                }
            }

            f32x4 acc[4][2] = {};
            #pragma unroll
            for (int kk = 0; kk < 16; ++kk) {
                bfrag av0 = Wf[(kk*4 + 0) * 64 + lane];
                bfrag av1 = Wf[(kk*4 + 1) * 64 + lane];
                bfrag av2 = Wf[(kk*4 + 2) * 64 + lane];
                bfrag av3 = Wf[(kk*4 + 3) * 64 + lane];
                #pragma unroll
                for (int ni = 0; ni < 2; ++ni) {
                    acc[0][ni] = __builtin_amdgcn_mfma_f32_16x16x32_bf16(av0, hreg[ni][kk], acc[0][ni], 0,0,0);
                    acc[1][ni] = __builtin_amdgcn_mfma_f32_16x16x32_bf16(av1, hreg[ni][kk], acc[1][ni], 0,0,0);
                    acc[2][ni] = __builtin_amdgcn_mfma_f32_16x16x32_bf16(av2, hreg[ni][kk], acc[2][ni], 0,0,0);
                    acc[3][ni] = __builtin_amdgcn_mfma_f32_16x16x32_bf16(av3, hreg[ni][kk], acc[3][ni], 0,0,0);
                }
            }

            u16* hd = h_b + (long)t * (BB*HH);
            #pragma unroll
            for (int ni = 0; ni < 2; ++ni) {
                u64 hq = 0;
                #pragma unroll
                for (int rr = 0; rr < 4; ++rr) {
                    float ig = fast_sig (acc[0][ni][rr] + gxc[0][ni][rr]);
                    float fg = fast_sig (acc[1][ni][rr] + gxc[1][ni][rr]);
                    float gg = fast_tanh(acc[2][ni][rr] + gxc[2][ni][rr]);
                    float og = fast_sig (acc[3][ni][rr] + gxc[3][ni][rr]);
                    float c  = fg * creg[ni][rr] + ig * gg;
                    creg[ni][rr] = c;
                    hq |= (u64)f2bf(og * fast_tanh(c)) << (rr * 16);
                }
                __hip_atomic_store((u64*)(hd + (long)(b0 + ni*16) * 512 + jcol), hq,
                                   __ATOMIC_RELAXED, __HIP_MEMORY_SCOPE_AGENT);
            }
            hsrc = hd;

            // release: drain THIS wave's stores (gx prefetch already landed), then flag
            asm volatile("s_waitcnt vmcnt(0)" ::: "memory");
            __builtin_amdgcn_sched_barrier(0);
            if (lane == 0)
                __hip_atomic_store(&fl[jb], (unsigned)(t + 1),
                                   __ATOMIC_RELAXED, __HIP_MEMORY_SCOPE_AGENT);
            if (t < TB - 1) {
                // acquire: 32 lanes poll this group's 32 flags in parallel
                while (true) {
                    unsigned v = __hip_atomic_load(&fl[lane & 31],
                                                   __ATOMIC_RELAXED, __HIP_MEMORY_SCOPE_AGENT);
                    if (__all(v > (unsigned)t)) break;
                    __builtin_amdgcn_s_sleep(1);
                }
                __builtin_amdgcn_fence(__ATOMIC_ACQUIRE, "agent");  // inv caches, no wb
                #pragma unroll
                for (int g = 0; g < 4; ++g)
                    #pragma unroll
                    for (int ni = 0; ni < 2; ++ni) gxc[g][ni] = gxn[g][ni];
            }
        }
    } else if (bid < 64) {
        // ======== fc1 workers: o_t = relu(h_t @ Wfc1^T + b), 4 tiles/step ========
        const int wkr = bid - 32;                 // 0..31
        for (int g = wkr; g < TB * 4; g += 32) {
            int tt = g >> 2, nt4 = g & 3;
            if (t256 < 64) {                       // wave 0: poll ALL 128 per-wave flags
                while (true) {
                    unsigned v0 = __hip_atomic_load(&bar[lane],
                                                    __ATOMIC_RELAXED, __HIP_MEMORY_SCOPE_AGENT);
                    unsigned v1 = __hip_atomic_load(&bar[64 + lane],
                                                    __ATOMIC_RELAXED, __HIP_MEMORY_SCOPE_AGENT);
                    if (__all((v0 > (unsigned)tt) && (v1 > (unsigned)tt))) break;
                    __builtin_amdgcn_s_sleep(8);
                }
            }
            __syncthreads();
            __builtin_amdgcn_fence(__ATOMIC_ACQUIRE, "agent");
            tile_gemm<2,1>(shm, h_b + (long)tt * (BB*HH), wfc1, nt4 * 128, HH, b_fc1,
                           (char*)(o_b + (long)tt * (BB*HH)), HH * 2);
            __syncthreads();                      // drain WT o stores (all waves)
            if (t256 == 0)
                __hip_atomic_fetch_add(bar + 600 + tt, 1u,
                                       __ATOMIC_RELAXED, __HIP_MEMORY_SCOPE_AGENT);
        }
    } else {
        // ======== fc2 workers: out[:,t,:] = o_t @ Wfc2^T + b, 79 tiles/step ========
        const int wkr = bid - 64;                 // 0..191
        for (int g = wkr; g < TB * 79; g += 192) {
            int tt = g / 79, nt = g - tt * 79;
            if (t256 == 0) {
                while (__hip_atomic_load(bar + 600 + tt, __ATOMIC_RELAXED,
                                         __HIP_MEMORY_SCOPE_AGENT) < 4)
                    __builtin_amdgcn_s_sleep(8);
            }
            __syncthreads();
            __builtin_amdgcn_fence(__ATOMIC_ACQUIRE, "agent");
            tile_gemm<0,0>(shm, o_b + (long)tt * (BB*HH), wfc2, nt * 128, VV, b_fc2,
                           (char*)(out + (long)tt * VV), (long)TB * VV * 4);
        }
    }
}

extern "C" void kernel_launch(void* const* d_in, const int* in_sizes, int n_in,
                              void* d_out, int out_size, void* d_ws, size_t ws_size,
                              hipStream_t stream)
{
    const float* img    = (const float*)d_in[0];
    const int*   seqs   = (const int*)d_in[1];
    const float* emb    = (const float*)d_in[3];
    const float* W_ih   = (const float*)d_in[4];
    const float* b_ih   = (const float*)d_in[5];
    const float* W_hh   = (const float*)d_in[6];
    const float* b_hh   = (const float*)d_in[7];
    const float* W_inh  = (const float*)d_in[8];
    const float* b_inh  = (const float*)d_in[9];
    const float* W_inc  = (const float*)d_in[10];
    const float* b_inc  = (const float*)d_in[11];
    const float* W_fc1  = (const float*)d_in[12];
    const float* b_fc1  = (const float*)d_in[13];
    const float* W_fc2  = (const float*)d_in[14];
    const float* b_fc2  = (const float*)d_in[15];
    float* out = (float*)d_out;

    float*    ws  = (float*)d_ws;
    unsigned* bar = (unsigned*)ws;          // 1024 reserved; rec flags bar[0..127], o_ctr bar[600+t]
    float* mf    = ws    + 1024;            // 180224
    float* c_cur = mf    + 180224;          // 65536
    float* gxb   = c_cur + 65536;           // 262144
    float* gx    = gxb   + 262144;          // 9175040  [t][b][2048] fp32
    float* ipart = gx;                      // alias (1572864 <= 9175040), dead before gx
    u16*   h_b    = (u16*)(gx + 9175040);   // 2293760  [t][b][512] bf16
    u16*   h0b    = h_b    + 2293760;       // 65536
    u16*   emb_b  = h0b    + 65536;         // 5120000
    u16*   wih_b  = emb_b  + 5120000;       // 1048576
    u16*   wfc1_b = wih_b  + 1048576;       // 262144
    u16*   wfc2_b = wfc1_b + 262144;        // 5120000
    u16*   o_b    = wfc2_b + 5120000;       // 2293760

    // merged prologue: 4 casts + region mean in one launch
    prolog_k<<<11984, 256, 0, stream>>>(emb, W_ih, W_fc1, W_fc2,
                                        emb_b, wih_b, wfc1_b, wfc2_b, img, mf);

    init_partial_k<<<dim3(48, 2, 4), 256, 0, stream>>>(mf, W_inh, W_inc, W_ih, ipart);
    init_combine_k<<<1536, 256, 0, stream>>>(ipart, b_ih, b_hh, b_inh, b_inc,
                                             h0b, c_cur, gxb, bar);

    // gx[t][b][n] = emb_b[seq[b][t]] . wih_b[n] + gxb[b][n]
    gemm_mfma<0,0><<<dim3(16 * 35), 256, 0, stream>>>(emb_b, EE, seqs, wih_b, nullptr,
                                                      gxb, TB, G4, gx, TB, G4,
                                                      (long)BB * G4, 35, G4, EE);

    // recurrence + overlapped fc1/fc2: ONE plain-launched persistent kernel (256 = 1/CU)
    mega_k<<<dim3(256), dim3(256), 0, stream>>>(h0b, c_cur, W_hh, gx, h_b, bar,
                                                wfc1_b, b_fc1, o_b, wfc2_b, b_fc2, out);
}